// Round 4
// baseline (14729.837 us; speedup 1.0000x reference)
//
#include <hip/hip_runtime.h>
#include <hip/hip_bf16.h>

#define DEV __device__ __forceinline__

DEV float lrelu_(float x){ return x > 0.f ? x : 0.01f * x; }
DEV float ssp_(float x){ float sp = fmaxf(x, 0.f) + log1pf(__expf(-fabsf(x))); return sp - 0.69314718055994530942f; }
DEV float sigm_(float x){ return 1.f / (1.f + __expf(-x)); }

DEV void fma44(float (&acc)[4][4], const float4 (&xa)[4], const float4 (&wa)[4])
{
    #pragma unroll
    for (int kk = 0; kk < 4; kk++) {
        #pragma unroll
        for (int i = 0; i < 4; i++) {
            float x = ((const float*)&xa[i])[kk];
            #pragma unroll
            for (int j = 0; j < 4; j++)
                acc[i][j] += x * ((const float*)&wa[kk])[j];
        }
    }
}

// ================= generic tiled GEMM:  Y[N x 64] = act( (X .* scale?) @ W[K x 64] + b ) =========
template<int K, int ACT, bool SCALE>
__global__ __launch_bounds__(256) void gemm64_kernel(const float* __restrict__ X,
                                                     const float* __restrict__ scale,
                                                     const float* __restrict__ W,
                                                     const float* __restrict__ B,
                                                     float* __restrict__ Y, int nrows)
{
    constexpr int XS = K + 4;
    constexpr int KQ = K / 4;
    __shared__ float Ws[K * 64];
    __shared__ float bs[64];
    __shared__ float Xs[64 * XS];
    for (int i = threadIdx.x; i < K * 64; i += 256) Ws[i] = W[i];
    if (threadIdx.x < 64) bs[threadIdx.x] = B[threadIdx.x];
    const int tr = threadIdx.x >> 4, tc = threadIdx.x & 15;
    const int r0 = tr * 4, c0 = tc * 4;
    for (int base = blockIdx.x * 64; base < nrows; base += gridDim.x * 64) {
        __syncthreads();
        for (int i = threadIdx.x; i < 64 * KQ; i += 256) {
            int row = i / KQ, kq = (i % KQ) * 4;
            int g = base + row;
            float4 v = make_float4(0.f, 0.f, 0.f, 0.f);
            if (g < nrows) {
                v = *(const float4*)&X[(size_t)g * K + kq];
                if (SCALE) { float s = scale[g]; v.x *= s; v.y *= s; v.z *= s; v.w *= s; }
            }
            *(float4*)&Xs[row * XS + kq] = v;
        }
        __syncthreads();
        float acc[4][4];
        #pragma unroll
        for (int i = 0; i < 4; i++)
            #pragma unroll
            for (int j = 0; j < 4; j++) acc[i][j] = bs[c0 + j];
        #pragma unroll
        for (int kq = 0; kq < K; kq += 4) {
            float4 xa[4], wa[4];
            #pragma unroll
            for (int i = 0; i < 4; i++) xa[i] = *(const float4*)&Xs[(r0 + i) * XS + kq];
            #pragma unroll
            for (int j = 0; j < 4; j++) wa[j] = *(const float4*)&Ws[(kq + j) * 64 + c0];
            fma44(acc, xa, wa);
        }
        #pragma unroll
        for (int i = 0; i < 4; i++) {
            int g = base + r0 + i;
            if (g < nrows) {
                float4 o;
                float* op = (float*)&o;
                #pragma unroll
                for (int j = 0; j < 4; j++) {
                    float a = acc[i][j];
                    if (ACT == 1) a = lrelu_(a);
                    else if (ACT == 2) a = fmaxf(a, 0.f);
                    op[j] = a;
                }
                *(float4*)&Y[(size_t)g * 64 + c0] = o;
            }
        }
    }
}

// ---------------- small scalar GEMV (pin encoder, C=16) ----------------
template<int K, int C, int ACT>
__global__ __launch_bounds__(256) void lin_kernel(const float* __restrict__ X,
                                                  const float* __restrict__ W,
                                                  const float* __restrict__ B,
                                                  float* __restrict__ Y, int nrows)
{
    constexpr int ROWS = 256 / C;
    __shared__ float Ws[K * C];
    __shared__ float bs[C];
    __shared__ float Xs[ROWS * K];
    for (int i = threadIdx.x; i < K * C; i += 256) Ws[i] = W[i];
    if (threadIdx.x < C) bs[threadIdx.x] = B[threadIdx.x];
    __syncthreads();
    const int r = threadIdx.x / C, c = threadIdx.x % C;
    for (int base = blockIdx.x * ROWS; base < nrows; base += gridDim.x * ROWS) {
        __syncthreads();
        for (int i = threadIdx.x; i < ROWS * K; i += 256) {
            int rr = base + i / K;
            Xs[i] = (rr < nrows) ? X[(size_t)rr * K + i % K] : 0.f;
        }
        __syncthreads();
        int row = base + r;
        if (row < nrows) {
            float acc = bs[c];
            #pragma unroll
            for (int k = 0; k < K; k++) acc += Xs[r * K + k] * Ws[k * C + c];
            if (ACT == 1) acc = lrelu_(acc);
            else if (ACT == 2) acc = fmaxf(acc, 0.f);
            Y[(size_t)row * C + c] = acc;
        }
    }
}

// ---------------- degrees ----------------
__global__ __launch_bounds__(256) void deg_kernel(const int* __restrict__ src, const int* __restrict__ dst,
                                                  int* __restrict__ degs, int* __restrict__ degd, int np)
{
    int p = blockIdx.x * 256 + threadIdx.x;
    if (p < np) { atomicAdd(&degs[src[p]], 1); atomicAdd(&degd[dst[p]], 1); }
}

__global__ __launch_bounds__(256) void norm_kernel(int* __restrict__ arr, int n)
{
    int i = blockIdx.x * 256 + threadIdx.x;
    if (i < n) {
        int v = arr[i]; if (v < 1) v = 1;
        arr[i] = __float_as_int(rsqrtf((float)v));
    }
}

// ---------------- edge weights for all 3 layers ----------------
__global__ __launch_bounds__(256) void edge_ew_kernel(const float* __restrict__ in_edge,
                                                      const float* __restrict__ elW, const float* __restrict__ elb,
                                                      const float* __restrict__ gW, const float* __restrict__ gb,
                                                      float* __restrict__ ew3, int ne)
{
    __shared__ float W[32], B[8], G[24], Gb[3];
    if (threadIdx.x < 32) W[threadIdx.x] = elW[threadIdx.x];
    if (threadIdx.x < 8)  B[threadIdx.x] = elb[threadIdx.x];
    if (threadIdx.x < 24) G[threadIdx.x] = gW[threadIdx.x];
    if (threadIdx.x < 3)  Gb[threadIdx.x] = gb[threadIdx.x];
    __syncthreads();
    for (int e = blockIdx.x * 256 + threadIdx.x; e < ne; e += gridDim.x * 256) {
        float4 x = *(const float4*)&in_edge[(size_t)e * 4];
        float ef[8];
        #pragma unroll
        for (int j = 0; j < 8; j++)
            ef[j] = lrelu_(B[j] + x.x * W[j] + x.y * W[8 + j] + x.z * W[16 + j] + x.w * W[24 + j]);
        #pragma unroll
        for (int i = 0; i < 3; i++) {
            float a = Gb[i];
            #pragma unroll
            for (int j = 0; j < 8; j++) a += ef[j] * G[i * 8 + j];
            ew3[(size_t)i * ne + e] = sigm_(a);
        }
    }
}

// ---------------- pins GraphConv scatter (float4 lanes):  agg[dst] += node*srcnorm ----------------
__global__ __launch_bounds__(256) void pins_scatter2(const float* __restrict__ nf, const float* __restrict__ snorm,
                                                     const int* __restrict__ src, const int* __restrict__ dst,
                                                     float* __restrict__ agg, int np)
{
    long long idx = (long long)blockIdx.x * 256 + threadIdx.x;
    int p = (int)(idx >> 4); if (p >= np) return;
    int c0 = (int)(idx & 15) * 4;
    int s = src[p], d = dst[p];
    float sn = snorm[s];
    float4 v = *(const float4*)&nf[(size_t)s * 64 + c0];
    float* agp = &agg[(size_t)d * 64 + c0];
    unsafeAtomicAdd(agp + 0, v.x * sn);
    unsafeAtomicAdd(agp + 1, v.y * sn);
    unsafeAtomicAdd(agp + 2, v.z * sn);
    unsafeAtomicAdd(agp + 3, v.w * sn);
}

// ---------------- CFConv fused, register-tiled, fused epilogue scatter ----------------
__global__ __launch_bounds__(256) void cf_pin3_kernel(const float* __restrict__ pinf, const float* __restrict__ hv,
                                                      const int* __restrict__ psrc, const int* __restrict__ pdst,
                                                      const float* __restrict__ W1, const float* __restrict__ B1,
                                                      const float* __restrict__ W2, const float* __restrict__ B2,
                                                      float* __restrict__ h_cf, int np)
{
    __shared__ float Ws1[16 * 64], Ws2[64 * 64], bs1[64], bs2[64];
    __shared__ float PF[64 * 20], T1[64 * 68];
    __shared__ int srcS[64], dstS[64];
    for (int i = threadIdx.x; i < 16 * 64; i += 256) Ws1[i] = W1[i];
    for (int i = threadIdx.x; i < 64 * 64; i += 256) Ws2[i] = W2[i];
    if (threadIdx.x < 64) { bs1[threadIdx.x] = B1[threadIdx.x]; bs2[threadIdx.x] = B2[threadIdx.x]; }
    const int tr = threadIdx.x >> 4, tc = threadIdx.x & 15;
    const int r0 = tr * 4, c0 = tc * 4;
    for (int base = blockIdx.x * 64; base < np; base += gridDim.x * 64) {
        __syncthreads();
        {
            int row = threadIdx.x >> 2, kq = (threadIdx.x & 3) * 4;
            int p = base + row;
            float4 v = make_float4(0.f, 0.f, 0.f, 0.f);
            if (p < np) v = *(const float4*)&pinf[(size_t)p * 16 + kq];
            *(float4*)&PF[row * 20 + kq] = v;
            if (threadIdx.x < 64) {
                int pp = base + threadIdx.x;
                srcS[threadIdx.x] = (pp < np) ? psrc[pp] : 0;
                dstS[threadIdx.x] = (pp < np) ? pdst[pp] : 0;
            }
        }
        __syncthreads();
        // GEMM1: T1 = ssp(PF @ W1 + b1), K=16
        {
            float acc[4][4];
            #pragma unroll
            for (int i = 0; i < 4; i++)
                #pragma unroll
                for (int j = 0; j < 4; j++) acc[i][j] = bs1[c0 + j];
            #pragma unroll
            for (int kq = 0; kq < 16; kq += 4) {
                float4 xa[4], wa[4];
                #pragma unroll
                for (int i = 0; i < 4; i++) xa[i] = *(const float4*)&PF[(r0 + i) * 20 + kq];
                #pragma unroll
                for (int j = 0; j < 4; j++) wa[j] = *(const float4*)&Ws1[(kq + j) * 64 + c0];
                fma44(acc, xa, wa);
            }
            #pragma unroll
            for (int i = 0; i < 4; i++) {
                float4 o; float* op = (float*)&o;
                #pragma unroll
                for (int j = 0; j < 4; j++) op[j] = ssp_(acc[i][j]);
                *(float4*)&T1[(r0 + i) * 68 + c0] = o;
            }
        }
        __syncthreads();
        // GEMM2 + fused scatter epilogue
        {
            float acc[4][4];
            #pragma unroll
            for (int i = 0; i < 4; i++)
                #pragma unroll
                for (int j = 0; j < 4; j++) acc[i][j] = bs2[c0 + j];
            #pragma unroll
            for (int kq = 0; kq < 64; kq += 4) {
                float4 xa[4], wa[4];
                #pragma unroll
                for (int i = 0; i < 4; i++) xa[i] = *(const float4*)&T1[(r0 + i) * 68 + kq];
                #pragma unroll
                for (int j = 0; j < 4; j++) wa[j] = *(const float4*)&Ws2[(kq + j) * 64 + c0];
                fma44(acc, xa, wa);
            }
            #pragma unroll
            for (int i = 0; i < 4; i++) {
                int row = r0 + i;
                int p = base + row;
                if (p < np) {
                    float4 hv4 = *(const float4*)&hv[(size_t)dstS[row] * 64 + c0];
                    float* cp = &h_cf[(size_t)srcS[row] * 64 + c0];
                    unsafeAtomicAdd(cp + 0, hv4.x * ssp_(acc[i][0]));
                    unsafeAtomicAdd(cp + 1, hv4.y * ssp_(acc[i][1]));
                    unsafeAtomicAdd(cp + 2, hv4.z * ssp_(acc[i][2]));
                    unsafeAtomicAdd(cp + 3, hv4.w * ssp_(acc[i][3]));
                }
            }
        }
    }
}

// ---------------- SAGE edge scatter-max (float4 lanes) ----------------
__global__ __launch_bounds__(256) void sage_edge2_kernel(const float* __restrict__ hp, const float* __restrict__ ew,
                                                         const int* __restrict__ esrc, const int* __restrict__ edst,
                                                         unsigned int* __restrict__ h_ng, int ne)
{
    long long idx = (long long)blockIdx.x * 256 + threadIdx.x;
    int e = (int)(idx >> 4); if (e >= ne) return;
    int c0 = (int)(idx & 15) * 4;
    int s = esrc[e], d = edst[e];
    float w = ew[e];
    float4 v = *(const float4*)&hp[(size_t)s * 64 + c0];
    unsigned int* hg = &h_ng[(size_t)d * 64 + c0];
    atomicMax(hg + 0, __float_as_uint(v.x * w));
    atomicMax(hg + 1, __float_as_uint(v.y * w));
    atomicMax(hg + 2, __float_as_uint(v.z * w));
    atomicMax(hg + 3, __float_as_uint(v.w * w));
}

// ---------------- combine (32 rows/iter, grid-stride) ----------------
__global__ __launch_bounds__(256) void combine3_kernel(const float* __restrict__ h_cf, const float* __restrict__ nf,
                                                       const float* __restrict__ h_ng,
                                                       const float* __restrict__ cW, const float* __restrict__ cB,
                                                       const float* __restrict__ sW, const float* __restrict__ nW,
                                                       const float* __restrict__ sB,
                                                       float* __restrict__ out, int n)
{
    __shared__ float Wc[64 * 64], Wsf[64 * 64], Wng[64 * 64];
    __shared__ float bc[64], bsg[64];
    __shared__ float Xc[32 * 68], Xf[32 * 68], Xn[32 * 68];
    for (int i = threadIdx.x; i < 64 * 64; i += 256) { Wc[i] = cW[i]; Wsf[i] = sW[i]; Wng[i] = nW[i]; }
    if (threadIdx.x < 64) { bc[threadIdx.x] = cB[threadIdx.x]; bsg[threadIdx.x] = sB[threadIdx.x]; }
    const int tr = threadIdx.x >> 4, tc = threadIdx.x & 15;
    const int r0 = tr * 2, c0 = tc * 4;
    for (int base = blockIdx.x * 32; base < n; base += gridDim.x * 32) {
        __syncthreads();
        for (int i = threadIdx.x; i < 512; i += 256) {
            int row = i >> 4, kq = (i & 15) * 4;
            int g = base + row;
            float4 a = make_float4(0,0,0,0), b = a, c = a;
            if (g < n) {
                a = *(const float4*)&h_cf[(size_t)g * 64 + kq];
                b = *(const float4*)&nf[(size_t)g * 64 + kq];
                c = *(const float4*)&h_ng[(size_t)g * 64 + kq];
            }
            *(float4*)&Xc[row * 68 + kq] = a;
            *(float4*)&Xf[row * 68 + kq] = b;
            *(float4*)&Xn[row * 68 + kq] = c;
        }
        __syncthreads();
        float a1[2][4], a2[2][4];
        #pragma unroll
        for (int i = 0; i < 2; i++)
            #pragma unroll
            for (int j = 0; j < 4; j++) { a1[i][j] = bc[c0 + j]; a2[i][j] = bsg[c0 + j]; }
        #pragma unroll
        for (int kq = 0; kq < 64; kq += 4) {
            float4 xc[2], xf[2], xn[2];
            #pragma unroll
            for (int i = 0; i < 2; i++) {
                xc[i] = *(const float4*)&Xc[(r0 + i) * 68 + kq];
                xf[i] = *(const float4*)&Xf[(r0 + i) * 68 + kq];
                xn[i] = *(const float4*)&Xn[(r0 + i) * 68 + kq];
            }
            #pragma unroll
            for (int kk = 0; kk < 4; kk++) {
                float4 wc = *(const float4*)&Wc[(kq + kk) * 64 + c0];
                float4 wsf = *(const float4*)&Wsf[(kq + kk) * 64 + c0];
                float4 wng = *(const float4*)&Wng[(kq + kk) * 64 + c0];
                #pragma unroll
                for (int i = 0; i < 2; i++) {
                    float x1 = ((const float*)&xc[i])[kk];
                    float x2 = ((const float*)&xf[i])[kk];
                    float x3 = ((const float*)&xn[i])[kk];
                    #pragma unroll
                    for (int j = 0; j < 4; j++) {
                        a1[i][j] += x1 * ((const float*)&wc)[j];
                        a2[i][j] += x2 * ((const float*)&wsf)[j] + x3 * ((const float*)&wng)[j];
                    }
                }
            }
        }
        #pragma unroll
        for (int i = 0; i < 2; i++) {
            int g = base + r0 + i;
            if (g < n) {
                float4 o; float* op = (float*)&o;
                #pragma unroll
                for (int j = 0; j < 4; j++) op[j] = lrelu_(fmaxf(ssp_(a1[i][j]), a2[i][j]));
                *(float4*)&out[(size_t)g * 64 + c0] = o;
            }
        }
    }
}

// ---------------- node head (32 rows/iter, grid-stride, 3-stage MLP) ----------------
__global__ __launch_bounds__(256) void node_head3_kernel(const float* __restrict__ in_node, const float* __restrict__ nf,
                                                         const float* __restrict__ W1, const float* __restrict__ B1,
                                                         const float* __restrict__ W2, const float* __restrict__ B2,
                                                         const float* __restrict__ W3, const float* __restrict__ B3,
                                                         float* __restrict__ out, int n)
{
    __shared__ float Ws1[80 * 64], Ws2[64 * 64], Ws3[64 * 4];
    __shared__ float bs1[64], bs2[64], bs3[4];
    __shared__ float Xs[32 * 84];       // reused as H2 (stride 68)
    __shared__ float H1[32 * 68];
    for (int i = threadIdx.x; i < 80 * 64; i += 256) Ws1[i] = W1[i];
    for (int i = threadIdx.x; i < 64 * 64; i += 256) Ws2[i] = W2[i];
    for (int i = threadIdx.x; i < 64 * 4; i += 256) Ws3[i] = W3[i];
    if (threadIdx.x < 64) { bs1[threadIdx.x] = B1[threadIdx.x]; bs2[threadIdx.x] = B2[threadIdx.x]; }
    if (threadIdx.x < 4) bs3[threadIdx.x] = B3[threadIdx.x];
    const int tr = threadIdx.x >> 4, tc = threadIdx.x & 15;
    const int r0 = tr * 2, c0 = tc * 4;
    for (int base = blockIdx.x * 32; base < n; base += gridDim.x * 32) {
        __syncthreads();
        for (int i = threadIdx.x; i < 32 * 4; i += 256) {
            int row = i >> 2, kq = (i & 3) * 4;
            int g = base + row;
            float4 v = make_float4(0,0,0,0);
            if (g < n) v = *(const float4*)&in_node[(size_t)g * 16 + kq];
            *(float4*)&Xs[row * 84 + kq] = v;
        }
        for (int i = threadIdx.x; i < 32 * 16; i += 256) {
            int row = i >> 4, kq = (i & 15) * 4;
            int g = base + row;
            float4 v = make_float4(0,0,0,0);
            if (g < n) v = *(const float4*)&nf[(size_t)g * 64 + kq];
            *(float4*)&Xs[row * 84 + 16 + kq] = v;
        }
        __syncthreads();
        {
            float acc[2][4];
            #pragma unroll
            for (int i = 0; i < 2; i++)
                #pragma unroll
                for (int j = 0; j < 4; j++) acc[i][j] = bs1[c0 + j];
            #pragma unroll
            for (int kq = 0; kq < 80; kq += 4) {
                float4 xa[2], wa[4];
                #pragma unroll
                for (int i = 0; i < 2; i++) xa[i] = *(const float4*)&Xs[(r0 + i) * 84 + kq];
                #pragma unroll
                for (int j = 0; j < 4; j++) wa[j] = *(const float4*)&Ws1[(kq + j) * 64 + c0];
                #pragma unroll
                for (int kk = 0; kk < 4; kk++)
                    #pragma unroll
                    for (int i = 0; i < 2; i++) {
                        float x = ((const float*)&xa[i])[kk];
                        #pragma unroll
                        for (int j = 0; j < 4; j++) acc[i][j] += x * ((const float*)&wa[kk])[j];
                    }
            }
            #pragma unroll
            for (int i = 0; i < 2; i++) {
                float4 o; float* op = (float*)&o;
                #pragma unroll
                for (int j = 0; j < 4; j++) op[j] = lrelu_(acc[i][j]);
                *(float4*)&H1[(r0 + i) * 68 + c0] = o;
            }
        }
        __syncthreads();
        float* H2 = Xs;
        {
            float acc[2][4];
            #pragma unroll
            for (int i = 0; i < 2; i++)
                #pragma unroll
                for (int j = 0; j < 4; j++) acc[i][j] = bs2[c0 + j];
            #pragma unroll
            for (int kq = 0; kq < 64; kq += 4) {
                float4 xa[2], wa[4];
                #pragma unroll
                for (int i = 0; i < 2; i++) xa[i] = *(const float4*)&H1[(r0 + i) * 68 + kq];
                #pragma unroll
                for (int j = 0; j < 4; j++) wa[j] = *(const float4*)&Ws2[(kq + j) * 64 + c0];
                #pragma unroll
                for (int kk = 0; kk < 4; kk++)
                    #pragma unroll
                    for (int i = 0; i < 2; i++) {
                        float x = ((const float*)&xa[i])[kk];
                        #pragma unroll
                        for (int j = 0; j < 4; j++) acc[i][j] += x * ((const float*)&wa[kk])[j];
                    }
            }
            __syncthreads();
            #pragma unroll
            for (int i = 0; i < 2; i++) {
                float4 o; float* op = (float*)&o;
                #pragma unroll
                for (int j = 0; j < 4; j++) op[j] = lrelu_(acc[i][j]);
                *(float4*)&H2[(r0 + i) * 68 + c0] = o;
            }
        }
        __syncthreads();
        if (threadIdx.x < 128) {
            int row = threadIdx.x >> 2, c = threadIdx.x & 3;
            float acc = bs3[c];
            #pragma unroll
            for (int kq = 0; kq < 64; kq += 4) {
                float4 h = *(const float4*)&H2[row * 68 + kq];
                #pragma unroll
                for (int j = 0; j < 4; j++) acc += ((const float*)&h)[j] * Ws3[(kq + j) * 4 + c];
            }
            int g = base + row;
            if (g < n) out[(size_t)g * 4 + c] = sigm_(acc);
        }
    }
}

// ---------------- net head (32 rows/iter, grid-stride, C_out=1) ----------------
__global__ __launch_bounds__(256) void net_head3_kernel(const float* __restrict__ in_net, const float* __restrict__ tf,
                                                        const float* __restrict__ W1, const float* __restrict__ B1,
                                                        const float* __restrict__ W2, const float* __restrict__ B2,
                                                        const float* __restrict__ W3, const float* __restrict__ B3,
                                                        float* __restrict__ out, int n)
{
    __shared__ float Ws1[72 * 64], Ws2[64 * 64], Ws3[64];
    __shared__ float bs1[64], bs2[64], bs3[1];
    __shared__ float Xs[32 * 76];       // reused as H2 (stride 68)
    __shared__ float H1[32 * 68];
    for (int i = threadIdx.x; i < 72 * 64; i += 256) Ws1[i] = W1[i];
    for (int i = threadIdx.x; i < 64 * 64; i += 256) Ws2[i] = W2[i];
    if (threadIdx.x < 64) { Ws3[threadIdx.x] = W3[threadIdx.x]; bs1[threadIdx.x] = B1[threadIdx.x]; bs2[threadIdx.x] = B2[threadIdx.x]; }
    if (threadIdx.x == 0) bs3[0] = B3[0];
    const int tr = threadIdx.x >> 4, tc = threadIdx.x & 15;
    const int r0 = tr * 2, c0 = tc * 4;
    for (int base = blockIdx.x * 32; base < n; base += gridDim.x * 32) {
        __syncthreads();
        for (int i = threadIdx.x; i < 32 * 2; i += 256) {
            int row = i >> 1, kq = (i & 1) * 4;
            int g = base + row;
            float4 v = make_float4(0,0,0,0);
            if (g < n) v = *(const float4*)&in_net[(size_t)g * 8 + kq];
            *(float4*)&Xs[row * 76 + kq] = v;
        }
        for (int i = threadIdx.x; i < 32 * 16; i += 256) {
            int row = i >> 4, kq = (i & 15) * 4;
            int g = base + row;
            float4 v = make_float4(0,0,0,0);
            if (g < n) v = *(const float4*)&tf[(size_t)g * 64 + kq];
            *(float4*)&Xs[row * 76 + 8 + kq] = v;
        }
        __syncthreads();
        {
            float acc[2][4];
            #pragma unroll
            for (int i = 0; i < 2; i++)
                #pragma unroll
                for (int j = 0; j < 4; j++) acc[i][j] = bs1[c0 + j];
            #pragma unroll
            for (int kq = 0; kq < 72; kq += 4) {
                float4 xa[2], wa[4];
                #pragma unroll
                for (int i = 0; i < 2; i++) xa[i] = *(const float4*)&Xs[(r0 + i) * 76 + kq];
                #pragma unroll
                for (int j = 0; j < 4; j++) wa[j] = *(const float4*)&Ws1[(kq + j) * 64 + c0];
                #pragma unroll
                for (int kk = 0; kk < 4; kk++)
                    #pragma unroll
                    for (int i = 0; i < 2; i++) {
                        float x = ((const float*)&xa[i])[kk];
                        #pragma unroll
                        for (int j = 0; j < 4; j++) acc[i][j] += x * ((const float*)&wa[kk])[j];
                    }
            }
            #pragma unroll
            for (int i = 0; i < 2; i++) {
                float4 o; float* op = (float*)&o;
                #pragma unroll
                for (int j = 0; j < 4; j++) op[j] = lrelu_(acc[i][j]);
                *(float4*)&H1[(r0 + i) * 68 + c0] = o;
            }
        }
        __syncthreads();
        float* H2 = Xs;
        {
            float acc[2][4];
            #pragma unroll
            for (int i = 0; i < 2; i++)
                #pragma unroll
                for (int j = 0; j < 4; j++) acc[i][j] = bs2[c0 + j];
            #pragma unroll
            for (int kq = 0; kq < 64; kq += 4) {
                float4 xa[2], wa[4];
                #pragma unroll
                for (int i = 0; i < 2; i++) xa[i] = *(const float4*)&H1[(r0 + i) * 68 + kq];
                #pragma unroll
                for (int j = 0; j < 4; j++) wa[j] = *(const float4*)&Ws2[(kq + j) * 64 + c0];
                #pragma unroll
                for (int kk = 0; kk < 4; kk++)
                    #pragma unroll
                    for (int i = 0; i < 2; i++) {
                        float x = ((const float*)&xa[i])[kk];
                        #pragma unroll
                        for (int j = 0; j < 4; j++) acc[i][j] += x * ((const float*)&wa[kk])[j];
                    }
            }
            __syncthreads();
            #pragma unroll
            for (int i = 0; i < 2; i++) {
                float4 o; float* op = (float*)&o;
                #pragma unroll
                for (int j = 0; j < 4; j++) op[j] = lrelu_(acc[i][j]);
                *(float4*)&H2[(r0 + i) * 68 + c0] = o;
            }
        }
        __syncthreads();
        if (threadIdx.x < 32) {
            int row = threadIdx.x;
            float acc = bs3[0];
            #pragma unroll
            for (int kq = 0; kq < 64; kq += 4) {
                float4 h = *(const float4*)&H2[row * 68 + kq];
                float4 w = *(const float4*)&Ws3[kq];
                acc += h.x * w.x + h.y * w.y + h.z * w.z + h.w * w.w;
            }
            int g = base + row;
            if (g < n) out[g] = sigm_(acc);
        }
    }
}

extern "C" void kernel_launch(void* const* d_in, const int* in_sizes, int n_in,
                              void* d_out, int out_size, void* d_ws, size_t ws_size,
                              hipStream_t stream)
{
    (void)in_sizes; (void)n_in; (void)out_size; (void)ws_size;
    constexpr int Nn = 100000, Nt = 30000, Np = 400000, Ne = 1000000;
    constexpr int H = 64, L = 3, T = 4;

    auto fpt = [&](int i){ return (const float*)d_in[i]; };
    auto ipt = [&](int i){ return (const int*)d_in[i]; };

    const float* in_node = fpt(0);
    const float* in_net  = fpt(1);
    const float* in_pin  = fpt(2);
    const float* in_edge = fpt(3);
    const int* psrc = ipt(4);
    const int* pdst = ipt(5);
    const int* esrc = ipt(6);
    const int* edst = ipt(7);

    float* ws = (float*)d_ws;
    size_t o = 0;
    auto alloc = [&](size_t nel){ float* p = ws + o; o += nel; return p; };
    float* node_a = alloc((size_t)Nn * H);
    float* node_b = alloc((size_t)Nn * H);
    float* net_a  = alloc((size_t)Nt * H);
    float* net_b  = alloc((size_t)Nt * H);
    float* agg    = alloc((size_t)Nt * H);
    float* hv     = alloc((size_t)Nt * H);
    float* pinf   = alloc((size_t)Np * 16);
    float* h_cf   = alloc((size_t)Nn * H);
    float* hp     = alloc((size_t)Nn * H);
    float* h_ng   = alloc((size_t)Nn * H);
    float* ew3    = alloc((size_t)3 * Ne);
    float* snorm  = alloc((size_t)Nn);
    float* dnorm  = alloc((size_t)Nt);

    // degree norms
    hipMemsetAsync(snorm, 0, (size_t)Nn * 4, stream);
    hipMemsetAsync(dnorm, 0, (size_t)Nt * 4, stream);
    deg_kernel<<<(Np + 255) / 256, 256, 0, stream>>>(psrc, pdst, (int*)snorm, (int*)dnorm, Np);
    norm_kernel<<<(Nn + 255) / 256, 256, 0, stream>>>((int*)snorm, Nn);
    norm_kernel<<<(Nt + 255) / 256, 256, 0, stream>>>((int*)dnorm, Nt);

    // input encoders
    gemm64_kernel<16, 1, false><<<1024, 256, 0, stream>>>(in_node, nullptr, fpt(8),  fpt(9),  node_a, Nn);
    gemm64_kernel< 8, 1, false><<<469, 256, 0, stream>>>(in_net,  nullptr, fpt(10), fpt(11), net_a,  Nt);
    lin_kernel<8, 16, 1><<<1024, 256, 0, stream>>>(in_pin, fpt(12), fpt(13), pinf, Np);
    edge_ew_kernel<<<2048, 256, 0, stream>>>(in_edge, fpt(14), fpt(15), fpt(16), fpt(17), ew3, Ne);

    float* ncur = node_a; float* nnew = node_b;
    float* tcur = net_a;  float* tnew = net_b;

    for (int i = 0; i < L; i++) {
        // pins GraphConv (node -> net)
        hipMemsetAsync(agg, 0, (size_t)Nt * H * 4, stream);
        pins_scatter2<<<(int)(((long long)Np * 16 + 255) / 256), 256, 0, stream>>>(ncur, snorm, psrc, pdst, agg, Np);
        gemm64_kernel<64, 1, true><<<469, 256, 0, stream>>>(agg, dnorm, fpt(18) + (size_t)i * 4096, fpt(19) + (size_t)i * 64, tnew, Nt);

        // CFConv (net -> node)
        gemm64_kernel<64, 0, false><<<469, 256, 0, stream>>>(tcur, nullptr, fpt(20) + (size_t)i * 4096, fpt(21) + (size_t)i * 64, hv, Nt);
        hipMemsetAsync(h_cf, 0, (size_t)Nn * H * 4, stream);
        cf_pin3_kernel<<<1024, 256, 0, stream>>>(pinf, hv, psrc, pdst,
                                                 fpt(22) + (size_t)i * 1024, fpt(23) + (size_t)i * 64,
                                                 fpt(24) + (size_t)i * 4096, fpt(25) + (size_t)i * 64,
                                                 h_cf, Np);

        // SAGE (near)
        gemm64_kernel<64, 2, false><<<1024, 256, 0, stream>>>(ncur, nullptr, fpt(28) + (size_t)i * 4096, fpt(29) + (size_t)i * 64, hp, Nn);
        hipMemsetAsync(h_ng, 0, (size_t)Nn * H * 4, stream);
        sage_edge2_kernel<<<(int)(((long long)Ne * 16 + 255) / 256), 256, 0, stream>>>(hp, ew3 + (size_t)i * Ne, esrc, edst, (unsigned int*)h_ng, Ne);

        // combine + activations
        combine3_kernel<<<640, 256, 0, stream>>>(h_cf, ncur, h_ng,
                                                 fpt(26) + (size_t)i * 4096, fpt(27) + (size_t)i * 64,
                                                 fpt(30) + (size_t)i * 4096, fpt(31) + (size_t)i * 4096,
                                                 fpt(32) + (size_t)i * 64,
                                                 nnew, Nn);
        float* t;
        t = ncur; ncur = nnew; nnew = t;
        t = tcur; tcur = tnew; tnew = t;
    }

    float* out = (float*)d_out;
    node_head3_kernel<<<640, 256, 0, stream>>>(in_node, ncur, fpt(33), fpt(34), fpt(35), fpt(36), fpt(37), fpt(38), out, Nn);
    net_head3_kernel<<<480, 256, 0, stream>>>(in_net, tcur, fpt(39), fpt(40), fpt(41), fpt(42), fpt(43), fpt(44), out + (size_t)Nn * T, Nt);
}

// Round 5
// 2796.788 us; speedup vs baseline: 5.2667x; 5.2667x over previous
//
#include <hip/hip_runtime.h>
#include <hip/hip_bf16.h>

#define DEV __device__ __forceinline__

DEV float lrelu_(float x){ return x > 0.f ? x : 0.01f * x; }
DEV float ssp_(float x){ float sp = fmaxf(x, 0.f) + log1pf(__expf(-fabsf(x))); return sp - 0.69314718055994530942f; }
DEV float sigm_(float x){ return 1.f / (1.f + __expf(-x)); }

DEV void fma44(float (&acc)[4][4], const float4 (&xa)[4], const float4 (&wa)[4])
{
    #pragma unroll
    for (int kk = 0; kk < 4; kk++) {
        #pragma unroll
        for (int i = 0; i < 4; i++) {
            float x = ((const float*)&xa[i])[kk];
            #pragma unroll
            for (int j = 0; j < 4; j++)
                acc[i][j] += x * ((const float*)&wa[kk])[j];
        }
    }
}

// ====== generic tiled GEMM: Y[N x 64] = act( (X .* scale?) @ W[K x 64] + b )  (ADD: Y += X@W) ====
// ACT: 0=none 1=lrelu 2=relu 3=ssp
template<int K, int ACT, bool SCALE, bool ADD>
__global__ __launch_bounds__(256) void gemm64_kernel(const float* __restrict__ X,
                                                     const float* __restrict__ scale,
                                                     const float* __restrict__ W,
                                                     const float* __restrict__ B,
                                                     float* __restrict__ Y, int nrows)
{
    constexpr int XS = K + 4;
    constexpr int KQ = K / 4;
    __shared__ float Ws[K * 64];
    __shared__ float bs[64];
    __shared__ float Xs[64 * XS];
    for (int i = threadIdx.x; i < K * 64; i += 256) Ws[i] = W[i];
    if (threadIdx.x < 64) bs[threadIdx.x] = ADD ? 0.f : B[threadIdx.x];
    const int tr = threadIdx.x >> 4, tc = threadIdx.x & 15;
    const int r0 = tr * 4, c0 = tc * 4;
    for (int base = blockIdx.x * 64; base < nrows; base += gridDim.x * 64) {
        __syncthreads();
        for (int i = threadIdx.x; i < 64 * KQ; i += 256) {
            int row = i / KQ, kq = (i % KQ) * 4;
            int g = base + row;
            float4 v = make_float4(0.f, 0.f, 0.f, 0.f);
            if (g < nrows) {
                v = *(const float4*)&X[(size_t)g * K + kq];
                if (SCALE) { float s = scale[g]; v.x *= s; v.y *= s; v.z *= s; v.w *= s; }
            }
            *(float4*)&Xs[row * XS + kq] = v;
        }
        __syncthreads();
        float acc[4][4];
        #pragma unroll
        for (int i = 0; i < 4; i++)
            #pragma unroll
            for (int j = 0; j < 4; j++) acc[i][j] = bs[c0 + j];
        #pragma unroll 4
        for (int kq = 0; kq < K; kq += 4) {
            float4 xa[4], wa[4];
            #pragma unroll
            for (int i = 0; i < 4; i++) xa[i] = *(const float4*)&Xs[(r0 + i) * XS + kq];
            #pragma unroll
            for (int j = 0; j < 4; j++) wa[j] = *(const float4*)&Ws[(kq + j) * 64 + c0];
            fma44(acc, xa, wa);
        }
        #pragma unroll
        for (int i = 0; i < 4; i++) {
            int g = base + r0 + i;
            if (g < nrows) {
                float4 o;
                float* op = (float*)&o;
                float4 prev = make_float4(0,0,0,0);
                if (ADD) prev = *(const float4*)&Y[(size_t)g * 64 + c0];
                #pragma unroll
                for (int j = 0; j < 4; j++) {
                    float a = acc[i][j] + ((const float*)&prev)[j];
                    if (ACT == 1) a = lrelu_(a);
                    else if (ACT == 2) a = fmaxf(a, 0.f);
                    else if (ACT == 3) a = ssp_(a);
                    op[j] = a;
                }
                *(float4*)&Y[(size_t)g * 64 + c0] = o;
            }
        }
    }
}

// ---------------- small scalar GEMV (pin encoder, C=16) ----------------
template<int K, int C, int ACT>
__global__ __launch_bounds__(256) void lin_kernel(const float* __restrict__ X,
                                                  const float* __restrict__ W,
                                                  const float* __restrict__ B,
                                                  float* __restrict__ Y, int nrows)
{
    constexpr int ROWS = 256 / C;
    __shared__ float Ws[K * C];
    __shared__ float bs[C];
    __shared__ float Xs[ROWS * K];
    for (int i = threadIdx.x; i < K * C; i += 256) Ws[i] = W[i];
    if (threadIdx.x < C) bs[threadIdx.x] = B[threadIdx.x];
    __syncthreads();
    const int r = threadIdx.x / C, c = threadIdx.x % C;
    for (int base = blockIdx.x * ROWS; base < nrows; base += gridDim.x * ROWS) {
        __syncthreads();
        for (int i = threadIdx.x; i < ROWS * K; i += 256) {
            int rr = base + i / K;
            Xs[i] = (rr < nrows) ? X[(size_t)rr * K + i % K] : 0.f;
        }
        __syncthreads();
        int row = base + r;
        if (row < nrows) {
            float acc = bs[c];
            #pragma unroll
            for (int k = 0; k < K; k++) acc += Xs[r * K + k] * Ws[k * C + c];
            if (ACT == 1) acc = lrelu_(acc);
            else if (ACT == 2) acc = fmaxf(acc, 0.f);
            Y[(size_t)row * C + c] = acc;
        }
    }
}

// ---------------- degrees ----------------
__global__ __launch_bounds__(256) void deg_kernel(const int* __restrict__ src, const int* __restrict__ dst,
                                                  int* __restrict__ degs, int* __restrict__ degd, int np)
{
    int p = blockIdx.x * 256 + threadIdx.x;
    if (p < np) { atomicAdd(&degs[src[p]], 1); atomicAdd(&degd[dst[p]], 1); }
}

__global__ __launch_bounds__(256) void norm_kernel(int* __restrict__ arr, int n)
{
    int i = blockIdx.x * 256 + threadIdx.x;
    if (i < n) {
        int v = arr[i]; if (v < 1) v = 1;
        arr[i] = __float_as_int(rsqrtf((float)v));
    }
}

// ---------------- edge weights for all 3 layers ----------------
__global__ __launch_bounds__(256) void edge_ew_kernel(const float* __restrict__ in_edge,
                                                      const float* __restrict__ elW, const float* __restrict__ elb,
                                                      const float* __restrict__ gW, const float* __restrict__ gb,
                                                      float* __restrict__ ew3, int ne)
{
    __shared__ float W[32], B[8], G[24], Gb[3];
    if (threadIdx.x < 32) W[threadIdx.x] = elW[threadIdx.x];
    if (threadIdx.x < 8)  B[threadIdx.x] = elb[threadIdx.x];
    if (threadIdx.x < 24) G[threadIdx.x] = gW[threadIdx.x];
    if (threadIdx.x < 3)  Gb[threadIdx.x] = gb[threadIdx.x];
    __syncthreads();
    for (int e = blockIdx.x * 256 + threadIdx.x; e < ne; e += gridDim.x * 256) {
        float4 x = *(const float4*)&in_edge[(size_t)e * 4];
        float ef[8];
        #pragma unroll
        for (int j = 0; j < 8; j++)
            ef[j] = lrelu_(B[j] + x.x * W[j] + x.y * W[8 + j] + x.z * W[16 + j] + x.w * W[24 + j]);
        #pragma unroll
        for (int i = 0; i < 3; i++) {
            float a = Gb[i];
            #pragma unroll
            for (int j = 0; j < 8; j++) a += ef[j] * G[i * 8 + j];
            ew3[(size_t)i * ne + e] = sigm_(a);
        }
    }
}

// ---------------- pins GraphConv scatter (1 lane = 1 channel) ----------------
__global__ __launch_bounds__(256) void pins_scatter(const float* __restrict__ nf, const float* __restrict__ snorm,
                                                    const int* __restrict__ src, const int* __restrict__ dst,
                                                    float* __restrict__ agg, int np)
{
    long long idx = (long long)blockIdx.x * 256 + threadIdx.x;
    int p = (int)(idx >> 6); if (p >= np) return;
    int c = (int)(idx & 63);
    int s = src[p], d = dst[p];
    unsafeAtomicAdd(&agg[(size_t)d * 64 + c], nf[(size_t)s * 64 + c] * snorm[s]);
}

// ---------------- CFConv fused, register-tiled, fused epilogue scatter ----------------
__global__ __launch_bounds__(256) void cf_pin3_kernel(const float* __restrict__ pinf, const float* __restrict__ hv,
                                                      const int* __restrict__ psrc, const int* __restrict__ pdst,
                                                      const float* __restrict__ W1, const float* __restrict__ B1,
                                                      const float* __restrict__ W2, const float* __restrict__ B2,
                                                      float* __restrict__ h_cf, int np)
{
    __shared__ float Ws1[16 * 64], Ws2[64 * 64], bs1[64], bs2[64];
    __shared__ float PF[64 * 20], T1[64 * 68];
    __shared__ int srcS[64], dstS[64];
    for (int i = threadIdx.x; i < 16 * 64; i += 256) Ws1[i] = W1[i];
    for (int i = threadIdx.x; i < 64 * 64; i += 256) Ws2[i] = W2[i];
    if (threadIdx.x < 64) { bs1[threadIdx.x] = B1[threadIdx.x]; bs2[threadIdx.x] = B2[threadIdx.x]; }
    const int tr = threadIdx.x >> 4, tc = threadIdx.x & 15;
    const int r0 = tr * 4, c0 = tc * 4;
    for (int base = blockIdx.x * 64; base < np; base += gridDim.x * 64) {
        __syncthreads();
        {
            int row = threadIdx.x >> 2, kq = (threadIdx.x & 3) * 4;
            int p = base + row;
            float4 v = make_float4(0.f, 0.f, 0.f, 0.f);
            if (p < np) v = *(const float4*)&pinf[(size_t)p * 16 + kq];
            *(float4*)&PF[row * 20 + kq] = v;
            if (threadIdx.x < 64) {
                int pp = base + threadIdx.x;
                srcS[threadIdx.x] = (pp < np) ? psrc[pp] : 0;
                dstS[threadIdx.x] = (pp < np) ? pdst[pp] : 0;
            }
        }
        __syncthreads();
        // GEMM1: T1 = ssp(PF @ W1 + b1), K=16
        {
            float acc[4][4];
            #pragma unroll
            for (int i = 0; i < 4; i++)
                #pragma unroll
                for (int j = 0; j < 4; j++) acc[i][j] = bs1[c0 + j];
            #pragma unroll
            for (int kq = 0; kq < 16; kq += 4) {
                float4 xa[4], wa[4];
                #pragma unroll
                for (int i = 0; i < 4; i++) xa[i] = *(const float4*)&PF[(r0 + i) * 20 + kq];
                #pragma unroll
                for (int j = 0; j < 4; j++) wa[j] = *(const float4*)&Ws1[(kq + j) * 64 + c0];
                fma44(acc, xa, wa);
            }
            #pragma unroll
            for (int i = 0; i < 4; i++) {
                float4 o; float* op = (float*)&o;
                #pragma unroll
                for (int j = 0; j < 4; j++) op[j] = ssp_(acc[i][j]);
                *(float4*)&T1[(r0 + i) * 68 + c0] = o;
            }
        }
        __syncthreads();
        // GEMM2 + fused scatter epilogue
        {
            float acc[4][4];
            #pragma unroll
            for (int i = 0; i < 4; i++)
                #pragma unroll
                for (int j = 0; j < 4; j++) acc[i][j] = bs2[c0 + j];
            #pragma unroll 4
            for (int kq = 0; kq < 64; kq += 4) {
                float4 xa[4], wa[4];
                #pragma unroll
                for (int i = 0; i < 4; i++) xa[i] = *(const float4*)&T1[(r0 + i) * 68 + kq];
                #pragma unroll
                for (int j = 0; j < 4; j++) wa[j] = *(const float4*)&Ws2[(kq + j) * 64 + c0];
                fma44(acc, xa, wa);
            }
            #pragma unroll
            for (int i = 0; i < 4; i++) {
                int row = r0 + i;
                int p = base + row;
                if (p < np) {
                    float4 hv4 = *(const float4*)&hv[(size_t)dstS[row] * 64 + c0];
                    float* cp = &h_cf[(size_t)srcS[row] * 64 + c0];
                    unsafeAtomicAdd(cp + 0, hv4.x * ssp_(acc[i][0]));
                    unsafeAtomicAdd(cp + 1, hv4.y * ssp_(acc[i][1]));
                    unsafeAtomicAdd(cp + 2, hv4.z * ssp_(acc[i][2]));
                    unsafeAtomicAdd(cp + 3, hv4.w * ssp_(acc[i][3]));
                }
            }
        }
    }
}

// ---------------- SAGE edge scatter-max (1 lane = 1 channel) ----------------
__global__ __launch_bounds__(256) void sage_edge_kernel(const float* __restrict__ hp, const float* __restrict__ ew,
                                                        const int* __restrict__ esrc, const int* __restrict__ edst,
                                                        unsigned int* __restrict__ h_ng, int ne)
{
    long long idx = (long long)blockIdx.x * 256 + threadIdx.x;
    int e = (int)(idx >> 6); if (e >= ne) return;
    int c = (int)(idx & 63);
    int s = esrc[e], d = edst[e];
    float v = hp[(size_t)s * 64 + c] * ew[e];   // v >= 0 always
    atomicMax(&h_ng[(size_t)d * 64 + c], __float_as_uint(v));
}

// ---------------- final elementwise: out = lrelu(max(t1, a2)) ----------------
__global__ __launch_bounds__(256) void final_combine_kernel(const float* __restrict__ t1, const float* __restrict__ a2,
                                                            float* __restrict__ out, int n4)
{
    int i = blockIdx.x * 256 + threadIdx.x;
    if (i >= n4) return;
    float4 a = ((const float4*)t1)[i];
    float4 b = ((const float4*)a2)[i];
    float4 o;
    o.x = lrelu_(fmaxf(a.x, b.x));
    o.y = lrelu_(fmaxf(a.y, b.y));
    o.z = lrelu_(fmaxf(a.z, b.z));
    o.w = lrelu_(fmaxf(a.w, b.w));
    ((float4*)out)[i] = o;
}

// ---------------- node head (32 rows/iter, grid-stride, 3-stage MLP) ----------------
__global__ __launch_bounds__(256) void node_head3_kernel(const float* __restrict__ in_node, const float* __restrict__ nf,
                                                         const float* __restrict__ W1, const float* __restrict__ B1,
                                                         const float* __restrict__ W2, const float* __restrict__ B2,
                                                         const float* __restrict__ W3, const float* __restrict__ B3,
                                                         float* __restrict__ out, int n)
{
    __shared__ float Ws1[80 * 64], Ws2[64 * 64], Ws3[64 * 4];
    __shared__ float bs1[64], bs2[64], bs3[4];
    __shared__ float Xs[32 * 84];       // reused as H2 (stride 68)
    __shared__ float H1[32 * 68];
    for (int i = threadIdx.x; i < 80 * 64; i += 256) Ws1[i] = W1[i];
    for (int i = threadIdx.x; i < 64 * 64; i += 256) Ws2[i] = W2[i];
    for (int i = threadIdx.x; i < 64 * 4; i += 256) Ws3[i] = W3[i];
    if (threadIdx.x < 64) { bs1[threadIdx.x] = B1[threadIdx.x]; bs2[threadIdx.x] = B2[threadIdx.x]; }
    if (threadIdx.x < 4) bs3[threadIdx.x] = B3[threadIdx.x];
    const int tr = threadIdx.x >> 4, tc = threadIdx.x & 15;
    const int r0 = tr * 2, c0 = tc * 4;
    for (int base = blockIdx.x * 32; base < n; base += gridDim.x * 32) {
        __syncthreads();
        for (int i = threadIdx.x; i < 32 * 4; i += 256) {
            int row = i >> 2, kq = (i & 3) * 4;
            int g = base + row;
            float4 v = make_float4(0,0,0,0);
            if (g < n) v = *(const float4*)&in_node[(size_t)g * 16 + kq];
            *(float4*)&Xs[row * 84 + kq] = v;
        }
        for (int i = threadIdx.x; i < 32 * 16; i += 256) {
            int row = i >> 4, kq = (i & 15) * 4;
            int g = base + row;
            float4 v = make_float4(0,0,0,0);
            if (g < n) v = *(const float4*)&nf[(size_t)g * 64 + kq];
            *(float4*)&Xs[row * 84 + 16 + kq] = v;
        }
        __syncthreads();
        {
            float acc[2][4];
            #pragma unroll
            for (int i = 0; i < 2; i++)
                #pragma unroll
                for (int j = 0; j < 4; j++) acc[i][j] = bs1[c0 + j];
            #pragma unroll 4
            for (int kq = 0; kq < 80; kq += 4) {
                float4 xa[2], wa[4];
                #pragma unroll
                for (int i = 0; i < 2; i++) xa[i] = *(const float4*)&Xs[(r0 + i) * 84 + kq];
                #pragma unroll
                for (int j = 0; j < 4; j++) wa[j] = *(const float4*)&Ws1[(kq + j) * 64 + c0];
                #pragma unroll
                for (int kk = 0; kk < 4; kk++)
                    #pragma unroll
                    for (int i = 0; i < 2; i++) {
                        float x = ((const float*)&xa[i])[kk];
                        #pragma unroll
                        for (int j = 0; j < 4; j++) acc[i][j] += x * ((const float*)&wa[kk])[j];
                    }
            }
            #pragma unroll
            for (int i = 0; i < 2; i++) {
                float4 o; float* op = (float*)&o;
                #pragma unroll
                for (int j = 0; j < 4; j++) op[j] = lrelu_(acc[i][j]);
                *(float4*)&H1[(r0 + i) * 68 + c0] = o;
            }
        }
        __syncthreads();
        float* H2 = Xs;
        {
            float acc[2][4];
            #pragma unroll
            for (int i = 0; i < 2; i++)
                #pragma unroll
                for (int j = 0; j < 4; j++) acc[i][j] = bs2[c0 + j];
            #pragma unroll 4
            for (int kq = 0; kq < 64; kq += 4) {
                float4 xa[2], wa[4];
                #pragma unroll
                for (int i = 0; i < 2; i++) xa[i] = *(const float4*)&H1[(r0 + i) * 68 + kq];
                #pragma unroll
                for (int j = 0; j < 4; j++) wa[j] = *(const float4*)&Ws2[(kq + j) * 64 + c0];
                #pragma unroll
                for (int kk = 0; kk < 4; kk++)
                    #pragma unroll
                    for (int i = 0; i < 2; i++) {
                        float x = ((const float*)&xa[i])[kk];
                        #pragma unroll
                        for (int j = 0; j < 4; j++) acc[i][j] += x * ((const float*)&wa[kk])[j];
                    }
            }
            __syncthreads();
            #pragma unroll
            for (int i = 0; i < 2; i++) {
                float4 o; float* op = (float*)&o;
                #pragma unroll
                for (int j = 0; j < 4; j++) op[j] = lrelu_(acc[i][j]);
                *(float4*)&H2[(r0 + i) * 68 + c0] = o;
            }
        }
        __syncthreads();
        if (threadIdx.x < 128) {
            int row = threadIdx.x >> 2, c = threadIdx.x & 3;
            float acc = bs3[c];
            #pragma unroll 4
            for (int kq = 0; kq < 64; kq += 4) {
                float4 h = *(const float4*)&H2[row * 68 + kq];
                #pragma unroll
                for (int j = 0; j < 4; j++) acc += ((const float*)&h)[j] * Ws3[(kq + j) * 4 + c];
            }
            int g = base + row;
            if (g < n) out[(size_t)g * 4 + c] = sigm_(acc);
        }
    }
}

// ---------------- net head (32 rows/iter, grid-stride, C_out=1) ----------------
__global__ __launch_bounds__(256) void net_head3_kernel(const float* __restrict__ in_net, const float* __restrict__ tf,
                                                        const float* __restrict__ W1, const float* __restrict__ B1,
                                                        const float* __restrict__ W2, const float* __restrict__ B2,
                                                        const float* __restrict__ W3, const float* __restrict__ B3,
                                                        float* __restrict__ out, int n)
{
    __shared__ float Ws1[72 * 64], Ws2[64 * 64], Ws3[64];
    __shared__ float bs1[64], bs2[64], bs3[1];
    __shared__ float Xs[32 * 76];       // reused as H2 (stride 68)
    __shared__ float H1[32 * 68];
    for (int i = threadIdx.x; i < 72 * 64; i += 256) Ws1[i] = W1[i];
    for (int i = threadIdx.x; i < 64 * 64; i += 256) Ws2[i] = W2[i];
    if (threadIdx.x < 64) { Ws3[threadIdx.x] = W3[threadIdx.x]; bs1[threadIdx.x] = B1[threadIdx.x]; bs2[threadIdx.x] = B2[threadIdx.x]; }
    if (threadIdx.x == 0) bs3[0] = B3[0];
    const int tr = threadIdx.x >> 4, tc = threadIdx.x & 15;
    const int r0 = tr * 2, c0 = tc * 4;
    for (int base = blockIdx.x * 32; base < n; base += gridDim.x * 32) {
        __syncthreads();
        for (int i = threadIdx.x; i < 32 * 2; i += 256) {
            int row = i >> 1, kq = (i & 1) * 4;
            int g = base + row;
            float4 v = make_float4(0,0,0,0);
            if (g < n) v = *(const float4*)&in_net[(size_t)g * 8 + kq];
            *(float4*)&Xs[row * 76 + kq] = v;
        }
        for (int i = threadIdx.x; i < 32 * 16; i += 256) {
            int row = i >> 4, kq = (i & 15) * 4;
            int g = base + row;
            float4 v = make_float4(0,0,0,0);
            if (g < n) v = *(const float4*)&tf[(size_t)g * 64 + kq];
            *(float4*)&Xs[row * 76 + 8 + kq] = v;
        }
        __syncthreads();
        {
            float acc[2][4];
            #pragma unroll
            for (int i = 0; i < 2; i++)
                #pragma unroll
                for (int j = 0; j < 4; j++) acc[i][j] = bs1[c0 + j];
            #pragma unroll 4
            for (int kq = 0; kq < 72; kq += 4) {
                float4 xa[2], wa[4];
                #pragma unroll
                for (int i = 0; i < 2; i++) xa[i] = *(const float4*)&Xs[(r0 + i) * 76 + kq];
                #pragma unroll
                for (int j = 0; j < 4; j++) wa[j] = *(const float4*)&Ws1[(kq + j) * 64 + c0];
                #pragma unroll
                for (int kk = 0; kk < 4; kk++)
                    #pragma unroll
                    for (int i = 0; i < 2; i++) {
                        float x = ((const float*)&xa[i])[kk];
                        #pragma unroll
                        for (int j = 0; j < 4; j++) acc[i][j] += x * ((const float*)&wa[kk])[j];
                    }
            }
            #pragma unroll
            for (int i = 0; i < 2; i++) {
                float4 o; float* op = (float*)&o;
                #pragma unroll
                for (int j = 0; j < 4; j++) op[j] = lrelu_(acc[i][j]);
                *(float4*)&H1[(r0 + i) * 68 + c0] = o;
            }
        }
        __syncthreads();
        float* H2 = Xs;
        {
            float acc[2][4];
            #pragma unroll
            for (int i = 0; i < 2; i++)
                #pragma unroll
                for (int j = 0; j < 4; j++) acc[i][j] = bs2[c0 + j];
            #pragma unroll 4
            for (int kq = 0; kq < 64; kq += 4) {
                float4 xa[2], wa[4];
                #pragma unroll
                for (int i = 0; i < 2; i++) xa[i] = *(const float4*)&H1[(r0 + i) * 68 + kq];
                #pragma unroll
                for (int j = 0; j < 4; j++) wa[j] = *(const float4*)&Ws2[(kq + j) * 64 + c0];
                #pragma unroll
                for (int kk = 0; kk < 4; kk++)
                    #pragma unroll
                    for (int i = 0; i < 2; i++) {
                        float x = ((const float*)&xa[i])[kk];
                        #pragma unroll
                        for (int j = 0; j < 4; j++) acc[i][j] += x * ((const float*)&wa[kk])[j];
                    }
            }
            __syncthreads();
            #pragma unroll
            for (int i = 0; i < 2; i++) {
                float4 o; float* op = (float*)&o;
                #pragma unroll
                for (int j = 0; j < 4; j++) op[j] = lrelu_(acc[i][j]);
                *(float4*)&H2[(r0 + i) * 68 + c0] = o;
            }
        }
        __syncthreads();
        if (threadIdx.x < 32) {
            int row = threadIdx.x;
            float acc = bs3[0];
            #pragma unroll 4
            for (int kq = 0; kq < 64; kq += 4) {
                float4 h = *(const float4*)&H2[row * 68 + kq];
                float4 w = *(const float4*)&Ws3[kq];
                acc += h.x * w.x + h.y * w.y + h.z * w.z + h.w * w.w;
            }
            int g = base + row;
            if (g < n) out[g] = sigm_(acc);
        }
    }
}

extern "C" void kernel_launch(void* const* d_in, const int* in_sizes, int n_in,
                              void* d_out, int out_size, void* d_ws, size_t ws_size,
                              hipStream_t stream)
{
    (void)in_sizes; (void)n_in; (void)out_size; (void)ws_size;
    constexpr int Nn = 100000, Nt = 30000, Np = 400000, Ne = 1000000;
    constexpr int H = 64, L = 3, T = 4;

    auto fpt = [&](int i){ return (const float*)d_in[i]; };
    auto ipt = [&](int i){ return (const int*)d_in[i]; };

    const float* in_node = fpt(0);
    const float* in_net  = fpt(1);
    const float* in_pin  = fpt(2);
    const float* in_edge = fpt(3);
    const int* psrc = ipt(4);
    const int* pdst = ipt(5);
    const int* esrc = ipt(6);
    const int* edst = ipt(7);

    float* ws = (float*)d_ws;
    size_t o = 0;
    auto alloc = [&](size_t nel){ float* p = ws + o; o += nel; return p; };
    float* node_a = alloc((size_t)Nn * H);
    float* node_b = alloc((size_t)Nn * H);
    float* net_a  = alloc((size_t)Nt * H);
    float* net_b  = alloc((size_t)Nt * H);
    float* agg    = alloc((size_t)Nt * H);
    float* hv     = alloc((size_t)Nt * H);
    float* pinf   = alloc((size_t)Np * 16);
    float* h_cf   = alloc((size_t)Nn * H);
    float* hp     = alloc((size_t)Nn * H);   // also reused as SAGE a2 accumulator
    float* h_ng   = alloc((size_t)Nn * H);
    float* t1     = alloc((size_t)Nn * H);   // CF branch pre-activation output
    float* ew3    = alloc((size_t)3 * Ne);
    float* snorm  = alloc((size_t)Nn);
    float* dnorm  = alloc((size_t)Nt);

    // degree norms
    hipMemsetAsync(snorm, 0, (size_t)Nn * 4, stream);
    hipMemsetAsync(dnorm, 0, (size_t)Nt * 4, stream);
    deg_kernel<<<(Np + 255) / 256, 256, 0, stream>>>(psrc, pdst, (int*)snorm, (int*)dnorm, Np);
    norm_kernel<<<(Nn + 255) / 256, 256, 0, stream>>>((int*)snorm, Nn);
    norm_kernel<<<(Nt + 255) / 256, 256, 0, stream>>>((int*)dnorm, Nt);

    // input encoders
    gemm64_kernel<16, 1, false, false><<<1024, 256, 0, stream>>>(in_node, nullptr, fpt(8),  fpt(9),  node_a, Nn);
    gemm64_kernel< 8, 1, false, false><<<469, 256, 0, stream>>>(in_net,  nullptr, fpt(10), fpt(11), net_a,  Nt);
    lin_kernel<8, 16, 1><<<1024, 256, 0, stream>>>(in_pin, fpt(12), fpt(13), pinf, Np);
    edge_ew_kernel<<<2048, 256, 0, stream>>>(in_edge, fpt(14), fpt(15), fpt(16), fpt(17), ew3, Ne);

    float* ncur = node_a; float* nnew = node_b;
    float* tcur = net_a;  float* tnew = net_b;

    for (int i = 0; i < L; i++) {
        // pins GraphConv (node -> net)
        hipMemsetAsync(agg, 0, (size_t)Nt * H * 4, stream);
        pins_scatter<<<(int)(((long long)Np * 64 + 255) / 256), 256, 0, stream>>>(ncur, snorm, psrc, pdst, agg, Np);
        gemm64_kernel<64, 1, true, false><<<469, 256, 0, stream>>>(agg, dnorm, fpt(18) + (size_t)i * 4096, fpt(19) + (size_t)i * 64, tnew, Nt);

        // CFConv (net -> node)
        gemm64_kernel<64, 0, false, false><<<469, 256, 0, stream>>>(tcur, nullptr, fpt(20) + (size_t)i * 4096, fpt(21) + (size_t)i * 64, hv, Nt);
        hipMemsetAsync(h_cf, 0, (size_t)Nn * H * 4, stream);
        cf_pin3_kernel<<<1024, 256, 0, stream>>>(pinf, hv, psrc, pdst,
                                                 fpt(22) + (size_t)i * 1024, fpt(23) + (size_t)i * 64,
                                                 fpt(24) + (size_t)i * 4096, fpt(25) + (size_t)i * 64,
                                                 h_cf, Np);

        // SAGE (near): hp = relu(ncur @ pool + b), scatter-max into h_ng
        gemm64_kernel<64, 2, false, false><<<1024, 256, 0, stream>>>(ncur, nullptr, fpt(28) + (size_t)i * 4096, fpt(29) + (size_t)i * 64, hp, Nn);
        hipMemsetAsync(h_ng, 0, (size_t)Nn * H * 4, stream);
        sage_edge_kernel<<<(int)(((long long)Ne * 64 + 255) / 256), 256, 0, stream>>>(hp, ew3 + (size_t)i * Ne, esrc, edst, (unsigned int*)h_ng, Ne);

        // combine via three gemm64 + elementwise:
        // hp (reused) = ncur @ sage_self + sage_bias;  hp += h_ng @ sage_neigh
        gemm64_kernel<64, 0, false, false><<<1024, 256, 0, stream>>>(ncur, nullptr, fpt(30) + (size_t)i * 4096, fpt(32) + (size_t)i * 64, hp, Nn);
        gemm64_kernel<64, 0, false, true><<<1024, 256, 0, stream>>>(h_ng, nullptr, fpt(31) + (size_t)i * 4096, fpt(32) + (size_t)i * 64, hp, Nn);
        // t1 = ssp(h_cf @ cf_out + cf_out_b)
        gemm64_kernel<64, 3, false, false><<<1024, 256, 0, stream>>>(h_cf, nullptr, fpt(26) + (size_t)i * 4096, fpt(27) + (size_t)i * 64, t1, Nn);
        // nnew = lrelu(max(t1, hp))
        final_combine_kernel<<<(Nn * 16 + 255) / 256, 256, 0, stream>>>(t1, hp, nnew, Nn * 16);

        float* t;
        t = ncur; ncur = nnew; nnew = t;
        t = tcur; tcur = tnew; tnew = t;
    }

    float* out = (float*)d_out;
    node_head3_kernel<<<640, 256, 0, stream>>>(in_node, ncur, fpt(33), fpt(34), fpt(35), fpt(36), fpt(37), fpt(38), out, Nn);
    net_head3_kernel<<<480, 256, 0, stream>>>(in_net, tcur, fpt(39), fpt(40), fpt(41), fpt(42), fpt(43), fpt(44), out + (size_t)Nn * T, Nt);
}

// Round 6
// 2027.176 us; speedup vs baseline: 7.2662x; 1.3796x over previous
//
#include <hip/hip_runtime.h>
#include <hip/hip_bf16.h>

#define DEV __device__ __forceinline__

DEV float lrelu_(float x){ return x > 0.f ? x : 0.01f * x; }
DEV float ssp_(float x){ return fmaxf(x, 0.f) + __logf(1.f + __expf(-fabsf(x))) - 0.69314718055994530942f; }
DEV float sigm_(float x){ return 1.f / (1.f + __expf(-x)); }

DEV void fma44(float (&acc)[4][4], const float4 (&xa)[4], const float4 (&wa)[4])
{
    #pragma unroll
    for (int kk = 0; kk < 4; kk++) {
        #pragma unroll
        for (int i = 0; i < 4; i++) {
            float x = ((const float*)&xa[i])[kk];
            #pragma unroll
            for (int j = 0; j < 4; j++)
                acc[i][j] += x * ((const float*)&wa[kk])[j];
        }
    }
}

// ====== generic tiled GEMM: Y[N x 64] = act( (X .* scale?) @ W[K x 64] + b ) ====
// ACT: 0=none 1=lrelu 2=relu 3=ssp 4=lrelu(max(ssp(acc+b), P))   ADD: acc += P
template<int K, int ACT, bool SCALE, bool ADD>
__global__ __launch_bounds__(256) void gemm64_kernel(const float* __restrict__ X,
                                                     const float* __restrict__ scale,
                                                     const float* __restrict__ W,
                                                     const float* __restrict__ B,
                                                     const float* __restrict__ P,
                                                     float* __restrict__ Y, int nrows)
{
    constexpr int XS = K + 4;
    constexpr int KQ = K / 4;
    __shared__ float Ws[K * 64];
    __shared__ float bs[64];
    __shared__ float Xs[64 * XS];
    for (int i = threadIdx.x; i < K * 64; i += 256) Ws[i] = W[i];
    if (threadIdx.x < 64) bs[threadIdx.x] = ADD ? 0.f : B[threadIdx.x];
    const int tr = threadIdx.x >> 4, tc = threadIdx.x & 15;
    const int r0 = tr * 4, c0 = tc * 4;
    for (int base = blockIdx.x * 64; base < nrows; base += gridDim.x * 64) {
        __syncthreads();
        for (int i = threadIdx.x; i < 64 * KQ; i += 256) {
            int row = i / KQ, kq = (i % KQ) * 4;
            int g = base + row;
            float4 v = make_float4(0.f, 0.f, 0.f, 0.f);
            if (g < nrows) {
                v = *(const float4*)&X[(size_t)g * K + kq];
                if (SCALE) { float s = scale[g]; v.x *= s; v.y *= s; v.z *= s; v.w *= s; }
            }
            *(float4*)&Xs[row * XS + kq] = v;
        }
        __syncthreads();
        float acc[4][4];
        #pragma unroll
        for (int i = 0; i < 4; i++)
            #pragma unroll
            for (int j = 0; j < 4; j++) acc[i][j] = bs[c0 + j];
        #pragma unroll 4
        for (int kq = 0; kq < K; kq += 4) {
            float4 xa[4], wa[4];
            #pragma unroll
            for (int i = 0; i < 4; i++) xa[i] = *(const float4*)&Xs[(r0 + i) * XS + kq];
            #pragma unroll
            for (int j = 0; j < 4; j++) wa[j] = *(const float4*)&Ws[(kq + j) * 64 + c0];
            fma44(acc, xa, wa);
        }
        #pragma unroll
        for (int i = 0; i < 4; i++) {
            int g = base + r0 + i;
            if (g < nrows) {
                float4 prev = make_float4(0,0,0,0);
                if (ADD || ACT == 4) prev = *(const float4*)&P[(size_t)g * 64 + c0];
                float4 o;
                float* op = (float*)&o;
                #pragma unroll
                for (int j = 0; j < 4; j++) {
                    float a = acc[i][j];
                    if (ADD) a += ((const float*)&prev)[j];
                    if (ACT == 1) a = lrelu_(a);
                    else if (ACT == 2) a = fmaxf(a, 0.f);
                    else if (ACT == 3) a = ssp_(a);
                    else if (ACT == 4) a = lrelu_(fmaxf(ssp_(a), ((const float*)&prev)[j]));
                    op[j] = a;
                }
                *(float4*)&Y[(size_t)g * 64 + c0] = o;
            }
        }
    }
}

// ---------------- small scalar GEMV (pin encoder, C=16) ----------------
template<int K, int C, int ACT>
__global__ __launch_bounds__(256) void lin_kernel(const float* __restrict__ X,
                                                  const float* __restrict__ W,
                                                  const float* __restrict__ B,
                                                  float* __restrict__ Y, int nrows)
{
    constexpr int ROWS = 256 / C;
    __shared__ float Ws[K * C];
    __shared__ float bs[C];
    __shared__ float Xs[ROWS * K];
    for (int i = threadIdx.x; i < K * C; i += 256) Ws[i] = W[i];
    if (threadIdx.x < C) bs[threadIdx.x] = B[threadIdx.x];
    __syncthreads();
    const int r = threadIdx.x / C, c = threadIdx.x % C;
    for (int base = blockIdx.x * ROWS; base < nrows; base += gridDim.x * ROWS) {
        __syncthreads();
        for (int i = threadIdx.x; i < ROWS * K; i += 256) {
            int rr = base + i / K;
            Xs[i] = (rr < nrows) ? X[(size_t)rr * K + i % K] : 0.f;
        }
        __syncthreads();
        int row = base + r;
        if (row < nrows) {
            float acc = bs[c];
            #pragma unroll
            for (int k = 0; k < K; k++) acc += Xs[r * K + k] * Ws[k * C + c];
            if (ACT == 1) acc = lrelu_(acc);
            else if (ACT == 2) acc = fmaxf(acc, 0.f);
            Y[(size_t)row * C + c] = acc;
        }
    }
}

// ---------------- degrees ----------------
__global__ __launch_bounds__(256) void deg_kernel(const int* __restrict__ src, const int* __restrict__ dst,
                                                  int* __restrict__ degs, int* __restrict__ degd, int np)
{
    int p = blockIdx.x * 256 + threadIdx.x;
    if (p < np) { atomicAdd(&degs[src[p]], 1); atomicAdd(&degd[dst[p]], 1); }
}

__global__ __launch_bounds__(256) void norm_kernel(int* __restrict__ arr, int n)
{
    int i = blockIdx.x * 256 + threadIdx.x;
    if (i < n) {
        int v = arr[i]; if (v < 1) v = 1;
        arr[i] = __float_as_int(rsqrtf((float)v));
    }
}

// ---------------- edge weights for all 3 layers ----------------
__global__ __launch_bounds__(256) void edge_ew_kernel(const float* __restrict__ in_edge,
                                                      const float* __restrict__ elW, const float* __restrict__ elb,
                                                      const float* __restrict__ gW, const float* __restrict__ gb,
                                                      float* __restrict__ ew3, int ne)
{
    __shared__ float W[32], B[8], G[24], Gb[3];
    if (threadIdx.x < 32) W[threadIdx.x] = elW[threadIdx.x];
    if (threadIdx.x < 8)  B[threadIdx.x] = elb[threadIdx.x];
    if (threadIdx.x < 24) G[threadIdx.x] = gW[threadIdx.x];
    if (threadIdx.x < 3)  Gb[threadIdx.x] = gb[threadIdx.x];
    __syncthreads();
    for (int e = blockIdx.x * 256 + threadIdx.x; e < ne; e += gridDim.x * 256) {
        float4 x = *(const float4*)&in_edge[(size_t)e * 4];
        float ef[8];
        #pragma unroll
        for (int j = 0; j < 8; j++)
            ef[j] = lrelu_(B[j] + x.x * W[j] + x.y * W[8 + j] + x.z * W[16 + j] + x.w * W[24 + j]);
        #pragma unroll
        for (int i = 0; i < 3; i++) {
            float a = Gb[i];
            #pragma unroll
            for (int j = 0; j < 8; j++) a += ef[j] * G[i * 8 + j];
            ew3[(size_t)i * ne + e] = sigm_(a);
        }
    }
}

// ---------------- pins GraphConv scatter (1 lane = 1 channel, dense per-row atomics) -------------
__global__ __launch_bounds__(256) void pins_scatter(const float* __restrict__ nf, const float* __restrict__ snorm,
                                                    const int* __restrict__ src, const int* __restrict__ dst,
                                                    float* __restrict__ agg, int np)
{
    long long idx = (long long)blockIdx.x * 256 + threadIdx.x;
    int p = (int)(idx >> 6); if (p >= np) return;
    int c = (int)(idx & 63);
    int s = src[p], d = dst[p];
    unsafeAtomicAdd(&agg[(size_t)d * 64 + c], nf[(size_t)s * 64 + c] * snorm[s]);
}

// ---------------- CFConv fused: GEMMs in LDS, dense wave-per-row scatter ----------------
__global__ __launch_bounds__(256) void cf_pin4_kernel(const float* __restrict__ pinf, const float* __restrict__ hv,
                                                      const int* __restrict__ psrc, const int* __restrict__ pdst,
                                                      const float* __restrict__ W1, const float* __restrict__ B1,
                                                      const float* __restrict__ W2, const float* __restrict__ B2,
                                                      float* __restrict__ h_cf, int np)
{
    __shared__ float Ws1[16 * 64], Ws2[64 * 64], bs1[64], bs2[64];
    __shared__ float PF[64 * 20];
    __shared__ float T1[64 * 68];        // reused as HE after GEMM2
    __shared__ int srcS[64], dstS[64];
    for (int i = threadIdx.x; i < 16 * 64; i += 256) Ws1[i] = W1[i];
    for (int i = threadIdx.x; i < 64 * 64; i += 256) Ws2[i] = W2[i];
    if (threadIdx.x < 64) { bs1[threadIdx.x] = B1[threadIdx.x]; bs2[threadIdx.x] = B2[threadIdx.x]; }
    const int tr = threadIdx.x >> 4, tc = threadIdx.x & 15;
    const int r0 = tr * 4, c0 = tc * 4;
    const int lane = threadIdx.x & 63, wv = threadIdx.x >> 6;
    for (int base = blockIdx.x * 64; base < np; base += gridDim.x * 64) {
        __syncthreads();   // protect LDS from previous iteration's readers
        {
            int row = threadIdx.x >> 2, kq = (threadIdx.x & 3) * 4;
            int p = base + row;
            float4 v = make_float4(0.f, 0.f, 0.f, 0.f);
            if (p < np) v = *(const float4*)&pinf[(size_t)p * 16 + kq];
            *(float4*)&PF[row * 20 + kq] = v;
            if (threadIdx.x < 64) {
                int pp = base + threadIdx.x;
                srcS[threadIdx.x] = (pp < np) ? psrc[pp] : 0;
                dstS[threadIdx.x] = (pp < np) ? pdst[pp] : 0;
            }
        }
        __syncthreads();
        // GEMM1: T1 = ssp(PF @ W1 + b1), K=16
        {
            float acc[4][4];
            #pragma unroll
            for (int i = 0; i < 4; i++)
                #pragma unroll
                for (int j = 0; j < 4; j++) acc[i][j] = bs1[c0 + j];
            #pragma unroll
            for (int kq = 0; kq < 16; kq += 4) {
                float4 xa[4], wa[4];
                #pragma unroll
                for (int i = 0; i < 4; i++) xa[i] = *(const float4*)&PF[(r0 + i) * 20 + kq];
                #pragma unroll
                for (int j = 0; j < 4; j++) wa[j] = *(const float4*)&Ws1[(kq + j) * 64 + c0];
                fma44(acc, xa, wa);
            }
            #pragma unroll
            for (int i = 0; i < 4; i++) {
                float4 o; float* op = (float*)&o;
                #pragma unroll
                for (int j = 0; j < 4; j++) op[j] = ssp_(acc[i][j]);
                *(float4*)&T1[(r0 + i) * 68 + c0] = o;
            }
        }
        __syncthreads();
        // GEMM2: HE = ssp(T1 @ W2 + b2), K=64 ; HE overwrites T1 (write-after-read, guarded)
        {
            float acc[4][4];
            #pragma unroll
            for (int i = 0; i < 4; i++)
                #pragma unroll
                for (int j = 0; j < 4; j++) acc[i][j] = bs2[c0 + j];
            #pragma unroll 4
            for (int kq = 0; kq < 64; kq += 4) {
                float4 xa[4], wa[4];
                #pragma unroll
                for (int i = 0; i < 4; i++) xa[i] = *(const float4*)&T1[(r0 + i) * 68 + kq];
                #pragma unroll
                for (int j = 0; j < 4; j++) wa[j] = *(const float4*)&Ws2[(kq + j) * 64 + c0];
                fma44(acc, xa, wa);
            }
            __syncthreads();   // all T1 reads complete
            #pragma unroll
            for (int i = 0; i < 4; i++) {
                float4 o; float* op = (float*)&o;
                #pragma unroll
                for (int j = 0; j < 4; j++) op[j] = ssp_(acc[i][j]);
                *(float4*)&T1[(r0 + i) * 68 + c0] = o;
            }
        }
        __syncthreads();
        // scatter: one wave handles one pin-row at a time; 64 lanes = 64 contiguous channels
        #pragma unroll 4
        for (int i = 0; i < 16; i++) {
            int pl = wv * 16 + i;
            int p = base + pl;
            if (p < np) {
                float m = hv[(size_t)dstS[pl] * 64 + lane] * T1[pl * 68 + lane];
                unsafeAtomicAdd(&h_cf[(size_t)srcS[pl] * 64 + lane], m);
            }
        }
    }
}

// ---------------- SAGE edge scatter-max (1 lane = 1 channel) ----------------
__global__ __launch_bounds__(256) void sage_edge_kernel(const float* __restrict__ hp, const float* __restrict__ ew,
                                                        const int* __restrict__ esrc, const int* __restrict__ edst,
                                                        unsigned int* __restrict__ h_ng, int ne)
{
    long long idx = (long long)blockIdx.x * 256 + threadIdx.x;
    int e = (int)(idx >> 6); if (e >= ne) return;
    int c = (int)(idx & 63);
    int s = esrc[e], d = edst[e];
    float v = hp[(size_t)s * 64 + c] * ew[e];   // v >= 0 always
    atomicMax(&h_ng[(size_t)d * 64 + c], __float_as_uint(v));
}

// ---------------- node head (32 rows/iter, grid-stride, 3-stage MLP) ----------------
__global__ __launch_bounds__(256) void node_head3_kernel(const float* __restrict__ in_node, const float* __restrict__ nf,
                                                         const float* __restrict__ W1, const float* __restrict__ B1,
                                                         const float* __restrict__ W2, const float* __restrict__ B2,
                                                         const float* __restrict__ W3, const float* __restrict__ B3,
                                                         float* __restrict__ out, int n)
{
    __shared__ float Ws1[80 * 64], Ws2[64 * 64], Ws3[64 * 4];
    __shared__ float bs1[64], bs2[64], bs3[4];
    __shared__ float Xs[32 * 84];       // reused as H2 (stride 68)
    __shared__ float H1[32 * 68];
    for (int i = threadIdx.x; i < 80 * 64; i += 256) Ws1[i] = W1[i];
    for (int i = threadIdx.x; i < 64 * 64; i += 256) Ws2[i] = W2[i];
    for (int i = threadIdx.x; i < 64 * 4; i += 256) Ws3[i] = W3[i];
    if (threadIdx.x < 64) { bs1[threadIdx.x] = B1[threadIdx.x]; bs2[threadIdx.x] = B2[threadIdx.x]; }
    if (threadIdx.x < 4) bs3[threadIdx.x] = B3[threadIdx.x];
    const int tr = threadIdx.x >> 4, tc = threadIdx.x & 15;
    const int r0 = tr * 2, c0 = tc * 4;
    for (int base = blockIdx.x * 32; base < n; base += gridDim.x * 32) {
        __syncthreads();
        for (int i = threadIdx.x; i < 32 * 4; i += 256) {
            int row = i >> 2, kq = (i & 3) * 4;
            int g = base + row;
            float4 v = make_float4(0,0,0,0);
            if (g < n) v = *(const float4*)&in_node[(size_t)g * 16 + kq];
            *(float4*)&Xs[row * 84 + kq] = v;
        }
        for (int i = threadIdx.x; i < 32 * 16; i += 256) {
            int row = i >> 4, kq = (i & 15) * 4;
            int g = base + row;
            float4 v = make_float4(0,0,0,0);
            if (g < n) v = *(const float4*)&nf[(size_t)g * 64 + kq];
            *(float4*)&Xs[row * 84 + 16 + kq] = v;
        }
        __syncthreads();
        {
            float acc[2][4];
            #pragma unroll
            for (int i = 0; i < 2; i++)
                #pragma unroll
                for (int j = 0; j < 4; j++) acc[i][j] = bs1[c0 + j];
            #pragma unroll 4
            for (int kq = 0; kq < 80; kq += 4) {
                float4 xa[2], wa[4];
                #pragma unroll
                for (int i = 0; i < 2; i++) xa[i] = *(const float4*)&Xs[(r0 + i) * 84 + kq];
                #pragma unroll
                for (int j = 0; j < 4; j++) wa[j] = *(const float4*)&Ws1[(kq + j) * 64 + c0];
                #pragma unroll
                for (int kk = 0; kk < 4; kk++)
                    #pragma unroll
                    for (int i = 0; i < 2; i++) {
                        float x = ((const float*)&xa[i])[kk];
                        #pragma unroll
                        for (int j = 0; j < 4; j++) acc[i][j] += x * ((const float*)&wa[kk])[j];
                    }
            }
            #pragma unroll
            for (int i = 0; i < 2; i++) {
                float4 o; float* op = (float*)&o;
                #pragma unroll
                for (int j = 0; j < 4; j++) op[j] = lrelu_(acc[i][j]);
                *(float4*)&H1[(r0 + i) * 68 + c0] = o;
            }
        }
        __syncthreads();
        float* H2 = Xs;
        {
            float acc[2][4];
            #pragma unroll
            for (int i = 0; i < 2; i++)
                #pragma unroll
                for (int j = 0; j < 4; j++) acc[i][j] = bs2[c0 + j];
            #pragma unroll 4
            for (int kq = 0; kq < 64; kq += 4) {
                float4 xa[2], wa[4];
                #pragma unroll
                for (int i = 0; i < 2; i++) xa[i] = *(const float4*)&H1[(r0 + i) * 68 + kq];
                #pragma unroll
                for (int j = 0; j < 4; j++) wa[j] = *(const float4*)&Ws2[(kq + j) * 64 + c0];
                #pragma unroll
                for (int kk = 0; kk < 4; kk++)
                    #pragma unroll
                    for (int i = 0; i < 2; i++) {
                        float x = ((const float*)&xa[i])[kk];
                        #pragma unroll
                        for (int j = 0; j < 4; j++) acc[i][j] += x * ((const float*)&wa[kk])[j];
                    }
            }
            __syncthreads();
            #pragma unroll
            for (int i = 0; i < 2; i++) {
                float4 o; float* op = (float*)&o;
                #pragma unroll
                for (int j = 0; j < 4; j++) op[j] = lrelu_(acc[i][j]);
                *(float4*)&H2[(r0 + i) * 68 + c0] = o;
            }
        }
        __syncthreads();
        if (threadIdx.x < 128) {
            int row = threadIdx.x >> 2, c = threadIdx.x & 3;
            float acc = bs3[c];
            #pragma unroll 4
            for (int kq = 0; kq < 64; kq += 4) {
                float4 h = *(const float4*)&H2[row * 68 + kq];
                #pragma unroll
                for (int j = 0; j < 4; j++) acc += ((const float*)&h)[j] * Ws3[(kq + j) * 4 + c];
            }
            int g = base + row;
            if (g < n) out[(size_t)g * 4 + c] = sigm_(acc);
        }
    }
}

// ---------------- net head (32 rows/iter, grid-stride, C_out=1) ----------------
__global__ __launch_bounds__(256) void net_head3_kernel(const float* __restrict__ in_net, const float* __restrict__ tf,
                                                        const float* __restrict__ W1, const float* __restrict__ B1,
                                                        const float* __restrict__ W2, const float* __restrict__ B2,
                                                        const float* __restrict__ W3, const float* __restrict__ B3,
                                                        float* __restrict__ out, int n)
{
    __shared__ float Ws1[72 * 64], Ws2[64 * 64], Ws3[64];
    __shared__ float bs1[64], bs2[64], bs3[1];
    __shared__ float Xs[32 * 76];       // reused as H2 (stride 68)
    __shared__ float H1[32 * 68];
    for (int i = threadIdx.x; i < 72 * 64; i += 256) Ws1[i] = W1[i];
    for (int i = threadIdx.x; i < 64 * 64; i += 256) Ws2[i] = W2[i];
    if (threadIdx.x < 64) { Ws3[threadIdx.x] = W3[threadIdx.x]; bs1[threadIdx.x] = B1[threadIdx.x]; bs2[threadIdx.x] = B2[threadIdx.x]; }
    if (threadIdx.x == 0) bs3[0] = B3[0];
    const int tr = threadIdx.x >> 4, tc = threadIdx.x & 15;
    const int r0 = tr * 2, c0 = tc * 4;
    for (int base = blockIdx.x * 32; base < n; base += gridDim.x * 32) {
        __syncthreads();
        for (int i = threadIdx.x; i < 32 * 2; i += 256) {
            int row = i >> 1, kq = (i & 1) * 4;
            int g = base + row;
            float4 v = make_float4(0,0,0,0);
            if (g < n) v = *(const float4*)&in_net[(size_t)g * 8 + kq];
            *(float4*)&Xs[row * 76 + kq] = v;
        }
        for (int i = threadIdx.x; i < 32 * 16; i += 256) {
            int row = i >> 4, kq = (i & 15) * 4;
            int g = base + row;
            float4 v = make_float4(0,0,0,0);
            if (g < n) v = *(const float4*)&tf[(size_t)g * 64 + kq];
            *(float4*)&Xs[row * 76 + 8 + kq] = v;
        }
        __syncthreads();
        {
            float acc[2][4];
            #pragma unroll
            for (int i = 0; i < 2; i++)
                #pragma unroll
                for (int j = 0; j < 4; j++) acc[i][j] = bs1[c0 + j];
            #pragma unroll 4
            for (int kq = 0; kq < 72; kq += 4) {
                float4 xa[2], wa[4];
                #pragma unroll
                for (int i = 0; i < 2; i++) xa[i] = *(const float4*)&Xs[(r0 + i) * 76 + kq];
                #pragma unroll
                for (int j = 0; j < 4; j++) wa[j] = *(const float4*)&Ws1[(kq + j) * 64 + c0];
                #pragma unroll
                for (int kk = 0; kk < 4; kk++)
                    #pragma unroll
                    for (int i = 0; i < 2; i++) {
                        float x = ((const float*)&xa[i])[kk];
                        #pragma unroll
                        for (int j = 0; j < 4; j++) acc[i][j] += x * ((const float*)&wa[kk])[j];
                    }
            }
            #pragma unroll
            for (int i = 0; i < 2; i++) {
                float4 o; float* op = (float*)&o;
                #pragma unroll
                for (int j = 0; j < 4; j++) op[j] = lrelu_(acc[i][j]);
                *(float4*)&H1[(r0 + i) * 68 + c0] = o;
            }
        }
        __syncthreads();
        float* H2 = Xs;
        {
            float acc[2][4];
            #pragma unroll
            for (int i = 0; i < 2; i++)
                #pragma unroll
                for (int j = 0; j < 4; j++) acc[i][j] = bs2[c0 + j];
            #pragma unroll 4
            for (int kq = 0; kq < 64; kq += 4) {
                float4 xa[2], wa[4];
                #pragma unroll
                for (int i = 0; i < 2; i++) xa[i] = *(const float4*)&H1[(r0 + i) * 68 + kq];
                #pragma unroll
                for (int j = 0; j < 4; j++) wa[j] = *(const float4*)&Ws2[(kq + j) * 64 + c0];
                #pragma unroll
                for (int kk = 0; kk < 4; kk++)
                    #pragma unroll
                    for (int i = 0; i < 2; i++) {
                        float x = ((const float*)&xa[i])[kk];
                        #pragma unroll
                        for (int j = 0; j < 4; j++) acc[i][j] += x * ((const float*)&wa[kk])[j];
                    }
            }
            __syncthreads();
            #pragma unroll
            for (int i = 0; i < 2; i++) {
                float4 o; float* op = (float*)&o;
                #pragma unroll
                for (int j = 0; j < 4; j++) op[j] = lrelu_(acc[i][j]);
                *(float4*)&H2[(r0 + i) * 68 + c0] = o;
            }
        }
        __syncthreads();
        if (threadIdx.x < 32) {
            int row = threadIdx.x;
            float acc = bs3[0];
            #pragma unroll 4
            for (int kq = 0; kq < 64; kq += 4) {
                float4 h = *(const float4*)&H2[row * 68 + kq];
                float4 w = *(const float4*)&Ws3[kq];
                acc += h.x * w.x + h.y * w.y + h.z * w.z + h.w * w.w;
            }
            int g = base + row;
            if (g < n) out[g] = sigm_(acc);
        }
    }
}

extern "C" void kernel_launch(void* const* d_in, const int* in_sizes, int n_in,
                              void* d_out, int out_size, void* d_ws, size_t ws_size,
                              hipStream_t stream)
{
    (void)in_sizes; (void)n_in; (void)out_size; (void)ws_size;
    constexpr int Nn = 100000, Nt = 30000, Np = 400000, Ne = 1000000;
    constexpr int H = 64, L = 3, T = 4;

    auto fpt = [&](int i){ return (const float*)d_in[i]; };
    auto ipt = [&](int i){ return (const int*)d_in[i]; };

    const float* in_node = fpt(0);
    const float* in_net  = fpt(1);
    const float* in_pin  = fpt(2);
    const float* in_edge = fpt(3);
    const int* psrc = ipt(4);
    const int* pdst = ipt(5);
    const int* esrc = ipt(6);
    const int* edst = ipt(7);

    float* ws = (float*)d_ws;
    size_t o = 0;
    auto alloc = [&](size_t nel){ float* p = ws + o; o += nel; return p; };
    float* node_a = alloc((size_t)Nn * H);
    float* node_b = alloc((size_t)Nn * H);
    float* net_a  = alloc((size_t)Nt * H);
    float* net_b  = alloc((size_t)Nt * H);
    float* agg    = alloc((size_t)Nt * H);
    float* hv     = alloc((size_t)Nt * H);
    float* pinf   = alloc((size_t)Np * 16);
    float* h_cf   = alloc((size_t)Nn * H);
    float* hp     = alloc((size_t)Nn * H);   // SAGE linear accumulator
    float* h_ng   = alloc((size_t)Nn * H);
    float* ew3    = alloc((size_t)3 * Ne);
    float* snorm  = alloc((size_t)Nn);
    float* dnorm  = alloc((size_t)Nt);

    // degree norms
    hipMemsetAsync(snorm, 0, (size_t)Nn * 4, stream);
    hipMemsetAsync(dnorm, 0, (size_t)Nt * 4, stream);
    deg_kernel<<<(Np + 255) / 256, 256, 0, stream>>>(psrc, pdst, (int*)snorm, (int*)dnorm, Np);
    norm_kernel<<<(Nn + 255) / 256, 256, 0, stream>>>((int*)snorm, Nn);
    norm_kernel<<<(Nt + 255) / 256, 256, 0, stream>>>((int*)dnorm, Nt);

    // input encoders
    gemm64_kernel<16, 1, false, false><<<1024, 256, 0, stream>>>(in_node, nullptr, fpt(8),  fpt(9),  nullptr, node_a, Nn);
    gemm64_kernel< 8, 1, false, false><<<469, 256, 0, stream>>>(in_net,  nullptr, fpt(10), fpt(11), nullptr, net_a,  Nt);
    lin_kernel<8, 16, 1><<<1024, 256, 0, stream>>>(in_pin, fpt(12), fpt(13), pinf, Np);
    edge_ew_kernel<<<2048, 256, 0, stream>>>(in_edge, fpt(14), fpt(15), fpt(16), fpt(17), ew3, Ne);

    float* ncur = node_a; float* nnew = node_b;
    float* tcur = net_a;  float* tnew = net_b;

    for (int i = 0; i < L; i++) {
        // pins GraphConv (node -> net)
        hipMemsetAsync(agg, 0, (size_t)Nt * H * 4, stream);
        pins_scatter<<<(int)(((long long)Np * 64 + 255) / 256), 256, 0, stream>>>(ncur, snorm, psrc, pdst, agg, Np);
        gemm64_kernel<64, 1, true, false><<<469, 256, 0, stream>>>(agg, dnorm, fpt(18) + (size_t)i * 4096, fpt(19) + (size_t)i * 64, nullptr, tnew, Nt);

        // CFConv (net -> node)
        gemm64_kernel<64, 0, false, false><<<469, 256, 0, stream>>>(tcur, nullptr, fpt(20) + (size_t)i * 4096, fpt(21) + (size_t)i * 64, nullptr, hv, Nt);
        hipMemsetAsync(h_cf, 0, (size_t)Nn * H * 4, stream);
        cf_pin4_kernel<<<1024, 256, 0, stream>>>(pinf, hv, psrc, pdst,
                                                 fpt(22) + (size_t)i * 1024, fpt(23) + (size_t)i * 64,
                                                 fpt(24) + (size_t)i * 4096, fpt(25) + (size_t)i * 64,
                                                 h_cf, Np);

        // SAGE (near): hp = relu(ncur @ pool + b), scatter-max into h_ng
        gemm64_kernel<64, 2, false, false><<<1024, 256, 0, stream>>>(ncur, nullptr, fpt(28) + (size_t)i * 4096, fpt(29) + (size_t)i * 64, nullptr, hp, Nn);
        hipMemsetAsync(h_ng, 0, (size_t)Nn * H * 4, stream);
        sage_edge_kernel<<<(int)(((long long)Ne * 64 + 255) / 256), 256, 0, stream>>>(hp, ew3 + (size_t)i * Ne, esrc, edst, (unsigned int*)h_ng, Ne);

        // combine:
        // hp (reused) = ncur @ sage_self + sage_bias;  hp += h_ng @ sage_neigh
        gemm64_kernel<64, 0, false, false><<<1024, 256, 0, stream>>>(ncur, nullptr, fpt(30) + (size_t)i * 4096, fpt(32) + (size_t)i * 64, nullptr, hp, Nn);
        gemm64_kernel<64, 0, false, true><<<1024, 256, 0, stream>>>(h_ng, nullptr, fpt(31) + (size_t)i * 4096, fpt(32) + (size_t)i * 64, hp, hp, Nn);
        // nnew = lrelu(max(ssp(h_cf @ cf_out + b), hp))   (fused ACT=4)
        gemm64_kernel<64, 4, false, false><<<1024, 256, 0, stream>>>(h_cf, nullptr, fpt(26) + (size_t)i * 4096, fpt(27) + (size_t)i * 64, hp, nnew, Nn);

        float* t;
        t = ncur; ncur = nnew; nnew = t;
        t = tcur; tcur = tnew; tnew = t;
    }

    float* out = (float*)d_out;
    node_head3_kernel<<<640, 256, 0, stream>>>(in_node, ncur, fpt(33), fpt(34), fpt(35), fpt(36), fpt(37), fpt(38), out, Nn);
    net_head3_kernel<<<480, 256, 0, stream>>>(in_net, tcur, fpt(39), fpt(40), fpt(41), fpt(42), fpt(43), fpt(44), out + (size_t)Nn * T, Nt);
}

// Round 7
// 1908.326 us; speedup vs baseline: 7.7187x; 1.0623x over previous
//
#include <hip/hip_runtime.h>
#include <hip/hip_bf16.h>

#define DEV __device__ __forceinline__

DEV float lrelu_(float x){ return x > 0.f ? x : 0.01f * x; }
DEV float ssp_(float x){ return fmaxf(x, 0.f) + __logf(1.f + __expf(-fabsf(x))) - 0.69314718055994530942f; }
DEV float sigm_(float x){ return 1.f / (1.f + __expf(-x)); }

DEV void fma44(float (&acc)[4][4], const float4 (&xa)[4], const float4 (&wa)[4])
{
    #pragma unroll
    for (int kk = 0; kk < 4; kk++) {
        #pragma unroll
        for (int i = 0; i < 4; i++) {
            float x = ((const float*)&xa[i])[kk];
            #pragma unroll
            for (int j = 0; j < 4; j++)
                acc[i][j] += x * ((const float*)&wa[kk])[j];
        }
    }
}

// ====== generic tiled GEMM: Y[N x 64] = act( (X .* scale?) @ W[K x 64] + b ) ====
// ACT: 0=none 1=lrelu 2=relu 3=ssp 4=lrelu(max(ssp(acc+b), P))   ADD: acc += P
template<int K, int ACT, bool SCALE, bool ADD>
__global__ __launch_bounds__(256) void gemm64_kernel(const float* __restrict__ X,
                                                     const float* __restrict__ scale,
                                                     const float* __restrict__ W,
                                                     const float* __restrict__ B,
                                                     const float* __restrict__ P,
                                                     float* __restrict__ Y, int nrows)
{
    constexpr int XS = K + 4;
    constexpr int KQ = K / 4;
    __shared__ float Ws[K * 64];
    __shared__ float bs[64];
    __shared__ float Xs[64 * XS];
    for (int i = threadIdx.x; i < K * 64; i += 256) Ws[i] = W[i];
    if (threadIdx.x < 64) bs[threadIdx.x] = ADD ? 0.f : B[threadIdx.x];
    const int tr = threadIdx.x >> 4, tc = threadIdx.x & 15;
    const int r0 = tr * 4, c0 = tc * 4;
    for (int base = blockIdx.x * 64; base < nrows; base += gridDim.x * 64) {
        __syncthreads();
        for (int i = threadIdx.x; i < 64 * KQ; i += 256) {
            int row = i / KQ, kq = (i % KQ) * 4;
            int g = base + row;
            float4 v = make_float4(0.f, 0.f, 0.f, 0.f);
            if (g < nrows) {
                v = *(const float4*)&X[(size_t)g * K + kq];
                if (SCALE) { float s = scale[g]; v.x *= s; v.y *= s; v.z *= s; v.w *= s; }
            }
            *(float4*)&Xs[row * XS + kq] = v;
        }
        __syncthreads();
        float acc[4][4];
        #pragma unroll
        for (int i = 0; i < 4; i++)
            #pragma unroll
            for (int j = 0; j < 4; j++) acc[i][j] = bs[c0 + j];
        #pragma unroll 4
        for (int kq = 0; kq < K; kq += 4) {
            float4 xa[4], wa[4];
            #pragma unroll
            for (int i = 0; i < 4; i++) xa[i] = *(const float4*)&Xs[(r0 + i) * XS + kq];
            #pragma unroll
            for (int j = 0; j < 4; j++) wa[j] = *(const float4*)&Ws[(kq + j) * 64 + c0];
            fma44(acc, xa, wa);
        }
        #pragma unroll
        for (int i = 0; i < 4; i++) {
            int g = base + r0 + i;
            if (g < nrows) {
                float4 prev = make_float4(0,0,0,0);
                if (ADD || ACT == 4) prev = *(const float4*)&P[(size_t)g * 64 + c0];
                float4 o;
                float* op = (float*)&o;
                #pragma unroll
                for (int j = 0; j < 4; j++) {
                    float a = acc[i][j];
                    if (ADD) a += ((const float*)&prev)[j];
                    if (ACT == 1) a = lrelu_(a);
                    else if (ACT == 2) a = fmaxf(a, 0.f);
                    else if (ACT == 3) a = ssp_(a);
                    else if (ACT == 4) a = lrelu_(fmaxf(ssp_(a), ((const float*)&prev)[j]));
                    op[j] = a;
                }
                *(float4*)&Y[(size_t)g * 64 + c0] = o;
            }
        }
    }
}

// ---------------- small scalar GEMV (pin encoder, C=16) ----------------
template<int K, int C, int ACT>
__global__ __launch_bounds__(256) void lin_kernel(const float* __restrict__ X,
                                                  const float* __restrict__ W,
                                                  const float* __restrict__ B,
                                                  float* __restrict__ Y, int nrows)
{
    constexpr int ROWS = 256 / C;
    __shared__ float Ws[K * C];
    __shared__ float bs[C];
    __shared__ float Xs[ROWS * K];
    for (int i = threadIdx.x; i < K * C; i += 256) Ws[i] = W[i];
    if (threadIdx.x < C) bs[threadIdx.x] = B[threadIdx.x];
    __syncthreads();
    const int r = threadIdx.x / C, c = threadIdx.x % C;
    for (int base = blockIdx.x * ROWS; base < nrows; base += gridDim.x * ROWS) {
        __syncthreads();
        for (int i = threadIdx.x; i < ROWS * K; i += 256) {
            int rr = base + i / K;
            Xs[i] = (rr < nrows) ? X[(size_t)rr * K + i % K] : 0.f;
        }
        __syncthreads();
        int row = base + r;
        if (row < nrows) {
            float acc = bs[c];
            #pragma unroll
            for (int k = 0; k < K; k++) acc += Xs[r * K + k] * Ws[k * C + c];
            if (ACT == 1) acc = lrelu_(acc);
            else if (ACT == 2) acc = fmaxf(acc, 0.f);
            Y[(size_t)row * C + c] = acc;
        }
    }
}

// ---------------- degrees (for pins norms) ----------------
__global__ __launch_bounds__(256) void deg_kernel(const int* __restrict__ src, const int* __restrict__ dst,
                                                  int* __restrict__ degs, int* __restrict__ degd, int np)
{
    int p = blockIdx.x * 256 + threadIdx.x;
    if (p < np) { atomicAdd(&degs[src[p]], 1); atomicAdd(&degd[dst[p]], 1); }
}

__global__ __launch_bounds__(256) void norm_kernel(int* __restrict__ arr, int n)
{
    int i = blockIdx.x * 256 + threadIdx.x;
    if (i < n) {
        int v = arr[i]; if (v < 1) v = 1;
        arr[i] = __float_as_int(rsqrtf((float)v));
    }
}

// ================= CSR build for 'near' edges keyed by dst =================
__global__ __launch_bounds__(256) void csr_count_kernel(const int* __restrict__ edst, int* __restrict__ cnt, int ne)
{
    int e = blockIdx.x * 256 + threadIdx.x;
    if (e < ne) atomicAdd(&cnt[edst[e]], 1);
}

// per-block (256-elem) sums of cnt
__global__ __launch_bounds__(256) void scan_block_sum_kernel(const int* __restrict__ cnt, int* __restrict__ bsum, int n)
{
    __shared__ int sh[256];
    int i = blockIdx.x * 256 + threadIdx.x;
    sh[threadIdx.x] = (i < n) ? cnt[i] : 0;
    __syncthreads();
    for (int s = 128; s > 0; s >>= 1) {
        if (threadIdx.x < s) sh[threadIdx.x] += sh[threadIdx.x + s];
        __syncthreads();
    }
    if (threadIdx.x == 0) bsum[blockIdx.x] = sh[0];
}

// serial exclusive scan of block sums (nb ~ 391) + write total
__global__ void scan_bsum_kernel(int* __restrict__ bsum, int nb, int* __restrict__ total_out)
{
    if (threadIdx.x == 0 && blockIdx.x == 0) {
        int run = 0;
        for (int i = 0; i < nb; i++) { int v = bsum[i]; bsum[i] = run; run += v; }
        *total_out = run;
    }
}

// exclusive scan within block + block offset -> row_start & next
__global__ __launch_bounds__(256) void scan_final_kernel(const int* __restrict__ cnt, const int* __restrict__ bsum,
                                                         int* __restrict__ row_start, int* __restrict__ nxt, int n)
{
    __shared__ int sh[256];
    int i = blockIdx.x * 256 + threadIdx.x;
    int v = (i < n) ? cnt[i] : 0;
    sh[threadIdx.x] = v;
    __syncthreads();
    // Hillis-Steele inclusive scan
    for (int s = 1; s < 256; s <<= 1) {
        int add = (threadIdx.x >= s) ? sh[threadIdx.x - s] : 0;
        __syncthreads();
        sh[threadIdx.x] += add;
        __syncthreads();
    }
    if (i < n) {
        int excl = sh[threadIdx.x] - v + bsum[blockIdx.x];
        row_start[i] = excl;
        nxt[i] = excl;
    }
}

__global__ __launch_bounds__(256) void csr_fill_kernel(const int* __restrict__ edst, int* __restrict__ nxt,
                                                       int* __restrict__ eidx, int ne)
{
    int e = blockIdx.x * 256 + threadIdx.x;
    if (e < ne) {
        int slot = atomicAdd(&nxt[edst[e]], 1);
        eidx[slot] = e;
    }
}

// ---------------- edge weights for all 3 layers ----------------
__global__ __launch_bounds__(256) void edge_ew_kernel(const float* __restrict__ in_edge,
                                                      const float* __restrict__ elW, const float* __restrict__ elb,
                                                      const float* __restrict__ gW, const float* __restrict__ gb,
                                                      float* __restrict__ ew3, int ne)
{
    __shared__ float W[32], B[8], G[24], Gb[3];
    if (threadIdx.x < 32) W[threadIdx.x] = elW[threadIdx.x];
    if (threadIdx.x < 8)  B[threadIdx.x] = elb[threadIdx.x];
    if (threadIdx.x < 24) G[threadIdx.x] = gW[threadIdx.x];
    if (threadIdx.x < 3)  Gb[threadIdx.x] = gb[threadIdx.x];
    __syncthreads();
    for (int e = blockIdx.x * 256 + threadIdx.x; e < ne; e += gridDim.x * 256) {
        float4 x = *(const float4*)&in_edge[(size_t)e * 4];
        float ef[8];
        #pragma unroll
        for (int j = 0; j < 8; j++)
            ef[j] = lrelu_(B[j] + x.x * W[j] + x.y * W[8 + j] + x.z * W[16 + j] + x.w * W[24 + j]);
        #pragma unroll
        for (int i = 0; i < 3; i++) {
            float a = Gb[i];
            #pragma unroll
            for (int j = 0; j < 8; j++) a += ef[j] * G[i * 8 + j];
            ew3[(size_t)i * ne + e] = sigm_(a);
        }
    }
}

// ---------------- pins GraphConv scatter (1 lane = 1 channel, dense per-row atomics) -------------
__global__ __launch_bounds__(256) void pins_scatter(const float* __restrict__ nf, const float* __restrict__ snorm,
                                                    const int* __restrict__ src, const int* __restrict__ dst,
                                                    float* __restrict__ agg, int np)
{
    long long idx = (long long)blockIdx.x * 256 + threadIdx.x;
    int p = (int)(idx >> 6); if (p >= np) return;
    int c = (int)(idx & 63);
    int s = src[p], d = dst[p];
    unsafeAtomicAdd(&agg[(size_t)d * 64 + c], nf[(size_t)s * 64 + c] * snorm[s]);
}

// ---------------- CFConv fused: GEMMs in LDS, dense wave-per-row scatter ----------------
__global__ __launch_bounds__(256) void cf_pin4_kernel(const float* __restrict__ pinf, const float* __restrict__ hv,
                                                      const int* __restrict__ psrc, const int* __restrict__ pdst,
                                                      const float* __restrict__ W1, const float* __restrict__ B1,
                                                      const float* __restrict__ W2, const float* __restrict__ B2,
                                                      float* __restrict__ h_cf, int np)
{
    __shared__ float Ws1[16 * 64], Ws2[64 * 64], bs1[64], bs2[64];
    __shared__ float PF[64 * 20];
    __shared__ float T1[64 * 68];        // reused as HE after GEMM2
    __shared__ int srcS[64], dstS[64];
    for (int i = threadIdx.x; i < 16 * 64; i += 256) Ws1[i] = W1[i];
    for (int i = threadIdx.x; i < 64 * 64; i += 256) Ws2[i] = W2[i];
    if (threadIdx.x < 64) { bs1[threadIdx.x] = B1[threadIdx.x]; bs2[threadIdx.x] = B2[threadIdx.x]; }
    const int tr = threadIdx.x >> 4, tc = threadIdx.x & 15;
    const int r0 = tr * 4, c0 = tc * 4;
    const int lane = threadIdx.x & 63, wv = threadIdx.x >> 6;
    for (int base = blockIdx.x * 64; base < np; base += gridDim.x * 64) {
        __syncthreads();
        {
            int row = threadIdx.x >> 2, kq = (threadIdx.x & 3) * 4;
            int p = base + row;
            float4 v = make_float4(0.f, 0.f, 0.f, 0.f);
            if (p < np) v = *(const float4*)&pinf[(size_t)p * 16 + kq];
            *(float4*)&PF[row * 20 + kq] = v;
            if (threadIdx.x < 64) {
                int pp = base + threadIdx.x;
                srcS[threadIdx.x] = (pp < np) ? psrc[pp] : 0;
                dstS[threadIdx.x] = (pp < np) ? pdst[pp] : 0;
            }
        }
        __syncthreads();
        // GEMM1: T1 = ssp(PF @ W1 + b1), K=16
        {
            float acc[4][4];
            #pragma unroll
            for (int i = 0; i < 4; i++)
                #pragma unroll
                for (int j = 0; j < 4; j++) acc[i][j] = bs1[c0 + j];
            #pragma unroll
            for (int kq = 0; kq < 16; kq += 4) {
                float4 xa[4], wa[4];
                #pragma unroll
                for (int i = 0; i < 4; i++) xa[i] = *(const float4*)&PF[(r0 + i) * 20 + kq];
                #pragma unroll
                for (int j = 0; j < 4; j++) wa[j] = *(const float4*)&Ws1[(kq + j) * 64 + c0];
                fma44(acc, xa, wa);
            }
            #pragma unroll
            for (int i = 0; i < 4; i++) {
                float4 o; float* op = (float*)&o;
                #pragma unroll
                for (int j = 0; j < 4; j++) op[j] = ssp_(acc[i][j]);
                *(float4*)&T1[(r0 + i) * 68 + c0] = o;
            }
        }
        __syncthreads();
        // GEMM2: HE = ssp(T1 @ W2 + b2), K=64 ; HE overwrites T1 (write-after-read, guarded)
        {
            float acc[4][4];
            #pragma unroll
            for (int i = 0; i < 4; i++)
                #pragma unroll
                for (int j = 0; j < 4; j++) acc[i][j] = bs2[c0 + j];
            #pragma unroll 4
            for (int kq = 0; kq < 64; kq += 4) {
                float4 xa[4], wa[4];
                #pragma unroll
                for (int i = 0; i < 4; i++) xa[i] = *(const float4*)&T1[(r0 + i) * 68 + kq];
                #pragma unroll
                for (int j = 0; j < 4; j++) wa[j] = *(const float4*)&Ws2[(kq + j) * 64 + c0];
                fma44(acc, xa, wa);
            }
            __syncthreads();
            #pragma unroll
            for (int i = 0; i < 4; i++) {
                float4 o; float* op = (float*)&o;
                #pragma unroll
                for (int j = 0; j < 4; j++) op[j] = ssp_(acc[i][j]);
                *(float4*)&T1[(r0 + i) * 68 + c0] = o;
            }
        }
        __syncthreads();
        // scatter: one wave per pin-row; 64 lanes = 64 contiguous channels
        #pragma unroll 4
        for (int i = 0; i < 16; i++) {
            int pl = wv * 16 + i;
            int p = base + pl;
            if (p < np) {
                float m = hv[(size_t)dstS[pl] * 64 + lane] * T1[pl * 68 + lane];
                unsafeAtomicAdd(&h_cf[(size_t)srcS[pl] * 64 + lane], m);
            }
        }
    }
}

// ---------------- SAGE gather-max over dst-CSR (one wave per node, no atomics) ----------------
__global__ __launch_bounds__(256) void sage_gather_kernel(const float* __restrict__ hp, const float* __restrict__ ew,
                                                          const int* __restrict__ esrc,
                                                          const int* __restrict__ row_start,
                                                          const int* __restrict__ eidx,
                                                          float* __restrict__ h_ng, int nn)
{
    const int lane = threadIdx.x & 63, wv = threadIdx.x >> 6;
    for (int d = blockIdx.x * 4 + wv; d < nn; d += gridDim.x * 4) {
        int rs = row_start[d], re = row_start[d + 1];
        float acc = 0.f;
        for (int k = rs; k < re; k++) {
            int e = eidx[k];
            int s = esrc[e];
            float w = ew[e];
            acc = fmaxf(acc, hp[(size_t)s * 64 + lane] * w);
        }
        h_ng[(size_t)d * 64 + lane] = acc;
    }
}

// ---------------- node head (32 rows/iter, grid-stride, 3-stage MLP) ----------------
__global__ __launch_bounds__(256) void node_head3_kernel(const float* __restrict__ in_node, const float* __restrict__ nf,
                                                         const float* __restrict__ W1, const float* __restrict__ B1,
                                                         const float* __restrict__ W2, const float* __restrict__ B2,
                                                         const float* __restrict__ W3, const float* __restrict__ B3,
                                                         float* __restrict__ out, int n)
{
    __shared__ float Ws1[80 * 64], Ws2[64 * 64], Ws3[64 * 4];
    __shared__ float bs1[64], bs2[64], bs3[4];
    __shared__ float Xs[32 * 84];       // reused as H2 (stride 68)
    __shared__ float H1[32 * 68];
    for (int i = threadIdx.x; i < 80 * 64; i += 256) Ws1[i] = W1[i];
    for (int i = threadIdx.x; i < 64 * 64; i += 256) Ws2[i] = W2[i];
    for (int i = threadIdx.x; i < 64 * 4; i += 256) Ws3[i] = W3[i];
    if (threadIdx.x < 64) { bs1[threadIdx.x] = B1[threadIdx.x]; bs2[threadIdx.x] = B2[threadIdx.x]; }
    if (threadIdx.x < 4) bs3[threadIdx.x] = B3[threadIdx.x];
    const int tr = threadIdx.x >> 4, tc = threadIdx.x & 15;
    const int r0 = tr * 2, c0 = tc * 4;
    for (int base = blockIdx.x * 32; base < n; base += gridDim.x * 32) {
        __syncthreads();
        for (int i = threadIdx.x; i < 32 * 4; i += 256) {
            int row = i >> 2, kq = (i & 3) * 4;
            int g = base + row;
            float4 v = make_float4(0,0,0,0);
            if (g < n) v = *(const float4*)&in_node[(size_t)g * 16 + kq];
            *(float4*)&Xs[row * 84 + kq] = v;
        }
        for (int i = threadIdx.x; i < 32 * 16; i += 256) {
            int row = i >> 4, kq = (i & 15) * 4;
            int g = base + row;
            float4 v = make_float4(0,0,0,0);
            if (g < n) v = *(const float4*)&nf[(size_t)g * 64 + kq];
            *(float4*)&Xs[row * 84 + 16 + kq] = v;
        }
        __syncthreads();
        {
            float acc[2][4];
            #pragma unroll
            for (int i = 0; i < 2; i++)
                #pragma unroll
                for (int j = 0; j < 4; j++) acc[i][j] = bs1[c0 + j];
            #pragma unroll 4
            for (int kq = 0; kq < 80; kq += 4) {
                float4 xa[2], wa[4];
                #pragma unroll
                for (int i = 0; i < 2; i++) xa[i] = *(const float4*)&Xs[(r0 + i) * 84 + kq];
                #pragma unroll
                for (int j = 0; j < 4; j++) wa[j] = *(const float4*)&Ws1[(kq + j) * 64 + c0];
                #pragma unroll
                for (int kk = 0; kk < 4; kk++)
                    #pragma unroll
                    for (int i = 0; i < 2; i++) {
                        float x = ((const float*)&xa[i])[kk];
                        #pragma unroll
                        for (int j = 0; j < 4; j++) acc[i][j] += x * ((const float*)&wa[kk])[j];
                    }
            }
            #pragma unroll
            for (int i = 0; i < 2; i++) {
                float4 o; float* op = (float*)&o;
                #pragma unroll
                for (int j = 0; j < 4; j++) op[j] = lrelu_(acc[i][j]);
                *(float4*)&H1[(r0 + i) * 68 + c0] = o;
            }
        }
        __syncthreads();
        float* H2 = Xs;
        {
            float acc[2][4];
            #pragma unroll
            for (int i = 0; i < 2; i++)
                #pragma unroll
                for (int j = 0; j < 4; j++) acc[i][j] = bs2[c0 + j];
            #pragma unroll 4
            for (int kq = 0; kq < 64; kq += 4) {
                float4 xa[2], wa[4];
                #pragma unroll
                for (int i = 0; i < 2; i++) xa[i] = *(const float4*)&H1[(r0 + i) * 68 + kq];
                #pragma unroll
                for (int j = 0; j < 4; j++) wa[j] = *(const float4*)&Ws2[(kq + j) * 64 + c0];
                #pragma unroll
                for (int kk = 0; kk < 4; kk++)
                    #pragma unroll
                    for (int i = 0; i < 2; i++) {
                        float x = ((const float*)&xa[i])[kk];
                        #pragma unroll
                        for (int j = 0; j < 4; j++) acc[i][j] += x * ((const float*)&wa[kk])[j];
                    }
            }
            __syncthreads();
            #pragma unroll
            for (int i = 0; i < 2; i++) {
                float4 o; float* op = (float*)&o;
                #pragma unroll
                for (int j = 0; j < 4; j++) op[j] = lrelu_(acc[i][j]);
                *(float4*)&H2[(r0 + i) * 68 + c0] = o;
            }
        }
        __syncthreads();
        if (threadIdx.x < 128) {
            int row = threadIdx.x >> 2, c = threadIdx.x & 3;
            float acc = bs3[c];
            #pragma unroll 4
            for (int kq = 0; kq < 64; kq += 4) {
                float4 h = *(const float4*)&H2[row * 68 + kq];
                #pragma unroll
                for (int j = 0; j < 4; j++) acc += ((const float*)&h)[j] * Ws3[(kq + j) * 4 + c];
            }
            int g = base + row;
            if (g < n) out[(size_t)g * 4 + c] = sigm_(acc);
        }
    }
}

// ---------------- net head (32 rows/iter, grid-stride, C_out=1) ----------------
__global__ __launch_bounds__(256) void net_head3_kernel(const float* __restrict__ in_net, const float* __restrict__ tf,
                                                        const float* __restrict__ W1, const float* __restrict__ B1,
                                                        const float* __restrict__ W2, const float* __restrict__ B2,
                                                        const float* __restrict__ W3, const float* __restrict__ B3,
                                                        float* __restrict__ out, int n)
{
    __shared__ float Ws1[72 * 64], Ws2[64 * 64], Ws3[64];
    __shared__ float bs1[64], bs2[64], bs3[1];
    __shared__ float Xs[32 * 76];       // reused as H2 (stride 68)
    __shared__ float H1[32 * 68];
    for (int i = threadIdx.x; i < 72 * 64; i += 256) Ws1[i] = W1[i];
    for (int i = threadIdx.x; i < 64 * 64; i += 256) Ws2[i] = W2[i];
    if (threadIdx.x < 64) { Ws3[threadIdx.x] = W3[threadIdx.x]; bs1[threadIdx.x] = B1[threadIdx.x]; bs2[threadIdx.x] = B2[threadIdx.x]; }
    if (threadIdx.x == 0) bs3[0] = B3[0];
    const int tr = threadIdx.x >> 4, tc = threadIdx.x & 15;
    const int r0 = tr * 2, c0 = tc * 4;
    for (int base = blockIdx.x * 32; base < n; base += gridDim.x * 32) {
        __syncthreads();
        for (int i = threadIdx.x; i < 32 * 2; i += 256) {
            int row = i >> 1, kq = (i & 1) * 4;
            int g = base + row;
            float4 v = make_float4(0,0,0,0);
            if (g < n) v = *(const float4*)&in_net[(size_t)g * 8 + kq];
            *(float4*)&Xs[row * 76 + kq] = v;
        }
        for (int i = threadIdx.x; i < 32 * 16; i += 256) {
            int row = i >> 4, kq = (i & 15) * 4;
            int g = base + row;
            float4 v = make_float4(0,0,0,0);
            if (g < n) v = *(const float4*)&tf[(size_t)g * 64 + kq];
            *(float4*)&Xs[row * 76 + 8 + kq] = v;
        }
        __syncthreads();
        {
            float acc[2][4];
            #pragma unroll
            for (int i = 0; i < 2; i++)
                #pragma unroll
                for (int j = 0; j < 4; j++) acc[i][j] = bs1[c0 + j];
            #pragma unroll 4
            for (int kq = 0; kq < 72; kq += 4) {
                float4 xa[2], wa[4];
                #pragma unroll
                for (int i = 0; i < 2; i++) xa[i] = *(const float4*)&Xs[(r0 + i) * 76 + kq];
                #pragma unroll
                for (int j = 0; j < 4; j++) wa[j] = *(const float4*)&Ws1[(kq + j) * 64 + c0];
                #pragma unroll
                for (int kk = 0; kk < 4; kk++)
                    #pragma unroll
                    for (int i = 0; i < 2; i++) {
                        float x = ((const float*)&xa[i])[kk];
                        #pragma unroll
                        for (int j = 0; j < 4; j++) acc[i][j] += x * ((const float*)&wa[kk])[j];
                    }
            }
            #pragma unroll
            for (int i = 0; i < 2; i++) {
                float4 o; float* op = (float*)&o;
                #pragma unroll
                for (int j = 0; j < 4; j++) op[j] = lrelu_(acc[i][j]);
                *(float4*)&H1[(r0 + i) * 68 + c0] = o;
            }
        }
        __syncthreads();
        float* H2 = Xs;
        {
            float acc[2][4];
            #pragma unroll
            for (int i = 0; i < 2; i++)
                #pragma unroll
                for (int j = 0; j < 4; j++) acc[i][j] = bs2[c0 + j];
            #pragma unroll 4
            for (int kq = 0; kq < 64; kq += 4) {
                float4 xa[2], wa[4];
                #pragma unroll
                for (int i = 0; i < 2; i++) xa[i] = *(const float4*)&H1[(r0 + i) * 68 + kq];
                #pragma unroll
                for (int j = 0; j < 4; j++) wa[j] = *(const float4*)&Ws2[(kq + j) * 64 + c0];
                #pragma unroll
                for (int kk = 0; kk < 4; kk++)
                    #pragma unroll
                    for (int i = 0; i < 2; i++) {
                        float x = ((const float*)&xa[i])[kk];
                        #pragma unroll
                        for (int j = 0; j < 4; j++) acc[i][j] += x * ((const float*)&wa[kk])[j];
                    }
            }
            __syncthreads();
            #pragma unroll
            for (int i = 0; i < 2; i++) {
                float4 o; float* op = (float*)&o;
                #pragma unroll
                for (int j = 0; j < 4; j++) op[j] = lrelu_(acc[i][j]);
                *(float4*)&H2[(r0 + i) * 68 + c0] = o;
            }
        }
        __syncthreads();
        if (threadIdx.x < 32) {
            int row = threadIdx.x;
            float acc = bs3[0];
            #pragma unroll 4
            for (int kq = 0; kq < 64; kq += 4) {
                float4 h = *(const float4*)&H2[row * 68 + kq];
                float4 w = *(const float4*)&Ws3[kq];
                acc += h.x * w.x + h.y * w.y + h.z * w.z + h.w * w.w;
            }
            int g = base + row;
            if (g < n) out[g] = sigm_(acc);
        }
    }
}

extern "C" void kernel_launch(void* const* d_in, const int* in_sizes, int n_in,
                              void* d_out, int out_size, void* d_ws, size_t ws_size,
                              hipStream_t stream)
{
    (void)in_sizes; (void)n_in; (void)out_size; (void)ws_size;
    constexpr int Nn = 100000, Nt = 30000, Np = 400000, Ne = 1000000;
    constexpr int H = 64, L = 3, T = 4;

    auto fpt = [&](int i){ return (const float*)d_in[i]; };
    auto ipt = [&](int i){ return (const int*)d_in[i]; };

    const float* in_node = fpt(0);
    const float* in_net  = fpt(1);
    const float* in_pin  = fpt(2);
    const float* in_edge = fpt(3);
    const int* psrc = ipt(4);
    const int* pdst = ipt(5);
    const int* esrc = ipt(6);
    const int* edst = ipt(7);

    float* ws = (float*)d_ws;
    size_t o = 0;
    auto alloc = [&](size_t nel){ float* p = ws + o; o += nel; return p; };
    float* node_a = alloc((size_t)Nn * H);
    float* node_b = alloc((size_t)Nn * H);
    float* net_a  = alloc((size_t)Nt * H);
    float* net_b  = alloc((size_t)Nt * H);
    float* agg    = alloc((size_t)Nt * H);
    float* hv     = alloc((size_t)Nt * H);
    float* pinf   = alloc((size_t)Np * 16);
    float* h_cf   = alloc((size_t)Nn * H);
    float* hp     = alloc((size_t)Nn * H);   // SAGE linear accumulator
    float* h_ng   = alloc((size_t)Nn * H);
    float* ew3    = alloc((size_t)3 * Ne);
    float* snorm  = alloc((size_t)Nn);
    float* dnorm  = alloc((size_t)Nt);
    // CSR workspace (ints)
    int* cnt       = (int*)alloc((size_t)Nn);
    int* row_start = (int*)alloc((size_t)Nn + 1);
    int* nxt       = (int*)alloc((size_t)Nn);
    int* eidx      = (int*)alloc((size_t)Ne);
    int* bsum      = (int*)alloc((size_t)512);

    constexpr int NB = (Nn + 255) / 256;   // 391 blocks for scan

    // degree norms for pins
    hipMemsetAsync(snorm, 0, (size_t)Nn * 4, stream);
    hipMemsetAsync(dnorm, 0, (size_t)Nt * 4, stream);
    deg_kernel<<<(Np + 255) / 256, 256, 0, stream>>>(psrc, pdst, (int*)snorm, (int*)dnorm, Np);
    norm_kernel<<<(Nn + 255) / 256, 256, 0, stream>>>((int*)snorm, Nn);
    norm_kernel<<<(Nt + 255) / 256, 256, 0, stream>>>((int*)dnorm, Nt);

    // build dst-CSR for 'near'
    hipMemsetAsync(cnt, 0, (size_t)Nn * 4, stream);
    csr_count_kernel<<<(Ne + 255) / 256, 256, 0, stream>>>(edst, cnt, Ne);
    scan_block_sum_kernel<<<NB, 256, 0, stream>>>(cnt, bsum, Nn);
    scan_bsum_kernel<<<1, 64, 0, stream>>>(bsum, NB, row_start + Nn);
    scan_final_kernel<<<NB, 256, 0, stream>>>(cnt, bsum, row_start, nxt, Nn);
    csr_fill_kernel<<<(Ne + 255) / 256, 256, 0, stream>>>(edst, nxt, eidx, Ne);

    // input encoders
    gemm64_kernel<16, 1, false, false><<<1024, 256, 0, stream>>>(in_node, nullptr, fpt(8),  fpt(9),  nullptr, node_a, Nn);
    gemm64_kernel< 8, 1, false, false><<<469, 256, 0, stream>>>(in_net,  nullptr, fpt(10), fpt(11), nullptr, net_a,  Nt);
    lin_kernel<8, 16, 1><<<1024, 256, 0, stream>>>(in_pin, fpt(12), fpt(13), pinf, Np);
    edge_ew_kernel<<<2048, 256, 0, stream>>>(in_edge, fpt(14), fpt(15), fpt(16), fpt(17), ew3, Ne);

    float* ncur = node_a; float* nnew = node_b;
    float* tcur = net_a;  float* tnew = net_b;

    for (int i = 0; i < L; i++) {
        // pins GraphConv (node -> net)
        hipMemsetAsync(agg, 0, (size_t)Nt * H * 4, stream);
        pins_scatter<<<(int)(((long long)Np * 64 + 255) / 256), 256, 0, stream>>>(ncur, snorm, psrc, pdst, agg, Np);
        gemm64_kernel<64, 1, true, false><<<469, 256, 0, stream>>>(agg, dnorm, fpt(18) + (size_t)i * 4096, fpt(19) + (size_t)i * 64, nullptr, tnew, Nt);

        // CFConv (net -> node)
        gemm64_kernel<64, 0, false, false><<<469, 256, 0, stream>>>(tcur, nullptr, fpt(20) + (size_t)i * 4096, fpt(21) + (size_t)i * 64, nullptr, hv, Nt);
        hipMemsetAsync(h_cf, 0, (size_t)Nn * H * 4, stream);
        cf_pin4_kernel<<<1024, 256, 0, stream>>>(pinf, hv, psrc, pdst,
                                                 fpt(22) + (size_t)i * 1024, fpt(23) + (size_t)i * 64,
                                                 fpt(24) + (size_t)i * 4096, fpt(25) + (size_t)i * 64,
                                                 h_cf, Np);

        // SAGE (near): hp = relu(ncur @ pool + b), gather-max over dst-CSR
        gemm64_kernel<64, 2, false, false><<<1024, 256, 0, stream>>>(ncur, nullptr, fpt(28) + (size_t)i * 4096, fpt(29) + (size_t)i * 64, nullptr, hp, Nn);
        sage_gather_kernel<<<(Nn + 3) / 4, 256, 0, stream>>>(hp, ew3 + (size_t)i * Ne, esrc, row_start, eidx, h_ng, Nn);

        // combine:
        // hp (reused) = ncur @ sage_self + sage_bias;  hp += h_ng @ sage_neigh
        gemm64_kernel<64, 0, false, false><<<1024, 256, 0, stream>>>(ncur, nullptr, fpt(30) + (size_t)i * 4096, fpt(32) + (size_t)i * 64, nullptr, hp, Nn);
        gemm64_kernel<64, 0, false, true><<<1024, 256, 0, stream>>>(h_ng, nullptr, fpt(31) + (size_t)i * 4096, fpt(32) + (size_t)i * 64, hp, hp, Nn);
        // nnew = lrelu(max(ssp(h_cf @ cf_out + b), hp))   (fused ACT=4)
        gemm64_kernel<64, 4, false, false><<<1024, 256, 0, stream>>>(h_cf, nullptr, fpt(26) + (size_t)i * 4096, fpt(27) + (size_t)i * 64, hp, nnew, Nn);

        float* t;
        t = ncur; ncur = nnew; nnew = t;
        t = tcur; tcur = tnew; tnew = t;
    }

    float* out = (float*)d_out;
    node_head3_kernel<<<640, 256, 0, stream>>>(in_node, ncur, fpt(33), fpt(34), fpt(35), fpt(36), fpt(37), fpt(38), out, Nn);
    net_head3_kernel<<<480, 256, 0, stream>>>(in_net, tcur, fpt(39), fpt(40), fpt(41), fpt(42), fpt(43), fpt(44), out + (size_t)Nn * T, Nt);
}

// Round 8
// 1816.276 us; speedup vs baseline: 8.1099x; 1.0507x over previous
//
#include <hip/hip_runtime.h>
#include <hip/hip_bf16.h>

#define DEV __device__ __forceinline__

DEV float lrelu_(float x){ return x > 0.f ? x : 0.01f * x; }
DEV float ssp_(float x){ return fmaxf(x, 0.f) + __logf(1.f + __expf(-fabsf(x))) - 0.69314718055994530942f; }
DEV float sigm_(float x){ return 1.f / (1.f + __expf(-x)); }

DEV void fma44(float (&acc)[4][4], const float4 (&xa)[4], const float4 (&wa)[4])
{
    #pragma unroll
    for (int kk = 0; kk < 4; kk++) {
        #pragma unroll
        for (int i = 0; i < 4; i++) {
            float x = ((const float*)&xa[i])[kk];
            #pragma unroll
            for (int j = 0; j < 4; j++)
                acc[i][j] += x * ((const float*)&wa[kk])[j];
        }
    }
}

// ====== generic tiled GEMM: Y[N x 64] = act( (X .* scale?) @ W[K x 64] + b ) ====
// ACT: 0=none 1=lrelu 2=relu 3=ssp 4=lrelu(max(ssp(acc+b), P))   ADD: acc += P
template<int K, int ACT, bool SCALE, bool ADD>
__global__ __launch_bounds__(256) void gemm64_kernel(const float* __restrict__ X,
                                                     const float* __restrict__ scale,
                                                     const float* __restrict__ W,
                                                     const float* __restrict__ B,
                                                     const float* __restrict__ P,
                                                     float* __restrict__ Y, int nrows)
{
    constexpr int XS = K + 4;
    constexpr int KQ = K / 4;
    __shared__ float Ws[K * 64];
    __shared__ float bs[64];
    __shared__ float Xs[64 * XS];
    for (int i = threadIdx.x; i < K * 64; i += 256) Ws[i] = W[i];
    if (threadIdx.x < 64) bs[threadIdx.x] = ADD ? 0.f : B[threadIdx.x];
    const int tr = threadIdx.x >> 4, tc = threadIdx.x & 15;
    const int r0 = tr * 4, c0 = tc * 4;
    for (int base = blockIdx.x * 64; base < nrows; base += gridDim.x * 64) {
        __syncthreads();
        for (int i = threadIdx.x; i < 64 * KQ; i += 256) {
            int row = i / KQ, kq = (i % KQ) * 4;
            int g = base + row;
            float4 v = make_float4(0.f, 0.f, 0.f, 0.f);
            if (g < nrows) {
                v = *(const float4*)&X[(size_t)g * K + kq];
                if (SCALE) { float s = scale[g]; v.x *= s; v.y *= s; v.z *= s; v.w *= s; }
            }
            *(float4*)&Xs[row * XS + kq] = v;
        }
        __syncthreads();
        float acc[4][4];
        #pragma unroll
        for (int i = 0; i < 4; i++)
            #pragma unroll
            for (int j = 0; j < 4; j++) acc[i][j] = bs[c0 + j];
        #pragma unroll 4
        for (int kq = 0; kq < K; kq += 4) {
            float4 xa[4], wa[4];
            #pragma unroll
            for (int i = 0; i < 4; i++) xa[i] = *(const float4*)&Xs[(r0 + i) * XS + kq];
            #pragma unroll
            for (int j = 0; j < 4; j++) wa[j] = *(const float4*)&Ws[(kq + j) * 64 + c0];
            fma44(acc, xa, wa);
        }
        #pragma unroll
        for (int i = 0; i < 4; i++) {
            int g = base + r0 + i;
            if (g < nrows) {
                float4 prev = make_float4(0,0,0,0);
                if (ADD || ACT == 4) prev = *(const float4*)&P[(size_t)g * 64 + c0];
                float4 o;
                float* op = (float*)&o;
                #pragma unroll
                for (int j = 0; j < 4; j++) {
                    float a = acc[i][j];
                    if (ADD) a += ((const float*)&prev)[j];
                    if (ACT == 1) a = lrelu_(a);
                    else if (ACT == 2) a = fmaxf(a, 0.f);
                    else if (ACT == 3) a = ssp_(a);
                    else if (ACT == 4) a = lrelu_(fmaxf(ssp_(a), ((const float*)&prev)[j]));
                    op[j] = a;
                }
                *(float4*)&Y[(size_t)g * 64 + c0] = o;
            }
        }
    }
}

// ====== dual GEMM: Y[N x 64] = X1 @ W1 + X2 @ W2 + b   (no activation) ======
__global__ __launch_bounds__(256) void gemm64_dual_kernel(const float* __restrict__ X1,
                                                          const float* __restrict__ X2,
                                                          const float* __restrict__ W1g,
                                                          const float* __restrict__ W2g,
                                                          const float* __restrict__ B,
                                                          float* __restrict__ Y, int nrows)
{
    __shared__ float Ws1[64 * 64], Ws2[64 * 64], bs[64];
    __shared__ float Xs1[32 * 68], Xs2[32 * 68];
    for (int i = threadIdx.x; i < 64 * 64; i += 256) { Ws1[i] = W1g[i]; Ws2[i] = W2g[i]; }
    if (threadIdx.x < 64) bs[threadIdx.x] = B[threadIdx.x];
    const int tr = threadIdx.x >> 4, tc = threadIdx.x & 15;
    const int r0 = tr * 2, c0 = tc * 4;
    for (int base = blockIdx.x * 32; base < nrows; base += gridDim.x * 32) {
        __syncthreads();
        for (int i = threadIdx.x; i < 512; i += 256) {
            int row = i >> 4, kq = (i & 15) * 4;
            int g = base + row;
            float4 a = make_float4(0,0,0,0), b = a;
            if (g < nrows) {
                a = *(const float4*)&X1[(size_t)g * 64 + kq];
                b = *(const float4*)&X2[(size_t)g * 64 + kq];
            }
            *(float4*)&Xs1[row * 68 + kq] = a;
            *(float4*)&Xs2[row * 68 + kq] = b;
        }
        __syncthreads();
        float acc[2][4];
        #pragma unroll
        for (int i = 0; i < 2; i++)
            #pragma unroll
            for (int j = 0; j < 4; j++) acc[i][j] = bs[c0 + j];
        #pragma unroll 4
        for (int kq = 0; kq < 64; kq += 4) {
            float4 xa1[2], xa2[2];
            #pragma unroll
            for (int i = 0; i < 2; i++) {
                xa1[i] = *(const float4*)&Xs1[(r0 + i) * 68 + kq];
                xa2[i] = *(const float4*)&Xs2[(r0 + i) * 68 + kq];
            }
            #pragma unroll
            for (int kk = 0; kk < 4; kk++) {
                float4 w1 = *(const float4*)&Ws1[(kq + kk) * 64 + c0];
                float4 w2 = *(const float4*)&Ws2[(kq + kk) * 64 + c0];
                #pragma unroll
                for (int i = 0; i < 2; i++) {
                    float x1 = ((const float*)&xa1[i])[kk];
                    float x2 = ((const float*)&xa2[i])[kk];
                    #pragma unroll
                    for (int j = 0; j < 4; j++)
                        acc[i][j] += x1 * ((const float*)&w1)[j] + x2 * ((const float*)&w2)[j];
                }
            }
        }
        #pragma unroll
        for (int i = 0; i < 2; i++) {
            int g = base + r0 + i;
            if (g < nrows) *(float4*)&Y[(size_t)g * 64 + c0] = *(float4*)&acc[i][0];
        }
    }
}

// ---------------- small scalar GEMV (pin encoder, C=16) ----------------
template<int K, int C, int ACT>
__global__ __launch_bounds__(256) void lin_kernel(const float* __restrict__ X,
                                                  const float* __restrict__ W,
                                                  const float* __restrict__ B,
                                                  float* __restrict__ Y, int nrows)
{
    constexpr int ROWS = 256 / C;
    __shared__ float Ws[K * C];
    __shared__ float bs[C];
    __shared__ float Xs[ROWS * K];
    for (int i = threadIdx.x; i < K * C; i += 256) Ws[i] = W[i];
    if (threadIdx.x < C) bs[threadIdx.x] = B[threadIdx.x];
    __syncthreads();
    const int r = threadIdx.x / C, c = threadIdx.x % C;
    for (int base = blockIdx.x * ROWS; base < nrows; base += gridDim.x * ROWS) {
        __syncthreads();
        for (int i = threadIdx.x; i < ROWS * K; i += 256) {
            int rr = base + i / K;
            Xs[i] = (rr < nrows) ? X[(size_t)rr * K + i % K] : 0.f;
        }
        __syncthreads();
        int row = base + r;
        if (row < nrows) {
            float acc = bs[c];
            #pragma unroll
            for (int k = 0; k < K; k++) acc += Xs[r * K + k] * Ws[k * C + c];
            if (ACT == 1) acc = lrelu_(acc);
            else if (ACT == 2) acc = fmaxf(acc, 0.f);
            Y[(size_t)row * C + c] = acc;
        }
    }
}

// ---------------- degrees (for pins norms) ----------------
__global__ __launch_bounds__(256) void deg_kernel(const int* __restrict__ src, const int* __restrict__ dst,
                                                  int* __restrict__ degs, int* __restrict__ degd, int np)
{
    int p = blockIdx.x * 256 + threadIdx.x;
    if (p < np) { atomicAdd(&degs[src[p]], 1); atomicAdd(&degd[dst[p]], 1); }
}

__global__ __launch_bounds__(256) void norm_kernel(int* __restrict__ arr, int n)
{
    int i = blockIdx.x * 256 + threadIdx.x;
    if (i < n) {
        int v = arr[i]; if (v < 1) v = 1;
        arr[i] = __float_as_int(rsqrtf((float)v));
    }
}

// ================= CSR build (generic, keyed by given index array) =================
__global__ __launch_bounds__(256) void csr_count_kernel(const int* __restrict__ key, int* __restrict__ cnt, int ne)
{
    int e = blockIdx.x * 256 + threadIdx.x;
    if (e < ne) atomicAdd(&cnt[key[e]], 1);
}

__global__ __launch_bounds__(256) void scan_block_sum_kernel(const int* __restrict__ cnt, int* __restrict__ bsum, int n)
{
    __shared__ int sh[256];
    int i = blockIdx.x * 256 + threadIdx.x;
    sh[threadIdx.x] = (i < n) ? cnt[i] : 0;
    __syncthreads();
    for (int s = 128; s > 0; s >>= 1) {
        if (threadIdx.x < s) sh[threadIdx.x] += sh[threadIdx.x + s];
        __syncthreads();
    }
    if (threadIdx.x == 0) bsum[blockIdx.x] = sh[0];
}

__global__ void scan_bsum_kernel(int* __restrict__ bsum, int nb, int* __restrict__ total_out)
{
    if (threadIdx.x == 0 && blockIdx.x == 0) {
        int run = 0;
        for (int i = 0; i < nb; i++) { int v = bsum[i]; bsum[i] = run; run += v; }
        *total_out = run;
    }
}

__global__ __launch_bounds__(256) void scan_final_kernel(const int* __restrict__ cnt, const int* __restrict__ bsum,
                                                         int* __restrict__ row_start, int* __restrict__ nxt, int n)
{
    __shared__ int sh[256];
    int i = blockIdx.x * 256 + threadIdx.x;
    int v = (i < n) ? cnt[i] : 0;
    sh[threadIdx.x] = v;
    __syncthreads();
    for (int s = 1; s < 256; s <<= 1) {
        int add = (threadIdx.x >= s) ? sh[threadIdx.x - s] : 0;
        __syncthreads();
        sh[threadIdx.x] += add;
        __syncthreads();
    }
    if (i < n) {
        int excl = sh[threadIdx.x] - v + bsum[blockIdx.x];
        row_start[i] = excl;
        nxt[i] = excl;
    }
}

__global__ __launch_bounds__(256) void csr_fill_kernel(const int* __restrict__ key, int* __restrict__ nxt,
                                                       int* __restrict__ eidx, int ne)
{
    int e = blockIdx.x * 256 + threadIdx.x;
    if (e < ne) {
        int slot = atomicAdd(&nxt[key[e]], 1);
        eidx[slot] = e;
    }
}

// ---------------- edge weights for all 3 layers ----------------
__global__ __launch_bounds__(256) void edge_ew_kernel(const float* __restrict__ in_edge,
                                                      const float* __restrict__ elW, const float* __restrict__ elb,
                                                      const float* __restrict__ gW, const float* __restrict__ gb,
                                                      float* __restrict__ ew3, int ne)
{
    __shared__ float W[32], B[8], G[24], Gb[3];
    if (threadIdx.x < 32) W[threadIdx.x] = elW[threadIdx.x];
    if (threadIdx.x < 8)  B[threadIdx.x] = elb[threadIdx.x];
    if (threadIdx.x < 24) G[threadIdx.x] = gW[threadIdx.x];
    if (threadIdx.x < 3)  Gb[threadIdx.x] = gb[threadIdx.x];
    __syncthreads();
    for (int e = blockIdx.x * 256 + threadIdx.x; e < ne; e += gridDim.x * 256) {
        float4 x = *(const float4*)&in_edge[(size_t)e * 4];
        float ef[8];
        #pragma unroll
        for (int j = 0; j < 8; j++)
            ef[j] = lrelu_(B[j] + x.x * W[j] + x.y * W[8 + j] + x.z * W[16 + j] + x.w * W[24 + j]);
        #pragma unroll
        for (int i = 0; i < 3; i++) {
            float a = Gb[i];
            #pragma unroll
            for (int j = 0; j < 8; j++) a += ef[j] * G[i * 8 + j];
            ew3[(size_t)i * ne + e] = sigm_(a);
        }
    }
}

// ---------------- pins GraphConv gather over pdst-CSR (one wave per net, no atomics) -------------
__global__ __launch_bounds__(256) void pins_gather_kernel(const float* __restrict__ nf, const float* __restrict__ snorm,
                                                          const float* __restrict__ dnorm,
                                                          const int* __restrict__ psrc,
                                                          const int* __restrict__ prow,
                                                          const int* __restrict__ peidx,
                                                          float* __restrict__ agg, int nt)
{
    const int lane = threadIdx.x & 63, wv = threadIdx.x >> 6;
    for (int d = blockIdx.x * 4 + wv; d < nt; d += gridDim.x * 4) {
        int rs = prow[d], re = prow[d + 1];
        float acc = 0.f;
        int k = rs;
        for (; k + 1 < re; k += 2) {
            int p0 = peidx[k], p1 = peidx[k + 1];
            int s0 = psrc[p0], s1 = psrc[p1];
            float n0 = snorm[s0], n1 = snorm[s1];
            float v0 = nf[(size_t)s0 * 64 + lane] * n0;
            float v1 = nf[(size_t)s1 * 64 + lane] * n1;
            acc += v0 + v1;
        }
        if (k < re) {
            int p0 = peidx[k];
            int s0 = psrc[p0];
            acc += nf[(size_t)s0 * 64 + lane] * snorm[s0];
        }
        agg[(size_t)d * 64 + lane] = acc * dnorm[d];
    }
}

// ---------------- CFConv fused: GEMMs in LDS, dense wave-per-row scatter ----------------
__global__ __launch_bounds__(256) void cf_pin4_kernel(const float* __restrict__ pinf, const float* __restrict__ hv,
                                                      const int* __restrict__ psrc, const int* __restrict__ pdst,
                                                      const float* __restrict__ W1, const float* __restrict__ B1,
                                                      const float* __restrict__ W2, const float* __restrict__ B2,
                                                      float* __restrict__ h_cf, int np)
{
    __shared__ float Ws1[16 * 64], Ws2[64 * 64], bs1[64], bs2[64];
    __shared__ float PF[64 * 20];
    __shared__ float T1[64 * 68];        // reused as HE after GEMM2
    __shared__ int srcS[64], dstS[64];
    for (int i = threadIdx.x; i < 16 * 64; i += 256) Ws1[i] = W1[i];
    for (int i = threadIdx.x; i < 64 * 64; i += 256) Ws2[i] = W2[i];
    if (threadIdx.x < 64) { bs1[threadIdx.x] = B1[threadIdx.x]; bs2[threadIdx.x] = B2[threadIdx.x]; }
    const int tr = threadIdx.x >> 4, tc = threadIdx.x & 15;
    const int r0 = tr * 4, c0 = tc * 4;
    const int lane = threadIdx.x & 63, wv = threadIdx.x >> 6;
    for (int base = blockIdx.x * 64; base < np; base += gridDim.x * 64) {
        __syncthreads();
        {
            int row = threadIdx.x >> 2, kq = (threadIdx.x & 3) * 4;
            int p = base + row;
            float4 v = make_float4(0.f, 0.f, 0.f, 0.f);
            if (p < np) v = *(const float4*)&pinf[(size_t)p * 16 + kq];
            *(float4*)&PF[row * 20 + kq] = v;
            if (threadIdx.x < 64) {
                int pp = base + threadIdx.x;
                srcS[threadIdx.x] = (pp < np) ? psrc[pp] : 0;
                dstS[threadIdx.x] = (pp < np) ? pdst[pp] : 0;
            }
        }
        __syncthreads();
        // GEMM1: T1 = ssp(PF @ W1 + b1), K=16
        {
            float acc[4][4];
            #pragma unroll
            for (int i = 0; i < 4; i++)
                #pragma unroll
                for (int j = 0; j < 4; j++) acc[i][j] = bs1[c0 + j];
            #pragma unroll
            for (int kq = 0; kq < 16; kq += 4) {
                float4 xa[4], wa[4];
                #pragma unroll
                for (int i = 0; i < 4; i++) xa[i] = *(const float4*)&PF[(r0 + i) * 20 + kq];
                #pragma unroll
                for (int j = 0; j < 4; j++) wa[j] = *(const float4*)&Ws1[(kq + j) * 64 + c0];
                fma44(acc, xa, wa);
            }
            #pragma unroll
            for (int i = 0; i < 4; i++) {
                float4 o; float* op = (float*)&o;
                #pragma unroll
                for (int j = 0; j < 4; j++) op[j] = ssp_(acc[i][j]);
                *(float4*)&T1[(r0 + i) * 68 + c0] = o;
            }
        }
        __syncthreads();
        // GEMM2: HE = ssp(T1 @ W2 + b2), K=64 ; HE overwrites T1 (guarded)
        {
            float acc[4][4];
            #pragma unroll
            for (int i = 0; i < 4; i++)
                #pragma unroll
                for (int j = 0; j < 4; j++) acc[i][j] = bs2[c0 + j];
            #pragma unroll 4
            for (int kq = 0; kq < 64; kq += 4) {
                float4 xa[4], wa[4];
                #pragma unroll
                for (int i = 0; i < 4; i++) xa[i] = *(const float4*)&T1[(r0 + i) * 68 + kq];
                #pragma unroll
                for (int j = 0; j < 4; j++) wa[j] = *(const float4*)&Ws2[(kq + j) * 64 + c0];
                fma44(acc, xa, wa);
            }
            __syncthreads();
            #pragma unroll
            for (int i = 0; i < 4; i++) {
                float4 o; float* op = (float*)&o;
                #pragma unroll
                for (int j = 0; j < 4; j++) op[j] = ssp_(acc[i][j]);
                *(float4*)&T1[(r0 + i) * 68 + c0] = o;
            }
        }
        __syncthreads();
        // scatter: one wave per pin-row; 64 lanes = 64 contiguous channels
        #pragma unroll 4
        for (int i = 0; i < 16; i++) {
            int pl = wv * 16 + i;
            int p = base + pl;
            if (p < np) {
                float m = hv[(size_t)dstS[pl] * 64 + lane] * T1[pl * 68 + lane];
                unsafeAtomicAdd(&h_cf[(size_t)srcS[pl] * 64 + lane], m);
            }
        }
    }
}

// ---------------- SAGE gather-max over dst-CSR (one wave per node, no atomics) ----------------
__global__ __launch_bounds__(256) void sage_gather_kernel(const float* __restrict__ hp, const float* __restrict__ ew,
                                                          const int* __restrict__ esrc,
                                                          const int* __restrict__ row_start,
                                                          const int* __restrict__ eidx,
                                                          float* __restrict__ h_ng, int nn)
{
    const int lane = threadIdx.x & 63, wv = threadIdx.x >> 6;
    for (int d = blockIdx.x * 4 + wv; d < nn; d += gridDim.x * 4) {
        int rs = row_start[d], re = row_start[d + 1];
        float acc = 0.f;
        int k = rs;
        for (; k + 1 < re; k += 2) {
            int e0 = eidx[k], e1 = eidx[k + 1];
            int s0 = esrc[e0], s1 = esrc[e1];
            float w0 = ew[e0], w1 = ew[e1];
            float v0 = hp[(size_t)s0 * 64 + lane] * w0;
            float v1 = hp[(size_t)s1 * 64 + lane] * w1;
            acc = fmaxf(acc, fmaxf(v0, v1));
        }
        if (k < re) {
            int e0 = eidx[k];
            int s0 = esrc[e0];
            acc = fmaxf(acc, hp[(size_t)s0 * 64 + lane] * ew[e0]);
        }
        h_ng[(size_t)d * 64 + lane] = acc;
    }
}

// ---------------- node head (32 rows/iter, grid-stride, 3-stage MLP) ----------------
__global__ __launch_bounds__(256) void node_head3_kernel(const float* __restrict__ in_node, const float* __restrict__ nf,
                                                         const float* __restrict__ W1, const float* __restrict__ B1,
                                                         const float* __restrict__ W2, const float* __restrict__ B2,
                                                         const float* __restrict__ W3, const float* __restrict__ B3,
                                                         float* __restrict__ out, int n)
{
    __shared__ float Ws1[80 * 64], Ws2[64 * 64], Ws3[64 * 4];
    __shared__ float bs1[64], bs2[64], bs3[4];
    __shared__ float Xs[32 * 84];       // reused as H2 (stride 68)
    __shared__ float H1[32 * 68];
    for (int i = threadIdx.x; i < 80 * 64; i += 256) Ws1[i] = W1[i];
    for (int i = threadIdx.x; i < 64 * 64; i += 256) Ws2[i] = W2[i];
    for (int i = threadIdx.x; i < 64 * 4; i += 256) Ws3[i] = W3[i];
    if (threadIdx.x < 64) { bs1[threadIdx.x] = B1[threadIdx.x]; bs2[threadIdx.x] = B2[threadIdx.x]; }
    if (threadIdx.x < 4) bs3[threadIdx.x] = B3[threadIdx.x];
    const int tr = threadIdx.x >> 4, tc = threadIdx.x & 15;
    const int r0 = tr * 2, c0 = tc * 4;
    for (int base = blockIdx.x * 32; base < n; base += gridDim.x * 32) {
        __syncthreads();
        for (int i = threadIdx.x; i < 32 * 4; i += 256) {
            int row = i >> 2, kq = (i & 3) * 4;
            int g = base + row;
            float4 v = make_float4(0,0,0,0);
            if (g < n) v = *(const float4*)&in_node[(size_t)g * 16 + kq];
            *(float4*)&Xs[row * 84 + kq] = v;
        }
        for (int i = threadIdx.x; i < 32 * 16; i += 256) {
            int row = i >> 4, kq = (i & 15) * 4;
            int g = base + row;
            float4 v = make_float4(0,0,0,0);
            if (g < n) v = *(const float4*)&nf[(size_t)g * 64 + kq];
            *(float4*)&Xs[row * 84 + 16 + kq] = v;
        }
        __syncthreads();
        {
            float acc[2][4];
            #pragma unroll
            for (int i = 0; i < 2; i++)
                #pragma unroll
                for (int j = 0; j < 4; j++) acc[i][j] = bs1[c0 + j];
            #pragma unroll 4
            for (int kq = 0; kq < 80; kq += 4) {
                float4 xa[2], wa[4];
                #pragma unroll
                for (int i = 0; i < 2; i++) xa[i] = *(const float4*)&Xs[(r0 + i) * 84 + kq];
                #pragma unroll
                for (int j = 0; j < 4; j++) wa[j] = *(const float4*)&Ws1[(kq + j) * 64 + c0];
                #pragma unroll
                for (int kk = 0; kk < 4; kk++)
                    #pragma unroll
                    for (int i = 0; i < 2; i++) {
                        float x = ((const float*)&xa[i])[kk];
                        #pragma unroll
                        for (int j = 0; j < 4; j++) acc[i][j] += x * ((const float*)&wa[kk])[j];
                    }
            }
            #pragma unroll
            for (int i = 0; i < 2; i++) {
                float4 o; float* op = (float*)&o;
                #pragma unroll
                for (int j = 0; j < 4; j++) op[j] = lrelu_(acc[i][j]);
                *(float4*)&H1[(r0 + i) * 68 + c0] = o;
            }
        }
        __syncthreads();
        float* H2 = Xs;
        {
            float acc[2][4];
            #pragma unroll
            for (int i = 0; i < 2; i++)
                #pragma unroll
                for (int j = 0; j < 4; j++) acc[i][j] = bs2[c0 + j];
            #pragma unroll 4
            for (int kq = 0; kq < 64; kq += 4) {
                float4 xa[2], wa[4];
                #pragma unroll
                for (int i = 0; i < 2; i++) xa[i] = *(const float4*)&H1[(r0 + i) * 68 + kq];
                #pragma unroll
                for (int j = 0; j < 4; j++) wa[j] = *(const float4*)&Ws2[(kq + j) * 64 + c0];
                #pragma unroll
                for (int kk = 0; kk < 4; kk++)
                    #pragma unroll
                    for (int i = 0; i < 2; i++) {
                        float x = ((const float*)&xa[i])[kk];
                        #pragma unroll
                        for (int j = 0; j < 4; j++) acc[i][j] += x * ((const float*)&wa[kk])[j];
                    }
            }
            __syncthreads();
            #pragma unroll
            for (int i = 0; i < 2; i++) {
                float4 o; float* op = (float*)&o;
                #pragma unroll
                for (int j = 0; j < 4; j++) op[j] = lrelu_(acc[i][j]);
                *(float4*)&H2[(r0 + i) * 68 + c0] = o;
            }
        }
        __syncthreads();
        if (threadIdx.x < 128) {
            int row = threadIdx.x >> 2, c = threadIdx.x & 3;
            float acc = bs3[c];
            #pragma unroll 4
            for (int kq = 0; kq < 64; kq += 4) {
                float4 h = *(const float4*)&H2[row * 68 + kq];
                #pragma unroll
                for (int j = 0; j < 4; j++) acc += ((const float*)&h)[j] * Ws3[(kq + j) * 4 + c];
            }
            int g = base + row;
            if (g < n) out[(size_t)g * 4 + c] = sigm_(acc);
        }
    }
}

// ---------------- net head (32 rows/iter, grid-stride, C_out=1) ----------------
__global__ __launch_bounds__(256) void net_head3_kernel(const float* __restrict__ in_net, const float* __restrict__ tf,
                                                        const float* __restrict__ W1, const float* __restrict__ B1,
                                                        const float* __restrict__ W2, const float* __restrict__ B2,
                                                        const float* __restrict__ W3, const float* __restrict__ B3,
                                                        float* __restrict__ out, int n)
{
    __shared__ float Ws1[72 * 64], Ws2[64 * 64], Ws3[64];
    __shared__ float bs1[64], bs2[64], bs3[1];
    __shared__ float Xs[32 * 76];       // reused as H2 (stride 68)
    __shared__ float H1[32 * 68];
    for (int i = threadIdx.x; i < 72 * 64; i += 256) Ws1[i] = W1[i];
    for (int i = threadIdx.x; i < 64 * 64; i += 256) Ws2[i] = W2[i];
    if (threadIdx.x < 64) { Ws3[threadIdx.x] = W3[threadIdx.x]; bs1[threadIdx.x] = B1[threadIdx.x]; bs2[threadIdx.x] = B2[threadIdx.x]; }
    if (threadIdx.x == 0) bs3[0] = B3[0];
    const int tr = threadIdx.x >> 4, tc = threadIdx.x & 15;
    const int r0 = tr * 2, c0 = tc * 4;
    for (int base = blockIdx.x * 32; base < n; base += gridDim.x * 32) {
        __syncthreads();
        for (int i = threadIdx.x; i < 32 * 2; i += 256) {
            int row = i >> 1, kq = (i & 1) * 4;
            int g = base + row;
            float4 v = make_float4(0,0,0,0);
            if (g < n) v = *(const float4*)&in_net[(size_t)g * 8 + kq];
            *(float4*)&Xs[row * 76 + kq] = v;
        }
        for (int i = threadIdx.x; i < 32 * 16; i += 256) {
            int row = i >> 4, kq = (i & 15) * 4;
            int g = base + row;
            float4 v = make_float4(0,0,0,0);
            if (g < n) v = *(const float4*)&tf[(size_t)g * 64 + kq];
            *(float4*)&Xs[row * 76 + 8 + kq] = v;
        }
        __syncthreads();
        {
            float acc[2][4];
            #pragma unroll
            for (int i = 0; i < 2; i++)
                #pragma unroll
                for (int j = 0; j < 4; j++) acc[i][j] = bs1[c0 + j];
            #pragma unroll 4
            for (int kq = 0; kq < 72; kq += 4) {
                float4 xa[2], wa[4];
                #pragma unroll
                for (int i = 0; i < 2; i++) xa[i] = *(const float4*)&Xs[(r0 + i) * 76 + kq];
                #pragma unroll
                for (int j = 0; j < 4; j++) wa[j] = *(const float4*)&Ws1[(kq + j) * 64 + c0];
                #pragma unroll
                for (int kk = 0; kk < 4; kk++)
                    #pragma unroll
                    for (int i = 0; i < 2; i++) {
                        float x = ((const float*)&xa[i])[kk];
                        #pragma unroll
                        for (int j = 0; j < 4; j++) acc[i][j] += x * ((const float*)&wa[kk])[j];
                    }
            }
            #pragma unroll
            for (int i = 0; i < 2; i++) {
                float4 o; float* op = (float*)&o;
                #pragma unroll
                for (int j = 0; j < 4; j++) op[j] = lrelu_(acc[i][j]);
                *(float4*)&H1[(r0 + i) * 68 + c0] = o;
            }
        }
        __syncthreads();
        float* H2 = Xs;
        {
            float acc[2][4];
            #pragma unroll
            for (int i = 0; i < 2; i++)
                #pragma unroll
                for (int j = 0; j < 4; j++) acc[i][j] = bs2[c0 + j];
            #pragma unroll 4
            for (int kq = 0; kq < 64; kq += 4) {
                float4 xa[2], wa[4];
                #pragma unroll
                for (int i = 0; i < 2; i++) xa[i] = *(const float4*)&H1[(r0 + i) * 68 + kq];
                #pragma unroll
                for (int j = 0; j < 4; j++) wa[j] = *(const float4*)&Ws2[(kq + j) * 64 + c0];
                #pragma unroll
                for (int kk = 0; kk < 4; kk++)
                    #pragma unroll
                    for (int i = 0; i < 2; i++) {
                        float x = ((const float*)&xa[i])[kk];
                        #pragma unroll
                        for (int j = 0; j < 4; j++) acc[i][j] += x * ((const float*)&wa[kk])[j];
                    }
            }
            __syncthreads();
            #pragma unroll
            for (int i = 0; i < 2; i++) {
                float4 o; float* op = (float*)&o;
                #pragma unroll
                for (int j = 0; j < 4; j++) op[j] = lrelu_(acc[i][j]);
                *(float4*)&H2[(r0 + i) * 68 + c0] = o;
            }
        }
        __syncthreads();
        if (threadIdx.x < 32) {
            int row = threadIdx.x;
            float acc = bs3[0];
            #pragma unroll 4
            for (int kq = 0; kq < 64; kq += 4) {
                float4 h = *(const float4*)&H2[row * 68 + kq];
                float4 w = *(const float4*)&Ws3[kq];
                acc += h.x * w.x + h.y * w.y + h.z * w.z + h.w * w.w;
            }
            int g = base + row;
            if (g < n) out[g] = sigm_(acc);
        }
    }
}

extern "C" void kernel_launch(void* const* d_in, const int* in_sizes, int n_in,
                              void* d_out, int out_size, void* d_ws, size_t ws_size,
                              hipStream_t stream)
{
    (void)in_sizes; (void)n_in; (void)out_size; (void)ws_size;
    constexpr int Nn = 100000, Nt = 30000, Np = 400000, Ne = 1000000;
    constexpr int H = 64, L = 3, T = 4;

    auto fpt = [&](int i){ return (const float*)d_in[i]; };
    auto ipt = [&](int i){ return (const int*)d_in[i]; };

    const float* in_node = fpt(0);
    const float* in_net  = fpt(1);
    const float* in_pin  = fpt(2);
    const float* in_edge = fpt(3);
    const int* psrc = ipt(4);
    const int* pdst = ipt(5);
    const int* esrc = ipt(6);
    const int* edst = ipt(7);

    float* ws = (float*)d_ws;
    size_t o = 0;
    auto alloc = [&](size_t nel){ float* p = ws + o; o += nel; return p; };
    float* node_a = alloc((size_t)Nn * H);
    float* node_b = alloc((size_t)Nn * H);
    float* net_a  = alloc((size_t)Nt * H);
    float* net_b  = alloc((size_t)Nt * H);
    float* agg    = alloc((size_t)Nt * H);
    float* hv     = alloc((size_t)Nt * H);
    float* pinf   = alloc((size_t)Np * 16);
    float* h_cf   = alloc((size_t)Nn * H);
    float* hp     = alloc((size_t)Nn * H);   // SAGE pool / linear accumulator
    float* h_ng   = alloc((size_t)Nn * H);
    float* ew3    = alloc((size_t)3 * Ne);
    float* snorm  = alloc((size_t)Nn);
    float* dnorm  = alloc((size_t)Nt);
    // CSR workspace: near (keyed by edst, Nn rows) and pins (keyed by pdst, Nt rows)
    int* cnt       = (int*)alloc((size_t)Nn);
    int* row_start = (int*)alloc((size_t)Nn + 1);
    int* nxt       = (int*)alloc((size_t)Nn);
    int* eidx      = (int*)alloc((size_t)Ne);
    int* bsum      = (int*)alloc((size_t)512);
    int* pcnt      = (int*)alloc((size_t)Nt);
    int* prow      = (int*)alloc((size_t)Nt + 1);
    int* pnxt      = (int*)alloc((size_t)Nt);
    int* peidx     = (int*)alloc((size_t)Np);
    int* pbsum     = (int*)alloc((size_t)256);

    constexpr int NB  = (Nn + 255) / 256;   // 391 blocks (near scan)
    constexpr int NB2 = (Nt + 255) / 256;   // 118 blocks (pins scan)

    // degree norms for pins
    hipMemsetAsync(snorm, 0, (size_t)Nn * 4, stream);
    hipMemsetAsync(dnorm, 0, (size_t)Nt * 4, stream);
    deg_kernel<<<(Np + 255) / 256, 256, 0, stream>>>(psrc, pdst, (int*)snorm, (int*)dnorm, Np);
    norm_kernel<<<(Nn + 255) / 256, 256, 0, stream>>>((int*)snorm, Nn);
    norm_kernel<<<(Nt + 255) / 256, 256, 0, stream>>>((int*)dnorm, Nt);

    // build dst-CSR for 'near' (edst -> Nn rows)
    hipMemsetAsync(cnt, 0, (size_t)Nn * 4, stream);
    csr_count_kernel<<<(Ne + 255) / 256, 256, 0, stream>>>(edst, cnt, Ne);
    scan_block_sum_kernel<<<NB, 256, 0, stream>>>(cnt, bsum, Nn);
    scan_bsum_kernel<<<1, 64, 0, stream>>>(bsum, NB, row_start + Nn);
    scan_final_kernel<<<NB, 256, 0, stream>>>(cnt, bsum, row_start, nxt, Nn);
    csr_fill_kernel<<<(Ne + 255) / 256, 256, 0, stream>>>(edst, nxt, eidx, Ne);

    // build dst-CSR for 'pins' (pdst -> Nt rows)
    hipMemsetAsync(pcnt, 0, (size_t)Nt * 4, stream);
    csr_count_kernel<<<(Np + 255) / 256, 256, 0, stream>>>(pdst, pcnt, Np);
    scan_block_sum_kernel<<<NB2, 256, 0, stream>>>(pcnt, pbsum, Nt);
    scan_bsum_kernel<<<1, 64, 0, stream>>>(pbsum, NB2, prow + Nt);
    scan_final_kernel<<<NB2, 256, 0, stream>>>(pcnt, pbsum, prow, pnxt, Nt);
    csr_fill_kernel<<<(Np + 255) / 256, 256, 0, stream>>>(pdst, pnxt, peidx, Np);

    // input encoders
    gemm64_kernel<16, 1, false, false><<<1024, 256, 0, stream>>>(in_node, nullptr, fpt(8),  fpt(9),  nullptr, node_a, Nn);
    gemm64_kernel< 8, 1, false, false><<<469, 256, 0, stream>>>(in_net,  nullptr, fpt(10), fpt(11), nullptr, net_a,  Nt);
    lin_kernel<8, 16, 1><<<1024, 256, 0, stream>>>(in_pin, fpt(12), fpt(13), pinf, Np);
    edge_ew_kernel<<<2048, 256, 0, stream>>>(in_edge, fpt(14), fpt(15), fpt(16), fpt(17), ew3, Ne);

    float* ncur = node_a; float* nnew = node_b;
    float* tcur = net_a;  float* tnew = net_b;

    for (int i = 0; i < L; i++) {
        // pins GraphConv (node -> net): gather over pdst-CSR, dnorm folded
        pins_gather_kernel<<<(Nt + 3) / 4, 256, 0, stream>>>(ncur, snorm, dnorm, psrc, prow, peidx, agg, Nt);
        gemm64_kernel<64, 1, false, false><<<469, 256, 0, stream>>>(agg, nullptr, fpt(18) + (size_t)i * 4096, fpt(19) + (size_t)i * 64, nullptr, tnew, Nt);

        // CFConv (net -> node)
        gemm64_kernel<64, 0, false, false><<<469, 256, 0, stream>>>(tcur, nullptr, fpt(20) + (size_t)i * 4096, fpt(21) + (size_t)i * 64, nullptr, hv, Nt);
        hipMemsetAsync(h_cf, 0, (size_t)Nn * H * 4, stream);
        cf_pin4_kernel<<<1024, 256, 0, stream>>>(pinf, hv, psrc, pdst,
                                                 fpt(22) + (size_t)i * 1024, fpt(23) + (size_t)i * 64,
                                                 fpt(24) + (size_t)i * 4096, fpt(25) + (size_t)i * 64,
                                                 h_cf, Np);

        // SAGE (near): hp = relu(ncur @ pool + b), gather-max over dst-CSR
        gemm64_kernel<64, 2, false, false><<<1024, 256, 0, stream>>>(ncur, nullptr, fpt(28) + (size_t)i * 4096, fpt(29) + (size_t)i * 64, nullptr, hp, Nn);
        sage_gather_kernel<<<(Nn + 3) / 4, 256, 0, stream>>>(hp, ew3 + (size_t)i * Ne, esrc, row_start, eidx, h_ng, Nn);

        // combine:
        // hp (reused) = ncur @ sage_self + h_ng @ sage_neigh + sage_bias   (single dual-GEMM pass)
        gemm64_dual_kernel<<<1024, 256, 0, stream>>>(ncur, h_ng,
                                                     fpt(30) + (size_t)i * 4096, fpt(31) + (size_t)i * 4096,
                                                     fpt(32) + (size_t)i * 64, hp, Nn);
        // nnew = lrelu(max(ssp(h_cf @ cf_out + b), hp))   (fused ACT=4)
        gemm64_kernel<64, 4, false, false><<<1024, 256, 0, stream>>>(h_cf, nullptr, fpt(26) + (size_t)i * 4096, fpt(27) + (size_t)i * 64, hp, nnew, Nn);

        float* t;
        t = ncur; ncur = nnew; nnew = t;
        t = tcur; tcur = tnew; tnew = t;
    }

    float* out = (float*)d_out;
    node_head3_kernel<<<640, 256, 0, stream>>>(in_node, ncur, fpt(33), fpt(34), fpt(35), fpt(36), fpt(37), fpt(38), out, Nn);
    net_head3_kernel<<<480, 256, 0, stream>>>(in_net, tcur, fpt(39), fpt(40), fpt(41), fpt(42), fpt(43), fpt(44), out + (size_t)Nn * T, Nt);
}

// Round 9
// 1619.493 us; speedup vs baseline: 9.0953x; 1.1215x over previous
//
#include <hip/hip_runtime.h>
#include <hip/hip_bf16.h>

#define DEV __device__ __forceinline__

DEV float lrelu_(float x){ return x > 0.f ? x : 0.01f * x; }
DEV float ssp_(float x){ return fmaxf(x, 0.f) + __logf(1.f + __expf(-fabsf(x))) - 0.69314718055994530942f; }
DEV float sigm_(float x){ return 1.f / (1.f + __expf(-x)); }

DEV unsigned short f2bf(float x){
    unsigned int u = __float_as_uint(x);
    unsigned int r = (u + 0x7FFFu + ((u >> 16) & 1u)) >> 16;
    return (unsigned short)r;
}
DEV float bf2f(unsigned short s){ return __uint_as_float((unsigned int)s << 16); }

DEV void fma44(float (&acc)[4][4], const float4 (&xa)[4], const float4 (&wa)[4])
{
    #pragma unroll
    for (int kk = 0; kk < 4; kk++) {
        #pragma unroll
        for (int i = 0; i < 4; i++) {
            float x = ((const float*)&xa[i])[kk];
            #pragma unroll
            for (int j = 0; j < 4; j++)
                acc[i][j] += x * ((const float*)&wa[kk])[j];
        }
    }
}

// ====== generic tiled GEMM: Y[N x 64] = act( (X .* scale?) @ W[K x 64] + b ) ====
// ACT: 0=none 1=lrelu 2=relu 3=ssp 4=lrelu(max(ssp(acc+b), P))   ADD: acc += P
template<int K, int ACT, bool SCALE, bool ADD>
__global__ __launch_bounds__(256) void gemm64_kernel(const float* __restrict__ X,
                                                     const float* __restrict__ scale,
                                                     const float* __restrict__ W,
                                                     const float* __restrict__ B,
                                                     const float* __restrict__ P,
                                                     float* __restrict__ Y, int nrows)
{
    constexpr int XS = K + 4;
    constexpr int KQ = K / 4;
    __shared__ float Ws[K * 64];
    __shared__ float bs[64];
    __shared__ float Xs[64 * XS];
    for (int i = threadIdx.x; i < K * 64; i += 256) Ws[i] = W[i];
    if (threadIdx.x < 64) bs[threadIdx.x] = ADD ? 0.f : B[threadIdx.x];
    const int tr = threadIdx.x >> 4, tc = threadIdx.x & 15;
    const int r0 = tr * 4, c0 = tc * 4;
    for (int base = blockIdx.x * 64; base < nrows; base += gridDim.x * 64) {
        __syncthreads();
        for (int i = threadIdx.x; i < 64 * KQ; i += 256) {
            int row = i / KQ, kq = (i % KQ) * 4;
            int g = base + row;
            float4 v = make_float4(0.f, 0.f, 0.f, 0.f);
            if (g < nrows) {
                v = *(const float4*)&X[(size_t)g * K + kq];
                if (SCALE) { float s = scale[g]; v.x *= s; v.y *= s; v.z *= s; v.w *= s; }
            }
            *(float4*)&Xs[row * XS + kq] = v;
        }
        __syncthreads();
        float acc[4][4];
        #pragma unroll
        for (int i = 0; i < 4; i++)
            #pragma unroll
            for (int j = 0; j < 4; j++) acc[i][j] = bs[c0 + j];
        #pragma unroll 4
        for (int kq = 0; kq < K; kq += 4) {
            float4 xa[4], wa[4];
            #pragma unroll
            for (int i = 0; i < 4; i++) xa[i] = *(const float4*)&Xs[(r0 + i) * XS + kq];
            #pragma unroll
            for (int j = 0; j < 4; j++) wa[j] = *(const float4*)&Ws[(kq + j) * 64 + c0];
            fma44(acc, xa, wa);
        }
        #pragma unroll
        for (int i = 0; i < 4; i++) {
            int g = base + r0 + i;
            if (g < nrows) {
                float4 prev = make_float4(0,0,0,0);
                if (ADD || ACT == 4) prev = *(const float4*)&P[(size_t)g * 64 + c0];
                float4 o;
                float* op = (float*)&o;
                #pragma unroll
                for (int j = 0; j < 4; j++) {
                    float a = acc[i][j];
                    if (ADD) a += ((const float*)&prev)[j];
                    if (ACT == 1) a = lrelu_(a);
                    else if (ACT == 2) a = fmaxf(a, 0.f);
                    else if (ACT == 3) a = ssp_(a);
                    else if (ACT == 4) a = lrelu_(fmaxf(ssp_(a), ((const float*)&prev)[j]));
                    op[j] = a;
                }
                *(float4*)&Y[(size_t)g * 64 + c0] = o;
            }
        }
    }
}

// ====== dual GEMM: Y[N x 64] = X1 @ W1 + X2 @ W2 + b   (no activation) ======
__global__ __launch_bounds__(256) void gemm64_dual_kernel(const float* __restrict__ X1,
                                                          const float* __restrict__ X2,
                                                          const float* __restrict__ W1g,
                                                          const float* __restrict__ W2g,
                                                          const float* __restrict__ B,
                                                          float* __restrict__ Y, int nrows)
{
    __shared__ float Ws1[64 * 64], Ws2[64 * 64], bs[64];
    __shared__ float Xs1[32 * 68], Xs2[32 * 68];
    for (int i = threadIdx.x; i < 64 * 64; i += 256) { Ws1[i] = W1g[i]; Ws2[i] = W2g[i]; }
    if (threadIdx.x < 64) bs[threadIdx.x] = B[threadIdx.x];
    const int tr = threadIdx.x >> 4, tc = threadIdx.x & 15;
    const int r0 = tr * 2, c0 = tc * 4;
    for (int base = blockIdx.x * 32; base < nrows; base += gridDim.x * 32) {
        __syncthreads();
        for (int i = threadIdx.x; i < 512; i += 256) {
            int row = i >> 4, kq = (i & 15) * 4;
            int g = base + row;
            float4 a = make_float4(0,0,0,0), b = a;
            if (g < nrows) {
                a = *(const float4*)&X1[(size_t)g * 64 + kq];
                b = *(const float4*)&X2[(size_t)g * 64 + kq];
            }
            *(float4*)&Xs1[row * 68 + kq] = a;
            *(float4*)&Xs2[row * 68 + kq] = b;
        }
        __syncthreads();
        float acc[2][4];
        #pragma unroll
        for (int i = 0; i < 2; i++)
            #pragma unroll
            for (int j = 0; j < 4; j++) acc[i][j] = bs[c0 + j];
        #pragma unroll 4
        for (int kq = 0; kq < 64; kq += 4) {
            float4 xa1[2], xa2[2];
            #pragma unroll
            for (int i = 0; i < 2; i++) {
                xa1[i] = *(const float4*)&Xs1[(r0 + i) * 68 + kq];
                xa2[i] = *(const float4*)&Xs2[(r0 + i) * 68 + kq];
            }
            #pragma unroll
            for (int kk = 0; kk < 4; kk++) {
                float4 w1 = *(const float4*)&Ws1[(kq + kk) * 64 + c0];
                float4 w2 = *(const float4*)&Ws2[(kq + kk) * 64 + c0];
                #pragma unroll
                for (int i = 0; i < 2; i++) {
                    float x1 = ((const float*)&xa1[i])[kk];
                    float x2 = ((const float*)&xa2[i])[kk];
                    #pragma unroll
                    for (int j = 0; j < 4; j++)
                        acc[i][j] += x1 * ((const float*)&w1)[j] + x2 * ((const float*)&w2)[j];
                }
            }
        }
        #pragma unroll
        for (int i = 0; i < 2; i++) {
            int g = base + r0 + i;
            if (g < nrows) *(float4*)&Y[(size_t)g * 64 + c0] = *(float4*)&acc[i][0];
        }
    }
}

// ---------------- small scalar GEMV (pin encoder, C=16) ----------------
template<int K, int C, int ACT>
__global__ __launch_bounds__(256) void lin_kernel(const float* __restrict__ X,
                                                  const float* __restrict__ W,
                                                  const float* __restrict__ B,
                                                  float* __restrict__ Y, int nrows)
{
    constexpr int ROWS = 256 / C;
    __shared__ float Ws[K * C];
    __shared__ float bs[C];
    __shared__ float Xs[ROWS * K];
    for (int i = threadIdx.x; i < K * C; i += 256) Ws[i] = W[i];
    if (threadIdx.x < C) bs[threadIdx.x] = B[threadIdx.x];
    __syncthreads();
    const int r = threadIdx.x / C, c = threadIdx.x % C;
    for (int base = blockIdx.x * ROWS; base < nrows; base += gridDim.x * ROWS) {
        __syncthreads();
        for (int i = threadIdx.x; i < ROWS * K; i += 256) {
            int rr = base + i / K;
            Xs[i] = (rr < nrows) ? X[(size_t)rr * K + i % K] : 0.f;
        }
        __syncthreads();
        int row = base + r;
        if (row < nrows) {
            float acc = bs[c];
            #pragma unroll
            for (int k = 0; k < K; k++) acc += Xs[r * K + k] * Ws[k * C + c];
            if (ACT == 1) acc = lrelu_(acc);
            else if (ACT == 2) acc = fmaxf(acc, 0.f);
            Y[(size_t)row * C + c] = acc;
        }
    }
}

// ---------------- degrees (for pins norms) ----------------
__global__ __launch_bounds__(256) void deg_kernel(const int* __restrict__ src, const int* __restrict__ dst,
                                                  int* __restrict__ degs, int* __restrict__ degd, int np)
{
    int p = blockIdx.x * 256 + threadIdx.x;
    if (p < np) { atomicAdd(&degs[src[p]], 1); atomicAdd(&degd[dst[p]], 1); }
}

__global__ __launch_bounds__(256) void norm_kernel(int* __restrict__ arr, int n)
{
    int i = blockIdx.x * 256 + threadIdx.x;
    if (i < n) {
        int v = arr[i]; if (v < 1) v = 1;
        arr[i] = __float_as_int(rsqrtf((float)v));
    }
}

// ================= CSR build (generic, keyed by given index array) =================
__global__ __launch_bounds__(256) void csr_count_kernel(const int* __restrict__ key, int* __restrict__ cnt, int ne)
{
    int e = blockIdx.x * 256 + threadIdx.x;
    if (e < ne) atomicAdd(&cnt[key[e]], 1);
}

__global__ __launch_bounds__(256) void scan_block_sum_kernel(const int* __restrict__ cnt, int* __restrict__ bsum, int n)
{
    __shared__ int sh[256];
    int i = blockIdx.x * 256 + threadIdx.x;
    sh[threadIdx.x] = (i < n) ? cnt[i] : 0;
    __syncthreads();
    for (int s = 128; s > 0; s >>= 1) {
        if (threadIdx.x < s) sh[threadIdx.x] += sh[threadIdx.x + s];
        __syncthreads();
    }
    if (threadIdx.x == 0) bsum[blockIdx.x] = sh[0];
}

__global__ void scan_bsum_kernel(int* __restrict__ bsum, int nb, int* __restrict__ total_out)
{
    if (threadIdx.x == 0 && blockIdx.x == 0) {
        int run = 0;
        for (int i = 0; i < nb; i++) { int v = bsum[i]; bsum[i] = run; run += v; }
        *total_out = run;
    }
}

__global__ __launch_bounds__(256) void scan_final_kernel(const int* __restrict__ cnt, const int* __restrict__ bsum,
                                                         int* __restrict__ row_start, int* __restrict__ nxt, int n)
{
    __shared__ int sh[256];
    int i = blockIdx.x * 256 + threadIdx.x;
    int v = (i < n) ? cnt[i] : 0;
    sh[threadIdx.x] = v;
    __syncthreads();
    for (int s = 1; s < 256; s <<= 1) {
        int add = (threadIdx.x >= s) ? sh[threadIdx.x - s] : 0;
        __syncthreads();
        sh[threadIdx.x] += add;
        __syncthreads();
    }
    if (i < n) {
        int excl = sh[threadIdx.x] - v + bsum[blockIdx.x];
        row_start[i] = excl;
        nxt[i] = excl;
    }
}

__global__ __launch_bounds__(256) void csr_fill_kernel(const int* __restrict__ key, int* __restrict__ nxt,
                                                       int* __restrict__ eidx, int ne)
{
    int e = blockIdx.x * 256 + threadIdx.x;
    if (e < ne) {
        int slot = atomicAdd(&nxt[key[e]], 1);
        eidx[slot] = e;
    }
}

// ---------------- edge weights for all 3 layers ----------------
__global__ __launch_bounds__(256) void edge_ew_kernel(const float* __restrict__ in_edge,
                                                      const float* __restrict__ elW, const float* __restrict__ elb,
                                                      const float* __restrict__ gW, const float* __restrict__ gb,
                                                      float* __restrict__ ew3, int ne)
{
    __shared__ float W[32], B[8], G[24], Gb[3];
    if (threadIdx.x < 32) W[threadIdx.x] = elW[threadIdx.x];
    if (threadIdx.x < 8)  B[threadIdx.x] = elb[threadIdx.x];
    if (threadIdx.x < 24) G[threadIdx.x] = gW[threadIdx.x];
    if (threadIdx.x < 3)  Gb[threadIdx.x] = gb[threadIdx.x];
    __syncthreads();
    for (int e = blockIdx.x * 256 + threadIdx.x; e < ne; e += gridDim.x * 256) {
        float4 x = *(const float4*)&in_edge[(size_t)e * 4];
        float ef[8];
        #pragma unroll
        for (int j = 0; j < 8; j++)
            ef[j] = lrelu_(B[j] + x.x * W[j] + x.y * W[8 + j] + x.z * W[16 + j] + x.w * W[24 + j]);
        #pragma unroll
        for (int i = 0; i < 3; i++) {
            float a = Gb[i];
            #pragma unroll
            for (int j = 0; j < 8; j++) a += ef[j] * G[i * 8 + j];
            ew3[(size_t)i * ne + e] = sigm_(a);
        }
    }
}

// ---------------- pins GraphConv gather over pdst-CSR (one wave per net, no atomics) -------------
__global__ __launch_bounds__(256) void pins_gather_kernel(const float* __restrict__ nf, const float* __restrict__ snorm,
                                                          const float* __restrict__ dnorm,
                                                          const int* __restrict__ psrc,
                                                          const int* __restrict__ prow,
                                                          const int* __restrict__ peidx,
                                                          float* __restrict__ agg, int nt)
{
    const int lane = threadIdx.x & 63, wv = threadIdx.x >> 6;
    for (int d = blockIdx.x * 4 + wv; d < nt; d += gridDim.x * 4) {
        int rs = prow[d], re = prow[d + 1];
        float acc = 0.f;
        int k = rs;
        for (; k + 1 < re; k += 2) {
            int p0 = peidx[k], p1 = peidx[k + 1];
            int s0 = psrc[p0], s1 = psrc[p1];
            float n0 = snorm[s0], n1 = snorm[s1];
            float v0 = nf[(size_t)s0 * 64 + lane] * n0;
            float v1 = nf[(size_t)s1 * 64 + lane] * n1;
            acc += v0 + v1;
        }
        if (k < re) {
            int p0 = peidx[k];
            int s0 = psrc[p0];
            acc += nf[(size_t)s0 * 64 + lane] * snorm[s0];
        }
        agg[(size_t)d * 64 + lane] = acc * dnorm[d];
    }
}

// ---------------- CFConv fused: GEMM1 VALU + GEMM2 bf16-MFMA + dense wave scatter ----------------
__global__ __launch_bounds__(256) void cf_pin5_kernel(const float* __restrict__ pinf, const float* __restrict__ hv,
                                                      const int* __restrict__ psrc, const int* __restrict__ pdst,
                                                      const float* __restrict__ W1, const float* __restrict__ B1,
                                                      const float* __restrict__ W2, const float* __restrict__ B2,
                                                      float* __restrict__ h_cf, int np)
{
    typedef short s8v __attribute__((ext_vector_type(8)));
    typedef float f4v __attribute__((ext_vector_type(4)));
    __shared__ float Ws1[16 * 64], bs1[64], bs2[64];
    __shared__ __align__(16) unsigned short W2T[64 * 72];  // B operand: [n][k] bf16
    __shared__ __align__(16) unsigned short T1s[64 * 72];  // A operand rows [p][k] bf16; reused as HE
    __shared__ float PF[64 * 20];
    __shared__ int srcS[64], dstS[64];
    for (int i = threadIdx.x; i < 16 * 64; i += 256) Ws1[i] = W1[i];
    for (int i = threadIdx.x; i < 64 * 64; i += 256) {
        int k = i >> 6, n = i & 63;
        W2T[n * 72 + k] = f2bf(W2[i]);
    }
    if (threadIdx.x < 64) { bs1[threadIdx.x] = B1[threadIdx.x]; bs2[threadIdx.x] = B2[threadIdx.x]; }
    const int tr = threadIdx.x >> 4, tc = threadIdx.x & 15;
    const int r0 = tr * 4, c0 = tc * 4;
    const int lane = threadIdx.x & 63, wv = threadIdx.x >> 6;
    const int l15 = lane & 15, quad = lane >> 4;
    const int arow = 16 * wv + l15;          // A-operand row for this lane
    const int koff = quad * 8;               // A/B k-offset for this lane
    for (int base = blockIdx.x * 64; base < np; base += gridDim.x * 64) {
        __syncthreads();
        {
            int row = threadIdx.x >> 2, kq = (threadIdx.x & 3) * 4;
            int p = base + row;
            float4 v = make_float4(0.f, 0.f, 0.f, 0.f);
            if (p < np) v = *(const float4*)&pinf[(size_t)p * 16 + kq];
            *(float4*)&PF[row * 20 + kq] = v;
            if (threadIdx.x < 64) {
                int pp = base + threadIdx.x;
                srcS[threadIdx.x] = (pp < np) ? psrc[pp] : 0;
                dstS[threadIdx.x] = (pp < np) ? pdst[pp] : 0;
            }
        }
        __syncthreads();
        // GEMM1 (VALU, K=16): T1 = ssp(PF @ W1 + b1) -> bf16 LDS rows
        {
            float acc[4][4];
            #pragma unroll
            for (int i = 0; i < 4; i++)
                #pragma unroll
                for (int j = 0; j < 4; j++) acc[i][j] = bs1[c0 + j];
            #pragma unroll
            for (int kq = 0; kq < 16; kq += 4) {
                float4 xa[4], wa[4];
                #pragma unroll
                for (int i = 0; i < 4; i++) xa[i] = *(const float4*)&PF[(r0 + i) * 20 + kq];
                #pragma unroll
                for (int j = 0; j < 4; j++) wa[j] = *(const float4*)&Ws1[(kq + j) * 64 + c0];
                fma44(acc, xa, wa);
            }
            #pragma unroll
            for (int i = 0; i < 4; i++) {
                ushort4 o;
                o.x = f2bf(ssp_(acc[i][0]));
                o.y = f2bf(ssp_(acc[i][1]));
                o.z = f2bf(ssp_(acc[i][2]));
                o.w = f2bf(ssp_(acc[i][3]));
                *(ushort4*)&T1s[(r0 + i) * 72 + c0] = o;
            }
        }
        __syncthreads();
        // GEMM2 (MFMA bf16): HE = ssp(T1 @ W2 + b2); wave w computes rows 16w..16w+15
        {
            f4v acc4[4];
            #pragma unroll
            for (int t = 0; t < 4; t++) acc4[t] = (f4v){0.f, 0.f, 0.f, 0.f};
            s8v a0 = *(const s8v*)&T1s[arow * 72 + koff];
            s8v a1 = *(const s8v*)&T1s[arow * 72 + 32 + koff];
            #pragma unroll
            for (int t = 0; t < 4; t++) {
                int n = t * 16 + l15;
                s8v b0 = *(const s8v*)&W2T[n * 72 + koff];
                s8v b1 = *(const s8v*)&W2T[n * 72 + 32 + koff];
                acc4[t] = __builtin_amdgcn_mfma_f32_16x16x32_bf16(a0, b0, acc4[t], 0, 0, 0);
                acc4[t] = __builtin_amdgcn_mfma_f32_16x16x32_bf16(a1, b1, acc4[t], 0, 0, 0);
            }
            __syncthreads();   // all A reads done; safe to overwrite T1s with HE
            const int mrow = 16 * wv + quad * 4;
            #pragma unroll
            for (int t = 0; t < 4; t++) {
                int col = t * 16 + l15;
                float b = bs2[col];
                #pragma unroll
                for (int r = 0; r < 4; r++)
                    T1s[(mrow + r) * 72 + col] = f2bf(ssp_(acc4[t][r] + b));
            }
        }
        __syncthreads();
        // scatter: one wave per pin-row; 64 lanes = 64 contiguous channels
        #pragma unroll 4
        for (int i = 0; i < 16; i++) {
            int pl = wv * 16 + i;
            int p = base + pl;
            if (p < np) {
                float m = hv[(size_t)dstS[pl] * 64 + lane] * bf2f(T1s[pl * 72 + lane]);
                unsafeAtomicAdd(&h_cf[(size_t)srcS[pl] * 64 + lane], m);
            }
        }
    }
}

// ---------------- SAGE gather-max over dst-CSR (one wave per node, no atomics) ----------------
__global__ __launch_bounds__(256) void sage_gather_kernel(const float* __restrict__ hp, const float* __restrict__ ew,
                                                          const int* __restrict__ esrc,
                                                          const int* __restrict__ row_start,
                                                          const int* __restrict__ eidx,
                                                          float* __restrict__ h_ng, int nn)
{
    const int lane = threadIdx.x & 63, wv = threadIdx.x >> 6;
    for (int d = blockIdx.x * 4 + wv; d < nn; d += gridDim.x * 4) {
        int rs = row_start[d], re = row_start[d + 1];
        float acc = 0.f;
        int k = rs;
        for (; k + 1 < re; k += 2) {
            int e0 = eidx[k], e1 = eidx[k + 1];
            int s0 = esrc[e0], s1 = esrc[e1];
            float w0 = ew[e0], w1 = ew[e1];
            float v0 = hp[(size_t)s0 * 64 + lane] * w0;
            float v1 = hp[(size_t)s1 * 64 + lane] * w1;
            acc = fmaxf(acc, fmaxf(v0, v1));
        }
        if (k < re) {
            int e0 = eidx[k];
            int s0 = esrc[e0];
            acc = fmaxf(acc, hp[(size_t)s0 * 64 + lane] * ew[e0]);
        }
        h_ng[(size_t)d * 64 + lane] = acc;
    }
}

// ---------------- node head (32 rows/iter, grid-stride, 3-stage MLP) ----------------
__global__ __launch_bounds__(256) void node_head3_kernel(const float* __restrict__ in_node, const float* __restrict__ nf,
                                                         const float* __restrict__ W1, const float* __restrict__ B1,
                                                         const float* __restrict__ W2, const float* __restrict__ B2,
                                                         const float* __restrict__ W3, const float* __restrict__ B3,
                                                         float* __restrict__ out, int n)
{
    __shared__ float Ws1[80 * 64], Ws2[64 * 64], Ws3[64 * 4];
    __shared__ float bs1[64], bs2[64], bs3[4];
    __shared__ float Xs[32 * 84];       // reused as H2 (stride 68)
    __shared__ float H1[32 * 68];
    for (int i = threadIdx.x; i < 80 * 64; i += 256) Ws1[i] = W1[i];
    for (int i = threadIdx.x; i < 64 * 64; i += 256) Ws2[i] = W2[i];
    for (int i = threadIdx.x; i < 64 * 4; i += 256) Ws3[i] = W3[i];
    if (threadIdx.x < 64) { bs1[threadIdx.x] = B1[threadIdx.x]; bs2[threadIdx.x] = B2[threadIdx.x]; }
    if (threadIdx.x < 4) bs3[threadIdx.x] = B3[threadIdx.x];
    const int tr = threadIdx.x >> 4, tc = threadIdx.x & 15;
    const int r0 = tr * 2, c0 = tc * 4;
    for (int base = blockIdx.x * 32; base < n; base += gridDim.x * 32) {
        __syncthreads();
        for (int i = threadIdx.x; i < 32 * 4; i += 256) {
            int row = i >> 2, kq = (i & 3) * 4;
            int g = base + row;
            float4 v = make_float4(0,0,0,0);
            if (g < n) v = *(const float4*)&in_node[(size_t)g * 16 + kq];
            *(float4*)&Xs[row * 84 + kq] = v;
        }
        for (int i = threadIdx.x; i < 32 * 16; i += 256) {
            int row = i >> 4, kq = (i & 15) * 4;
            int g = base + row;
            float4 v = make_float4(0,0,0,0);
            if (g < n) v = *(const float4*)&nf[(size_t)g * 64 + kq];
            *(float4*)&Xs[row * 84 + 16 + kq] = v;
        }
        __syncthreads();
        {
            float acc[2][4];
            #pragma unroll
            for (int i = 0; i < 2; i++)
                #pragma unroll
                for (int j = 0; j < 4; j++) acc[i][j] = bs1[c0 + j];
            #pragma unroll 4
            for (int kq = 0; kq < 80; kq += 4) {
                float4 xa[2], wa[4];
                #pragma unroll
                for (int i = 0; i < 2; i++) xa[i] = *(const float4*)&Xs[(r0 + i) * 84 + kq];
                #pragma unroll
                for (int j = 0; j < 4; j++) wa[j] = *(const float4*)&Ws1[(kq + j) * 64 + c0];
                #pragma unroll
                for (int kk = 0; kk < 4; kk++)
                    #pragma unroll
                    for (int i = 0; i < 2; i++) {
                        float x = ((const float*)&xa[i])[kk];
                        #pragma unroll
                        for (int j = 0; j < 4; j++) acc[i][j] += x * ((const float*)&wa[kk])[j];
                    }
            }
            #pragma unroll
            for (int i = 0; i < 2; i++) {
                float4 o; float* op = (float*)&o;
                #pragma unroll
                for (int j = 0; j < 4; j++) op[j] = lrelu_(acc[i][j]);
                *(float4*)&H1[(r0 + i) * 68 + c0] = o;
            }
        }
        __syncthreads();
        float* H2 = Xs;
        {
            float acc[2][4];
            #pragma unroll
            for (int i = 0; i < 2; i++)
                #pragma unroll
                for (int j = 0; j < 4; j++) acc[i][j] = bs2[c0 + j];
            #pragma unroll 4
            for (int kq = 0; kq < 64; kq += 4) {
                float4 xa[2], wa[4];
                #pragma unroll
                for (int i = 0; i < 2; i++) xa[i] = *(const float4*)&H1[(r0 + i) * 68 + kq];
                #pragma unroll
                for (int j = 0; j < 4; j++) wa[j] = *(const float4*)&Ws2[(kq + j) * 64 + c0];
                #pragma unroll
                for (int kk = 0; kk < 4; kk++)
                    #pragma unroll
                    for (int i = 0; i < 2; i++) {
                        float x = ((const float*)&xa[i])[kk];
                        #pragma unroll
                        for (int j = 0; j < 4; j++) acc[i][j] += x * ((const float*)&wa[kk])[j];
                    }
            }
            __syncthreads();
            #pragma unroll
            for (int i = 0; i < 2; i++) {
                float4 o; float* op = (float*)&o;
                #pragma unroll
                for (int j = 0; j < 4; j++) op[j] = lrelu_(acc[i][j]);
                *(float4*)&H2[(r0 + i) * 68 + c0] = o;
            }
        }
        __syncthreads();
        if (threadIdx.x < 128) {
            int row = threadIdx.x >> 2, c = threadIdx.x & 3;
            float acc = bs3[c];
            #pragma unroll 4
            for (int kq = 0; kq < 64; kq += 4) {
                float4 h = *(const float4*)&H2[row * 68 + kq];
                #pragma unroll
                for (int j = 0; j < 4; j++) acc += ((const float*)&h)[j] * Ws3[(kq + j) * 4 + c];
            }
            int g = base + row;
            if (g < n) out[(size_t)g * 4 + c] = sigm_(acc);
        }
    }
}

// ---------------- net head (32 rows/iter, grid-stride, C_out=1) ----------------
__global__ __launch_bounds__(256) void net_head3_kernel(const float* __restrict__ in_net, const float* __restrict__ tf,
                                                        const float* __restrict__ W1, const float* __restrict__ B1,
                                                        const float* __restrict__ W2, const float* __restrict__ B2,
                                                        const float* __restrict__ W3, const float* __restrict__ B3,
                                                        float* __restrict__ out, int n)
{
    __shared__ float Ws1[72 * 64], Ws2[64 * 64], Ws3[64];
    __shared__ float bs1[64], bs2[64], bs3[1];
    __shared__ float Xs[32 * 76];       // reused as H2 (stride 68)
    __shared__ float H1[32 * 68];
    for (int i = threadIdx.x; i < 72 * 64; i += 256) Ws1[i] = W1[i];
    for (int i = threadIdx.x; i < 64 * 64; i += 256) Ws2[i] = W2[i];
    if (threadIdx.x < 64) { Ws3[threadIdx.x] = W3[threadIdx.x]; bs1[threadIdx.x] = B1[threadIdx.x]; bs2[threadIdx.x] = B2[threadIdx.x]; }
    if (threadIdx.x == 0) bs3[0] = B3[0];
    const int tr = threadIdx.x >> 4, tc = threadIdx.x & 15;
    const int r0 = tr * 2, c0 = tc * 4;
    for (int base = blockIdx.x * 32; base < n; base += gridDim.x * 32) {
        __syncthreads();
        for (int i = threadIdx.x; i < 32 * 2; i += 256) {
            int row = i >> 1, kq = (i & 1) * 4;
            int g = base + row;
            float4 v = make_float4(0,0,0,0);
            if (g < n) v = *(const float4*)&in_net[(size_t)g * 8 + kq];
            *(float4*)&Xs[row * 76 + kq] = v;
        }
        for (int i = threadIdx.x; i < 32 * 16; i += 256) {
            int row = i >> 4, kq = (i & 15) * 4;
            int g = base + row;
            float4 v = make_float4(0,0,0,0);
            if (g < n) v = *(const float4*)&tf[(size_t)g * 64 + kq];
            *(float4*)&Xs[row * 76 + 8 + kq] = v;
        }
        __syncthreads();
        {
            float acc[2][4];
            #pragma unroll
            for (int i = 0; i < 2; i++)
                #pragma unroll
                for (int j = 0; j < 4; j++) acc[i][j] = bs1[c0 + j];
            #pragma unroll 4
            for (int kq = 0; kq < 72; kq += 4) {
                float4 xa[2], wa[4];
                #pragma unroll
                for (int i = 0; i < 2; i++) xa[i] = *(const float4*)&Xs[(r0 + i) * 76 + kq];
                #pragma unroll
                for (int j = 0; j < 4; j++) wa[j] = *(const float4*)&Ws1[(kq + j) * 64 + c0];
                #pragma unroll
                for (int kk = 0; kk < 4; kk++)
                    #pragma unroll
                    for (int i = 0; i < 2; i++) {
                        float x = ((const float*)&xa[i])[kk];
                        #pragma unroll
                        for (int j = 0; j < 4; j++) acc[i][j] += x * ((const float*)&wa[kk])[j];
                    }
            }
            #pragma unroll
            for (int i = 0; i < 2; i++) {
                float4 o; float* op = (float*)&o;
                #pragma unroll
                for (int j = 0; j < 4; j++) op[j] = lrelu_(acc[i][j]);
                *(float4*)&H1[(r0 + i) * 68 + c0] = o;
            }
        }
        __syncthreads();
        float* H2 = Xs;
        {
            float acc[2][4];
            #pragma unroll
            for (int i = 0; i < 2; i++)
                #pragma unroll
                for (int j = 0; j < 4; j++) acc[i][j] = bs2[c0 + j];
            #pragma unroll 4
            for (int kq = 0; kq < 64; kq += 4) {
                float4 xa[2], wa[4];
                #pragma unroll
                for (int i = 0; i < 2; i++) xa[i] = *(const float4*)&H1[(r0 + i) * 68 + kq];
                #pragma unroll
                for (int j = 0; j < 4; j++) wa[j] = *(const float4*)&Ws2[(kq + j) * 64 + c0];
                #pragma unroll
                for (int kk = 0; kk < 4; kk++)
                    #pragma unroll
                    for (int i = 0; i < 2; i++) {
                        float x = ((const float*)&xa[i])[kk];
                        #pragma unroll
                        for (int j = 0; j < 4; j++) acc[i][j] += x * ((const float*)&wa[kk])[j];
                    }
            }
            __syncthreads();
            #pragma unroll
            for (int i = 0; i < 2; i++) {
                float4 o; float* op = (float*)&o;
                #pragma unroll
                for (int j = 0; j < 4; j++) op[j] = lrelu_(acc[i][j]);
                *(float4*)&H2[(r0 + i) * 68 + c0] = o;
            }
        }
        __syncthreads();
        if (threadIdx.x < 32) {
            int row = threadIdx.x;
            float acc = bs3[0];
            #pragma unroll 4
            for (int kq = 0; kq < 64; kq += 4) {
                float4 h = *(const float4*)&H2[row * 68 + kq];
                float4 w = *(const float4*)&Ws3[kq];
                acc += h.x * w.x + h.y * w.y + h.z * w.z + h.w * w.w;
            }
            int g = base + row;
            if (g < n) out[g] = sigm_(acc);
        }
    }
}

extern "C" void kernel_launch(void* const* d_in, const int* in_sizes, int n_in,
                              void* d_out, int out_size, void* d_ws, size_t ws_size,
                              hipStream_t stream)
{
    (void)in_sizes; (void)n_in; (void)out_size; (void)ws_size;
    constexpr int Nn = 100000, Nt = 30000, Np = 400000, Ne = 1000000;
    constexpr int H = 64, L = 3, T = 4;

    auto fpt = [&](int i){ return (const float*)d_in[i]; };
    auto ipt = [&](int i){ return (const int*)d_in[i]; };

    const float* in_node = fpt(0);
    const float* in_net  = fpt(1);
    const float* in_pin  = fpt(2);
    const float* in_edge = fpt(3);
    const int* psrc = ipt(4);
    const int* pdst = ipt(5);
    const int* esrc = ipt(6);
    const int* edst = ipt(7);

    float* ws = (float*)d_ws;
    size_t o = 0;
    auto alloc = [&](size_t nel){ float* p = ws + o; o += nel; return p; };
    float* node_a = alloc((size_t)Nn * H);
    float* node_b = alloc((size_t)Nn * H);
    float* net_a  = alloc((size_t)Nt * H);
    float* net_b  = alloc((size_t)Nt * H);
    float* agg    = alloc((size_t)Nt * H);
    float* hv     = alloc((size_t)Nt * H);
    float* pinf   = alloc((size_t)Np * 16);
    float* h_cf   = alloc((size_t)Nn * H);
    float* hp     = alloc((size_t)Nn * H);   // SAGE pool / linear accumulator
    float* h_ng   = alloc((size_t)Nn * H);
    float* ew3    = alloc((size_t)3 * Ne);
    float* snorm  = alloc((size_t)Nn);
    float* dnorm  = alloc((size_t)Nt);
    // CSR workspace: near (keyed by edst, Nn rows) and pins (keyed by pdst, Nt rows)
    int* cnt       = (int*)alloc((size_t)Nn);
    int* row_start = (int*)alloc((size_t)Nn + 1);
    int* nxt       = (int*)alloc((size_t)Nn);
    int* eidx      = (int*)alloc((size_t)Ne);
    int* bsum      = (int*)alloc((size_t)512);
    int* pcnt      = (int*)alloc((size_t)Nt);
    int* prow      = (int*)alloc((size_t)Nt + 1);
    int* pnxt      = (int*)alloc((size_t)Nt);
    int* peidx     = (int*)alloc((size_t)Np);
    int* pbsum     = (int*)alloc((size_t)256);

    constexpr int NB  = (Nn + 255) / 256;   // 391 blocks (near scan)
    constexpr int NB2 = (Nt + 255) / 256;   // 118 blocks (pins scan)

    // degree norms for pins
    hipMemsetAsync(snorm, 0, (size_t)Nn * 4, stream);
    hipMemsetAsync(dnorm, 0, (size_t)Nt * 4, stream);
    deg_kernel<<<(Np + 255) / 256, 256, 0, stream>>>(psrc, pdst, (int*)snorm, (int*)dnorm, Np);
    norm_kernel<<<(Nn + 255) / 256, 256, 0, stream>>>((int*)snorm, Nn);
    norm_kernel<<<(Nt + 255) / 256, 256, 0, stream>>>((int*)dnorm, Nt);

    // build dst-CSR for 'near' (edst -> Nn rows)
    hipMemsetAsync(cnt, 0, (size_t)Nn * 4, stream);
    csr_count_kernel<<<(Ne + 255) / 256, 256, 0, stream>>>(edst, cnt, Ne);
    scan_block_sum_kernel<<<NB, 256, 0, stream>>>(cnt, bsum, Nn);
    scan_bsum_kernel<<<1, 64, 0, stream>>>(bsum, NB, row_start + Nn);
    scan_final_kernel<<<NB, 256, 0, stream>>>(cnt, bsum, row_start, nxt, Nn);
    csr_fill_kernel<<<(Ne + 255) / 256, 256, 0, stream>>>(edst, nxt, eidx, Ne);

    // build dst-CSR for 'pins' (pdst -> Nt rows)
    hipMemsetAsync(pcnt, 0, (size_t)Nt * 4, stream);
    csr_count_kernel<<<(Np + 255) / 256, 256, 0, stream>>>(pdst, pcnt, Np);
    scan_block_sum_kernel<<<NB2, 256, 0, stream>>>(pcnt, pbsum, Nt);
    scan_bsum_kernel<<<1, 64, 0, stream>>>(pbsum, NB2, prow + Nt);
    scan_final_kernel<<<NB2, 256, 0, stream>>>(pcnt, pbsum, prow, pnxt, Nt);
    csr_fill_kernel<<<(Np + 255) / 256, 256, 0, stream>>>(pdst, pnxt, peidx, Np);

    // input encoders
    gemm64_kernel<16, 1, false, false><<<1024, 256, 0, stream>>>(in_node, nullptr, fpt(8),  fpt(9),  nullptr, node_a, Nn);
    gemm64_kernel< 8, 1, false, false><<<469, 256, 0, stream>>>(in_net,  nullptr, fpt(10), fpt(11), nullptr, net_a,  Nt);
    lin_kernel<8, 16, 1><<<1024, 256, 0, stream>>>(in_pin, fpt(12), fpt(13), pinf, Np);
    edge_ew_kernel<<<2048, 256, 0, stream>>>(in_edge, fpt(14), fpt(15), fpt(16), fpt(17), ew3, Ne);

    float* ncur = node_a; float* nnew = node_b;
    float* tcur = net_a;  float* tnew = net_b;

    for (int i = 0; i < L; i++) {
        // pins GraphConv (node -> net): gather over pdst-CSR, dnorm folded
        pins_gather_kernel<<<(Nt + 3) / 4, 256, 0, stream>>>(ncur, snorm, dnorm, psrc, prow, peidx, agg, Nt);
        gemm64_kernel<64, 1, false, false><<<469, 256, 0, stream>>>(agg, nullptr, fpt(18) + (size_t)i * 4096, fpt(19) + (size_t)i * 64, nullptr, tnew, Nt);

        // CFConv (net -> node)
        gemm64_kernel<64, 0, false, false><<<469, 256, 0, stream>>>(tcur, nullptr, fpt(20) + (size_t)i * 4096, fpt(21) + (size_t)i * 64, nullptr, hv, Nt);
        hipMemsetAsync(h_cf, 0, (size_t)Nn * H * 4, stream);
        cf_pin5_kernel<<<1024, 256, 0, stream>>>(pinf, hv, psrc, pdst,
                                                 fpt(22) + (size_t)i * 1024, fpt(23) + (size_t)i * 64,
                                                 fpt(24) + (size_t)i * 4096, fpt(25) + (size_t)i * 64,
                                                 h_cf, Np);

        // SAGE (near): hp = relu(ncur @ pool + b), gather-max over dst-CSR
        gemm64_kernel<64, 2, false, false><<<1024, 256, 0, stream>>>(ncur, nullptr, fpt(28) + (size_t)i * 4096, fpt(29) + (size_t)i * 64, nullptr, hp, Nn);
        sage_gather_kernel<<<(Nn + 3) / 4, 256, 0, stream>>>(hp, ew3 + (size_t)i * Ne, esrc, row_start, eidx, h_ng, Nn);

        // combine:
        // hp (reused) = ncur @ sage_self + h_ng @ sage_neigh + sage_bias   (single dual-GEMM pass)
        gemm64_dual_kernel<<<1024, 256, 0, stream>>>(ncur, h_ng,
                                                     fpt(30) + (size_t)i * 4096, fpt(31) + (size_t)i * 4096,
                                                     fpt(32) + (size_t)i * 64, hp, Nn);
        // nnew = lrelu(max(ssp(h_cf @ cf_out + b), hp))   (fused ACT=4)
        gemm64_kernel<64, 4, false, false><<<1024, 256, 0, stream>>>(h_cf, nullptr, fpt(26) + (size_t)i * 4096, fpt(27) + (size_t)i * 64, hp, nnew, Nn);

        float* t;
        t = ncur; ncur = nnew; nnew = t;
        t = tcur; tcur = tnew; tnew = t;
    }

    float* out = (float*)d_out;
    node_head3_kernel<<<640, 256, 0, stream>>>(in_node, ncur, fpt(33), fpt(34), fpt(35), fpt(36), fpt(37), fpt(38), out, Nn);
    net_head3_kernel<<<480, 256, 0, stream>>>(in_net, tcur, fpt(39), fpt(40), fpt(41), fpt(42), fpt(43), fpt(44), out + (size_t)Nn * T, Nt);
}

// Round 10
// 1437.447 us; speedup vs baseline: 10.2472x; 1.1266x over previous
//
#include <hip/hip_runtime.h>
#include <hip/hip_bf16.h>

#define DEV __device__ __forceinline__

DEV float lrelu_(float x){ return x > 0.f ? x : 0.01f * x; }
DEV float ssp_(float x){ return fmaxf(x, 0.f) + __logf(1.f + __expf(-fabsf(x))) - 0.69314718055994530942f; }
DEV float sigm_(float x){ return 1.f / (1.f + __expf(-x)); }

DEV unsigned short f2bf(float x){
    unsigned int u = __float_as_uint(x);
    unsigned int r = (u + 0x7FFFu + ((u >> 16) & 1u)) >> 16;
    return (unsigned short)r;
}
DEV float bf2f(unsigned short s){ return __uint_as_float((unsigned int)s << 16); }
DEV ushort4 pack4(float4 v){
    ushort4 u; u.x = f2bf(v.x); u.y = f2bf(v.y); u.z = f2bf(v.z); u.w = f2bf(v.w); return u;
}

DEV void fma44(float (&acc)[4][4], const float4 (&xa)[4], const float4 (&wa)[4])
{
    #pragma unroll
    for (int kk = 0; kk < 4; kk++) {
        #pragma unroll
        for (int i = 0; i < 4; i++) {
            float x = ((const float*)&xa[i])[kk];
            #pragma unroll
            for (int j = 0; j < 4; j++)
                acc[i][j] += x * ((const float*)&wa[kk])[j];
        }
    }
}

typedef short s8v __attribute__((ext_vector_type(8)));
typedef float f4v __attribute__((ext_vector_type(4)));

// ====== generic tiled GEMM (VALU, small K): Y[N x 64] = act(X @ W[K x 64] + b) ====
template<int K, int ACT>
__global__ __launch_bounds__(256) void gemm64_kernel(const float* __restrict__ X,
                                                     const float* __restrict__ W,
                                                     const float* __restrict__ B,
                                                     float* __restrict__ Y, int nrows)
{
    constexpr int XS = K + 4;
    constexpr int KQ = K / 4;
    __shared__ float Ws[K * 64];
    __shared__ float bs[64];
    __shared__ float Xs[64 * XS];
    for (int i = threadIdx.x; i < K * 64; i += 256) Ws[i] = W[i];
    if (threadIdx.x < 64) bs[threadIdx.x] = B[threadIdx.x];
    const int tr = threadIdx.x >> 4, tc = threadIdx.x & 15;
    const int r0 = tr * 4, c0 = tc * 4;
    for (int base = blockIdx.x * 64; base < nrows; base += gridDim.x * 64) {
        __syncthreads();
        for (int i = threadIdx.x; i < 64 * KQ; i += 256) {
            int row = i / KQ, kq = (i % KQ) * 4;
            int g = base + row;
            float4 v = make_float4(0.f, 0.f, 0.f, 0.f);
            if (g < nrows) v = *(const float4*)&X[(size_t)g * K + kq];
            *(float4*)&Xs[row * XS + kq] = v;
        }
        __syncthreads();
        float acc[4][4];
        #pragma unroll
        for (int i = 0; i < 4; i++)
            #pragma unroll
            for (int j = 0; j < 4; j++) acc[i][j] = bs[c0 + j];
        #pragma unroll 4
        for (int kq = 0; kq < K; kq += 4) {
            float4 xa[4], wa[4];
            #pragma unroll
            for (int i = 0; i < 4; i++) xa[i] = *(const float4*)&Xs[(r0 + i) * XS + kq];
            #pragma unroll
            for (int j = 0; j < 4; j++) wa[j] = *(const float4*)&Ws[(kq + j) * 64 + c0];
            fma44(acc, xa, wa);
        }
        #pragma unroll
        for (int i = 0; i < 4; i++) {
            int g = base + r0 + i;
            if (g < nrows) {
                float4 o;
                float* op = (float*)&o;
                #pragma unroll
                for (int j = 0; j < 4; j++) {
                    float a = acc[i][j];
                    if (ACT == 1) a = lrelu_(a);
                    else if (ACT == 2) a = fmaxf(a, 0.f);
                    op[j] = a;
                }
                *(float4*)&Y[(size_t)g * 64 + c0] = o;
            }
        }
    }
}

// ====== MFMA GEMM: Y[N x 64] = act(X[N x 64] @ W[64 x 64] + b), bf16 operands ======
template<int ACT>
__global__ __launch_bounds__(256) void mfma_gemm_kernel(const float* __restrict__ X,
                                                        const float* __restrict__ W,
                                                        const float* __restrict__ B,
                                                        float* __restrict__ Y, int nrows)
{
    __shared__ __align__(16) unsigned short WT[64 * 72];   // [n][k]
    __shared__ __align__(16) unsigned short Axs[64 * 72];  // [row][k]
    __shared__ float bs[64];
    for (int i = threadIdx.x; i < 4096; i += 256) {
        int k = i >> 6, nn = i & 63;
        WT[nn * 72 + k] = f2bf(W[i]);
    }
    if (threadIdx.x < 64) bs[threadIdx.x] = B[threadIdx.x];
    const int lane = threadIdx.x & 63, wv = threadIdx.x >> 6;
    const int l15 = lane & 15, quad = lane >> 4;
    const int arow = 16 * wv + l15;
    const int koff = quad * 8;
    for (int base = blockIdx.x * 64; base < nrows; base += gridDim.x * 64) {
        __syncthreads();
        {
            int row = threadIdx.x >> 2, kq = (threadIdx.x & 3) * 16;
            int g = base + row;
            #pragma unroll
            for (int m = 0; m < 4; m++) {
                float4 v = make_float4(0,0,0,0);
                if (g < nrows) v = *(const float4*)&X[(size_t)g * 64 + kq + m * 4];
                *(ushort4*)&Axs[row * 72 + kq + m * 4] = pack4(v);
            }
        }
        __syncthreads();
        f4v acc[4];
        #pragma unroll
        for (int t = 0; t < 4; t++) acc[t] = (f4v){0.f,0.f,0.f,0.f};
        s8v a0 = *(const s8v*)&Axs[arow * 72 + koff];
        s8v a1 = *(const s8v*)&Axs[arow * 72 + 32 + koff];
        #pragma unroll
        for (int t = 0; t < 4; t++) {
            int nn = t * 16 + l15;
            s8v b0 = *(const s8v*)&WT[nn * 72 + koff];
            s8v b1 = *(const s8v*)&WT[nn * 72 + 32 + koff];
            acc[t] = __builtin_amdgcn_mfma_f32_16x16x32_bf16(a0, b0, acc[t], 0, 0, 0);
            acc[t] = __builtin_amdgcn_mfma_f32_16x16x32_bf16(a1, b1, acc[t], 0, 0, 0);
        }
        const int mrow = 16 * wv + quad * 4;
        #pragma unroll
        for (int t = 0; t < 4; t++) {
            int col = t * 16 + l15;
            float b = bs[col];
            #pragma unroll
            for (int r = 0; r < 4; r++) {
                int g = base + mrow + r;
                if (g < nrows) {
                    float a = acc[t][r] + b;
                    if (ACT == 1) a = lrelu_(a);
                    else if (ACT == 2) a = fmaxf(a, 0.f);
                    Y[(size_t)g * 64 + col] = a;
                }
            }
        }
    }
}

// ====== MFMA triple-GEMM combine:
//   out = lrelu(max( ssp(h_cf@Wc + bc),  nf@Ws + h_ng@Wn + sb ))
__global__ __launch_bounds__(256) void mfma_combine_kernel(const float* __restrict__ h_cf,
                                                           const float* __restrict__ nf,
                                                           const float* __restrict__ h_ng,
                                                           const float* __restrict__ Wc, const float* __restrict__ cB,
                                                           const float* __restrict__ sW, const float* __restrict__ nW,
                                                           const float* __restrict__ sB,
                                                           float* __restrict__ out, int n)
{
    __shared__ __align__(16) unsigned short WcT[64 * 72], WsT[64 * 72], WnT[64 * 72];
    __shared__ __align__(16) unsigned short Ac[32 * 72], As[32 * 72], An[32 * 72];
    __shared__ float bc[64], bsg[64];
    for (int i = threadIdx.x; i < 4096; i += 256) {
        int k = i >> 6, nn = i & 63;
        WcT[nn * 72 + k] = f2bf(Wc[i]);
        WsT[nn * 72 + k] = f2bf(sW[i]);
        WnT[nn * 72 + k] = f2bf(nW[i]);
    }
    if (threadIdx.x < 64) { bc[threadIdx.x] = cB[threadIdx.x]; bsg[threadIdx.x] = sB[threadIdx.x]; }
    const int lane = threadIdx.x & 63, wv = threadIdx.x >> 6;
    const int l15 = lane & 15, quad = lane >> 4;
    const int arow = (wv & 1) * 16 + l15;
    const int ct0 = (wv >> 1) * 2;
    const int koff = quad * 8;
    for (int base = blockIdx.x * 32; base < n; base += gridDim.x * 32) {
        __syncthreads();
        {
            int row = threadIdx.x >> 3, kq = (threadIdx.x & 7) * 8;
            int g = base + row;
            float4 c0v = make_float4(0,0,0,0), c1 = c0v, f0 = c0v, f1 = c0v, g0 = c0v, g1 = c0v;
            if (g < n) {
                const float* pc = &h_cf[(size_t)g * 64 + kq];
                const float* pf = &nf[(size_t)g * 64 + kq];
                const float* pg = &h_ng[(size_t)g * 64 + kq];
                c0v = *(const float4*)pc; c1 = *(const float4*)(pc + 4);
                f0 = *(const float4*)pf;  f1 = *(const float4*)(pf + 4);
                g0 = *(const float4*)pg;  g1 = *(const float4*)(pg + 4);
            }
            *(ushort4*)&Ac[row * 72 + kq] = pack4(c0v);
            *(ushort4*)&Ac[row * 72 + kq + 4] = pack4(c1);
            *(ushort4*)&As[row * 72 + kq] = pack4(f0);
            *(ushort4*)&As[row * 72 + kq + 4] = pack4(f1);
            *(ushort4*)&An[row * 72 + kq] = pack4(g0);
            *(ushort4*)&An[row * 72 + kq + 4] = pack4(g1);
        }
        __syncthreads();
        f4v accC[2], accS[2];
        #pragma unroll
        for (int t = 0; t < 2; t++) { accC[t] = (f4v){0.f,0.f,0.f,0.f}; accS[t] = (f4v){0.f,0.f,0.f,0.f}; }
        s8v ac0 = *(const s8v*)&Ac[arow * 72 + koff];
        s8v ac1 = *(const s8v*)&Ac[arow * 72 + 32 + koff];
        s8v as0 = *(const s8v*)&As[arow * 72 + koff];
        s8v as1 = *(const s8v*)&As[arow * 72 + 32 + koff];
        s8v an0 = *(const s8v*)&An[arow * 72 + koff];
        s8v an1 = *(const s8v*)&An[arow * 72 + 32 + koff];
        #pragma unroll
        for (int t = 0; t < 2; t++) {
            int nn = (ct0 + t) * 16 + l15;
            s8v wc0 = *(const s8v*)&WcT[nn * 72 + koff];
            s8v wc1 = *(const s8v*)&WcT[nn * 72 + 32 + koff];
            accC[t] = __builtin_amdgcn_mfma_f32_16x16x32_bf16(ac0, wc0, accC[t], 0, 0, 0);
            accC[t] = __builtin_amdgcn_mfma_f32_16x16x32_bf16(ac1, wc1, accC[t], 0, 0, 0);
            s8v ws0 = *(const s8v*)&WsT[nn * 72 + koff];
            s8v ws1 = *(const s8v*)&WsT[nn * 72 + 32 + koff];
            accS[t] = __builtin_amdgcn_mfma_f32_16x16x32_bf16(as0, ws0, accS[t], 0, 0, 0);
            accS[t] = __builtin_amdgcn_mfma_f32_16x16x32_bf16(as1, ws1, accS[t], 0, 0, 0);
            s8v wn0 = *(const s8v*)&WnT[nn * 72 + koff];
            s8v wn1 = *(const s8v*)&WnT[nn * 72 + 32 + koff];
            accS[t] = __builtin_amdgcn_mfma_f32_16x16x32_bf16(an0, wn0, accS[t], 0, 0, 0);
            accS[t] = __builtin_amdgcn_mfma_f32_16x16x32_bf16(an1, wn1, accS[t], 0, 0, 0);
        }
        const int mrow = (wv & 1) * 16 + quad * 4;
        #pragma unroll
        for (int t = 0; t < 2; t++) {
            int col = (ct0 + t) * 16 + l15;
            float bcv = bc[col], bsv = bsg[col];
            #pragma unroll
            for (int r = 0; r < 4; r++) {
                int g = base + mrow + r;
                if (g < n)
                    out[(size_t)g * 64 + col] = lrelu_(fmaxf(ssp_(accC[t][r] + bcv), accS[t][r] + bsv));
            }
        }
    }
}

// ---------------- small scalar GEMV (pin encoder, C=16) ----------------
template<int K, int C, int ACT>
__global__ __launch_bounds__(256) void lin_kernel(const float* __restrict__ X,
                                                  const float* __restrict__ W,
                                                  const float* __restrict__ B,
                                                  float* __restrict__ Y, int nrows)
{
    constexpr int ROWS = 256 / C;
    __shared__ float Ws[K * C];
    __shared__ float bs[C];
    __shared__ float Xs[ROWS * K];
    for (int i = threadIdx.x; i < K * C; i += 256) Ws[i] = W[i];
    if (threadIdx.x < C) bs[threadIdx.x] = B[threadIdx.x];
    __syncthreads();
    const int r = threadIdx.x / C, c = threadIdx.x % C;
    for (int base = blockIdx.x * ROWS; base < nrows; base += gridDim.x * ROWS) {
        __syncthreads();
        for (int i = threadIdx.x; i < ROWS * K; i += 256) {
            int rr = base + i / K;
            Xs[i] = (rr < nrows) ? X[(size_t)rr * K + i % K] : 0.f;
        }
        __syncthreads();
        int row = base + r;
        if (row < nrows) {
            float acc = bs[c];
            #pragma unroll
            for (int k = 0; k < K; k++) acc += Xs[r * K + k] * Ws[k * C + c];
            if (ACT == 1) acc = lrelu_(acc);
            else if (ACT == 2) acc = fmaxf(acc, 0.f);
            Y[(size_t)row * C + c] = acc;
        }
    }
}

// ---------------- degrees (for pins norms) ----------------
__global__ __launch_bounds__(256) void deg_kernel(const int* __restrict__ src, const int* __restrict__ dst,
                                                  int* __restrict__ degs, int* __restrict__ degd, int np)
{
    int p = blockIdx.x * 256 + threadIdx.x;
    if (p < np) { atomicAdd(&degs[src[p]], 1); atomicAdd(&degd[dst[p]], 1); }
}

__global__ __launch_bounds__(256) void norm_kernel(int* __restrict__ arr, int n)
{
    int i = blockIdx.x * 256 + threadIdx.x;
    if (i < n) {
        int v = arr[i]; if (v < 1) v = 1;
        arr[i] = __float_as_int(rsqrtf((float)v));
    }
}

// ================= CSR build (generic, keyed by given index array) =================
__global__ __launch_bounds__(256) void csr_count_kernel(const int* __restrict__ key, int* __restrict__ cnt, int ne)
{
    int e = blockIdx.x * 256 + threadIdx.x;
    if (e < ne) atomicAdd(&cnt[key[e]], 1);
}

__global__ __launch_bounds__(256) void scan_block_sum_kernel(const int* __restrict__ cnt, int* __restrict__ bsum, int n)
{
    __shared__ int sh[256];
    int i = blockIdx.x * 256 + threadIdx.x;
    sh[threadIdx.x] = (i < n) ? cnt[i] : 0;
    __syncthreads();
    for (int s = 128; s > 0; s >>= 1) {
        if (threadIdx.x < s) sh[threadIdx.x] += sh[threadIdx.x + s];
        __syncthreads();
    }
    if (threadIdx.x == 0) bsum[blockIdx.x] = sh[0];
}

__global__ void scan_bsum_kernel(int* __restrict__ bsum, int nb, int* __restrict__ total_out)
{
    if (threadIdx.x == 0 && blockIdx.x == 0) {
        int run = 0;
        for (int i = 0; i < nb; i++) { int v = bsum[i]; bsum[i] = run; run += v; }
        *total_out = run;
    }
}

__global__ __launch_bounds__(256) void scan_final_kernel(const int* __restrict__ cnt, const int* __restrict__ bsum,
                                                         int* __restrict__ row_start, int* __restrict__ nxt, int n)
{
    __shared__ int sh[256];
    int i = blockIdx.x * 256 + threadIdx.x;
    int v = (i < n) ? cnt[i] : 0;
    sh[threadIdx.x] = v;
    __syncthreads();
    for (int s = 1; s < 256; s <<= 1) {
        int add = (threadIdx.x >= s) ? sh[threadIdx.x - s] : 0;
        __syncthreads();
        sh[threadIdx.x] += add;
        __syncthreads();
    }
    if (i < n) {
        int excl = sh[threadIdx.x] - v + bsum[blockIdx.x];
        row_start[i] = excl;
        nxt[i] = excl;
    }
}

__global__ __launch_bounds__(256) void csr_fill_kernel(const int* __restrict__ key, int* __restrict__ nxt,
                                                       int* __restrict__ eidx, int ne)
{
    int e = blockIdx.x * 256 + threadIdx.x;
    if (e < ne) {
        int slot = atomicAdd(&nxt[key[e]], 1);
        eidx[slot] = e;
    }
}

// ---------------- edge weights for all 3 layers ----------------
__global__ __launch_bounds__(256) void edge_ew_kernel(const float* __restrict__ in_edge,
                                                      const float* __restrict__ elW, const float* __restrict__ elb,
                                                      const float* __restrict__ gW, const float* __restrict__ gb,
                                                      float* __restrict__ ew3, int ne)
{
    __shared__ float W[32], B[8], G[24], Gb[3];
    if (threadIdx.x < 32) W[threadIdx.x] = elW[threadIdx.x];
    if (threadIdx.x < 8)  B[threadIdx.x] = elb[threadIdx.x];
    if (threadIdx.x < 24) G[threadIdx.x] = gW[threadIdx.x];
    if (threadIdx.x < 3)  Gb[threadIdx.x] = gb[threadIdx.x];
    __syncthreads();
    for (int e = blockIdx.x * 256 + threadIdx.x; e < ne; e += gridDim.x * 256) {
        float4 x = *(const float4*)&in_edge[(size_t)e * 4];
        float ef[8];
        #pragma unroll
        for (int j = 0; j < 8; j++)
            ef[j] = lrelu_(B[j] + x.x * W[j] + x.y * W[8 + j] + x.z * W[16 + j] + x.w * W[24 + j]);
        #pragma unroll
        for (int i = 0; i < 3; i++) {
            float a = Gb[i];
            #pragma unroll
            for (int j = 0; j < 8; j++) a += ef[j] * G[i * 8 + j];
            ew3[(size_t)i * ne + e] = sigm_(a);
        }
    }
}

// ---------------- pins GraphConv gather over pdst-CSR (one wave per net, no atomics) -------------
__global__ __launch_bounds__(256) void pins_gather_kernel(const float* __restrict__ nf, const float* __restrict__ snorm,
                                                          const float* __restrict__ dnorm,
                                                          const int* __restrict__ psrc,
                                                          const int* __restrict__ prow,
                                                          const int* __restrict__ peidx,
                                                          float* __restrict__ agg, int nt)
{
    const int lane = threadIdx.x & 63, wv = threadIdx.x >> 6;
    for (int d = blockIdx.x * 4 + wv; d < nt; d += gridDim.x * 4) {
        int rs = prow[d], re = prow[d + 1];
        float acc = 0.f;
        int k = rs;
        for (; k + 1 < re; k += 2) {
            int p0 = peidx[k], p1 = peidx[k + 1];
            int s0 = psrc[p0], s1 = psrc[p1];
            float n0 = snorm[s0], n1 = snorm[s1];
            float v0 = nf[(size_t)s0 * 64 + lane] * n0;
            float v1 = nf[(size_t)s1 * 64 + lane] * n1;
            acc += v0 + v1;
        }
        if (k < re) {
            int p0 = peidx[k];
            int s0 = psrc[p0];
            acc += nf[(size_t)s0 * 64 + lane] * snorm[s0];
        }
        agg[(size_t)d * 64 + lane] = acc * dnorm[d];
    }
}

// ---------------- CFConv fused: GEMM1 VALU + GEMM2 bf16-MFMA + dense wave scatter ----------------
__global__ __launch_bounds__(256) void cf_pin5_kernel(const float* __restrict__ pinf, const float* __restrict__ hv,
                                                      const int* __restrict__ psrc, const int* __restrict__ pdst,
                                                      const float* __restrict__ W1, const float* __restrict__ B1,
                                                      const float* __restrict__ W2, const float* __restrict__ B2,
                                                      float* __restrict__ h_cf, int np)
{
    __shared__ float Ws1[16 * 64], bs1[64], bs2[64];
    __shared__ __align__(16) unsigned short W2T[64 * 72];  // B operand: [n][k] bf16
    __shared__ __align__(16) unsigned short T1s[64 * 72];  // A operand rows [p][k] bf16; reused as HE
    __shared__ float PF[64 * 20];
    __shared__ int srcS[64], dstS[64];
    for (int i = threadIdx.x; i < 16 * 64; i += 256) Ws1[i] = W1[i];
    for (int i = threadIdx.x; i < 64 * 64; i += 256) {
        int k = i >> 6, n = i & 63;
        W2T[n * 72 + k] = f2bf(W2[i]);
    }
    if (threadIdx.x < 64) { bs1[threadIdx.x] = B1[threadIdx.x]; bs2[threadIdx.x] = B2[threadIdx.x]; }
    const int tr = threadIdx.x >> 4, tc = threadIdx.x & 15;
    const int r0 = tr * 4, c0 = tc * 4;
    const int lane = threadIdx.x & 63, wv = threadIdx.x >> 6;
    const int l15 = lane & 15, quad = lane >> 4;
    const int arow = 16 * wv + l15;
    const int koff = quad * 8;
    for (int base = blockIdx.x * 64; base < np; base += gridDim.x * 64) {
        __syncthreads();
        {
            int row = threadIdx.x >> 2, kq = (threadIdx.x & 3) * 4;
            int p = base + row;
            float4 v = make_float4(0.f, 0.f, 0.f, 0.f);
            if (p < np) v = *(const float4*)&pinf[(size_t)p * 16 + kq];
            *(float4*)&PF[row * 20 + kq] = v;
            if (threadIdx.x < 64) {
                int pp = base + threadIdx.x;
                srcS[threadIdx.x] = (pp < np) ? psrc[pp] : 0;
                dstS[threadIdx.x] = (pp < np) ? pdst[pp] : 0;
            }
        }
        __syncthreads();
        // GEMM1 (VALU, K=16): T1 = ssp(PF @ W1 + b1) -> bf16 LDS rows
        {
            float acc[4][4];
            #pragma unroll
            for (int i = 0; i < 4; i++)
                #pragma unroll
                for (int j = 0; j < 4; j++) acc[i][j] = bs1[c0 + j];
            #pragma unroll
            for (int kq = 0; kq < 16; kq += 4) {
                float4 xa[4], wa[4];
                #pragma unroll
                for (int i = 0; i < 4; i++) xa[i] = *(const float4*)&PF[(r0 + i) * 20 + kq];
                #pragma unroll
                for (int j = 0; j < 4; j++) wa[j] = *(const float4*)&Ws1[(kq + j) * 64 + c0];
                fma44(acc, xa, wa);
            }
            #pragma unroll
            for (int i = 0; i < 4; i++) {
                ushort4 o;
                o.x = f2bf(ssp_(acc[i][0]));
                o.y = f2bf(ssp_(acc[i][1]));
                o.z = f2bf(ssp_(acc[i][2]));
                o.w = f2bf(ssp_(acc[i][3]));
                *(ushort4*)&T1s[(r0 + i) * 72 + c0] = o;
            }
        }
        __syncthreads();
        // GEMM2 (MFMA bf16): HE = ssp(T1 @ W2 + b2); wave w computes rows 16w..16w+15
        {
            f4v acc4[4];
            #pragma unroll
            for (int t = 0; t < 4; t++) acc4[t] = (f4v){0.f, 0.f, 0.f, 0.f};
            s8v a0 = *(const s8v*)&T1s[arow * 72 + koff];
            s8v a1 = *(const s8v*)&T1s[arow * 72 + 32 + koff];
            #pragma unroll
            for (int t = 0; t < 4; t++) {
                int n = t * 16 + l15;
                s8v b0 = *(const s8v*)&W2T[n * 72 + koff];
                s8v b1 = *(const s8v*)&W2T[n * 72 + 32 + koff];
                acc4[t] = __builtin_amdgcn_mfma_f32_16x16x32_bf16(a0, b0, acc4[t], 0, 0, 0);
                acc4[t] = __builtin_amdgcn_mfma_f32_16x16x32_bf16(a1, b1, acc4[t], 0, 0, 0);
            }
            __syncthreads();   // all A reads done; safe to overwrite T1s with HE
            const int mrow = 16 * wv + quad * 4;
            #pragma unroll
            for (int t = 0; t < 4; t++) {
                int col = t * 16 + l15;
                float b = bs2[col];
                #pragma unroll
                for (int r = 0; r < 4; r++)
                    T1s[(mrow + r) * 72 + col] = f2bf(ssp_(acc4[t][r] + b));
            }
        }
        __syncthreads();
        // scatter: one wave per pin-row; 64 lanes = 64 contiguous channels
        #pragma unroll 4
        for (int i = 0; i < 16; i++) {
            int pl = wv * 16 + i;
            int p = base + pl;
            if (p < np) {
                float m = hv[(size_t)dstS[pl] * 64 + lane] * bf2f(T1s[pl * 72 + lane]);
                unsafeAtomicAdd(&h_cf[(size_t)srcS[pl] * 64 + lane], m);
            }
        }
    }
}

// ---------------- SAGE gather-max over dst-CSR (one wave per node, no atomics) ----------------
__global__ __launch_bounds__(256) void sage_gather_kernel(const float* __restrict__ hp, const float* __restrict__ ew,
                                                          const int* __restrict__ esrc,
                                                          const int* __restrict__ row_start,
                                                          const int* __restrict__ eidx,
                                                          float* __restrict__ h_ng, int nn)
{
    const int lane = threadIdx.x & 63, wv = threadIdx.x >> 6;
    for (int d = blockIdx.x * 4 + wv; d < nn; d += gridDim.x * 4) {
        int rs = row_start[d], re = row_start[d + 1];
        float acc = 0.f;
        int k = rs;
        for (; k + 1 < re; k += 2) {
            int e0 = eidx[k], e1 = eidx[k + 1];
            int s0 = esrc[e0], s1 = esrc[e1];
            float w0 = ew[e0], w1 = ew[e1];
            float v0 = hp[(size_t)s0 * 64 + lane] * w0;
            float v1 = hp[(size_t)s1 * 64 + lane] * w1;
            acc = fmaxf(acc, fmaxf(v0, v1));
        }
        if (k < re) {
            int e0 = eidx[k];
            int s0 = esrc[e0];
            acc = fmaxf(acc, hp[(size_t)s0 * 64 + lane] * ew[e0]);
        }
        h_ng[(size_t)d * 64 + lane] = acc;
    }
}

// ---------------- node head (32 rows/iter, grid-stride, 3-stage MLP) ----------------
__global__ __launch_bounds__(256) void node_head3_kernel(const float* __restrict__ in_node, const float* __restrict__ nf,
                                                         const float* __restrict__ W1, const float* __restrict__ B1,
                                                         const float* __restrict__ W2, const float* __restrict__ B2,
                                                         const float* __restrict__ W3, const float* __restrict__ B3,
                                                         float* __restrict__ out, int n)
{
    __shared__ float Ws1[80 * 64], Ws2[64 * 64], Ws3[64 * 4];
    __shared__ float bs1[64], bs2[64], bs3[4];
    __shared__ float Xs[32 * 84];       // reused as H2 (stride 68)
    __shared__ float H1[32 * 68];
    for (int i = threadIdx.x; i < 80 * 64; i += 256) Ws1[i] = W1[i];
    for (int i = threadIdx.x; i < 64 * 64; i += 256) Ws2[i] = W2[i];
    for (int i = threadIdx.x; i < 64 * 4; i += 256) Ws3[i] = W3[i];
    if (threadIdx.x < 64) { bs1[threadIdx.x] = B1[threadIdx.x]; bs2[threadIdx.x] = B2[threadIdx.x]; }
    if (threadIdx.x < 4) bs3[threadIdx.x] = B3[threadIdx.x];
    const int tr = threadIdx.x >> 4, tc = threadIdx.x & 15;
    const int r0 = tr * 2, c0 = tc * 4;
    for (int base = blockIdx.x * 32; base < n; base += gridDim.x * 32) {
        __syncthreads();
        for (int i = threadIdx.x; i < 32 * 4; i += 256) {
            int row = i >> 2, kq = (i & 3) * 4;
            int g = base + row;
            float4 v = make_float4(0,0,0,0);
            if (g < n) v = *(const float4*)&in_node[(size_t)g * 16 + kq];
            *(float4*)&Xs[row * 84 + kq] = v;
        }
        for (int i = threadIdx.x; i < 32 * 16; i += 256) {
            int row = i >> 4, kq = (i & 15) * 4;
            int g = base + row;
            float4 v = make_float4(0,0,0,0);
            if (g < n) v = *(const float4*)&nf[(size_t)g * 64 + kq];
            *(float4*)&Xs[row * 84 + 16 + kq] = v;
        }
        __syncthreads();
        {
            float acc[2][4];
            #pragma unroll
            for (int i = 0; i < 2; i++)
                #pragma unroll
                for (int j = 0; j < 4; j++) acc[i][j] = bs1[c0 + j];
            #pragma unroll 4
            for (int kq = 0; kq < 80; kq += 4) {
                float4 xa[2], wa[4];
                #pragma unroll
                for (int i = 0; i < 2; i++) xa[i] = *(const float4*)&Xs[(r0 + i) * 84 + kq];
                #pragma unroll
                for (int j = 0; j < 4; j++) wa[j] = *(const float4*)&Ws1[(kq + j) * 64 + c0];
                #pragma unroll
                for (int kk = 0; kk < 4; kk++)
                    #pragma unroll
                    for (int i = 0; i < 2; i++) {
                        float x = ((const float*)&xa[i])[kk];
                        #pragma unroll
                        for (int j = 0; j < 4; j++) acc[i][j] += x * ((const float*)&wa[kk])[j];
                    }
            }
            #pragma unroll
            for (int i = 0; i < 2; i++) {
                float4 o; float* op = (float*)&o;
                #pragma unroll
                for (int j = 0; j < 4; j++) op[j] = lrelu_(acc[i][j]);
                *(float4*)&H1[(r0 + i) * 68 + c0] = o;
            }
        }
        __syncthreads();
        float* H2 = Xs;
        {
            float acc[2][4];
            #pragma unroll
            for (int i = 0; i < 2; i++)
                #pragma unroll
                for (int j = 0; j < 4; j++) acc[i][j] = bs2[c0 + j];
            #pragma unroll 4
            for (int kq = 0; kq < 64; kq += 4) {
                float4 xa[2], wa[4];
                #pragma unroll
                for (int i = 0; i < 2; i++) xa[i] = *(const float4*)&H1[(r0 + i) * 68 + kq];
                #pragma unroll
                for (int j = 0; j < 4; j++) wa[j] = *(const float4*)&Ws2[(kq + j) * 64 + c0];
                #pragma unroll
                for (int kk = 0; kk < 4; kk++)
                    #pragma unroll
                    for (int i = 0; i < 2; i++) {
                        float x = ((const float*)&xa[i])[kk];
                        #pragma unroll
                        for (int j = 0; j < 4; j++) acc[i][j] += x * ((const float*)&wa[kk])[j];
                    }
            }
            __syncthreads();
            #pragma unroll
            for (int i = 0; i < 2; i++) {
                float4 o; float* op = (float*)&o;
                #pragma unroll
                for (int j = 0; j < 4; j++) op[j] = lrelu_(acc[i][j]);
                *(float4*)&H2[(r0 + i) * 68 + c0] = o;
            }
        }
        __syncthreads();
        if (threadIdx.x < 128) {
            int row = threadIdx.x >> 2, c = threadIdx.x & 3;
            float acc = bs3[c];
            #pragma unroll 4
            for (int kq = 0; kq < 64; kq += 4) {
                float4 h = *(const float4*)&H2[row * 68 + kq];
                #pragma unroll
                for (int j = 0; j < 4; j++) acc += ((const float*)&h)[j] * Ws3[(kq + j) * 4 + c];
            }
            int g = base + row;
            if (g < n) out[(size_t)g * 4 + c] = sigm_(acc);
        }
    }
}

// ---------------- net head (32 rows/iter, grid-stride, C_out=1) ----------------
__global__ __launch_bounds__(256) void net_head3_kernel(const float* __restrict__ in_net, const float* __restrict__ tf,
                                                        const float* __restrict__ W1, const float* __restrict__ B1,
                                                        const float* __restrict__ W2, const float* __restrict__ B2,
                                                        const float* __restrict__ W3, const float* __restrict__ B3,
                                                        float* __restrict__ out, int n)
{
    __shared__ float Ws1[72 * 64], Ws2[64 * 64], Ws3[64];
    __shared__ float bs1[64], bs2[64], bs3[1];
    __shared__ float Xs[32 * 76];       // reused as H2 (stride 68)
    __shared__ float H1[32 * 68];
    for (int i = threadIdx.x; i < 72 * 64; i += 256) Ws1[i] = W1[i];
    for (int i = threadIdx.x; i < 64 * 64; i += 256) Ws2[i] = W2[i];
    if (threadIdx.x < 64) { Ws3[threadIdx.x] = W3[threadIdx.x]; bs1[threadIdx.x] = B1[threadIdx.x]; bs2[threadIdx.x] = B2[threadIdx.x]; }
    if (threadIdx.x == 0) bs3[0] = B3[0];
    const int tr = threadIdx.x >> 4, tc = threadIdx.x & 15;
    const int r0 = tr * 2, c0 = tc * 4;
    for (int base = blockIdx.x * 32; base < n; base += gridDim.x * 32) {
        __syncthreads();
        for (int i = threadIdx.x; i < 32 * 2; i += 256) {
            int row = i >> 1, kq = (i & 1) * 4;
            int g = base + row;
            float4 v = make_float4(0,0,0,0);
            if (g < n) v = *(const float4*)&in_net[(size_t)g * 8 + kq];
            *(float4*)&Xs[row * 76 + kq] = v;
        }
        for (int i = threadIdx.x; i < 32 * 16; i += 256) {
            int row = i >> 4, kq = (i & 15) * 4;
            int g = base + row;
            float4 v = make_float4(0,0,0,0);
            if (g < n) v = *(const float4*)&tf[(size_t)g * 64 + kq];
            *(float4*)&Xs[row * 76 + 8 + kq] = v;
        }
        __syncthreads();
        {
            float acc[2][4];
            #pragma unroll
            for (int i = 0; i < 2; i++)
                #pragma unroll
                for (int j = 0; j < 4; j++) acc[i][j] = bs1[c0 + j];
            #pragma unroll 4
            for (int kq = 0; kq < 72; kq += 4) {
                float4 xa[2], wa[4];
                #pragma unroll
                for (int i = 0; i < 2; i++) xa[i] = *(const float4*)&Xs[(r0 + i) * 76 + kq];
                #pragma unroll
                for (int j = 0; j < 4; j++) wa[j] = *(const float4*)&Ws1[(kq + j) * 64 + c0];
                #pragma unroll
                for (int kk = 0; kk < 4; kk++)
                    #pragma unroll
                    for (int i = 0; i < 2; i++) {
                        float x = ((const float*)&xa[i])[kk];
                        #pragma unroll
                        for (int j = 0; j < 4; j++) acc[i][j] += x * ((const float*)&wa[kk])[j];
                    }
            }
            #pragma unroll
            for (int i = 0; i < 2; i++) {
                float4 o; float* op = (float*)&o;
                #pragma unroll
                for (int j = 0; j < 4; j++) op[j] = lrelu_(acc[i][j]);
                *(float4*)&H1[(r0 + i) * 68 + c0] = o;
            }
        }
        __syncthreads();
        float* H2 = Xs;
        {
            float acc[2][4];
            #pragma unroll
            for (int i = 0; i < 2; i++)
                #pragma unroll
                for (int j = 0; j < 4; j++) acc[i][j] = bs2[c0 + j];
            #pragma unroll 4
            for (int kq = 0; kq < 64; kq += 4) {
                float4 xa[2], wa[4];
                #pragma unroll
                for (int i = 0; i < 2; i++) xa[i] = *(const float4*)&H1[(r0 + i) * 68 + kq];
                #pragma unroll
                for (int j = 0; j < 4; j++) wa[j] = *(const float4*)&Ws2[(kq + j) * 64 + c0];
                #pragma unroll
                for (int kk = 0; kk < 4; kk++)
                    #pragma unroll
                    for (int i = 0; i < 2; i++) {
                        float x = ((const float*)&xa[i])[kk];
                        #pragma unroll
                        for (int j = 0; j < 4; j++) acc[i][j] += x * ((const float*)&wa[kk])[j];
                    }
            }
            __syncthreads();
            #pragma unroll
            for (int i = 0; i < 2; i++) {
                float4 o; float* op = (float*)&o;
                #pragma unroll
                for (int j = 0; j < 4; j++) op[j] = lrelu_(acc[i][j]);
                *(float4*)&H2[(r0 + i) * 68 + c0] = o;
            }
        }
        __syncthreads();
        if (threadIdx.x < 32) {
            int row = threadIdx.x;
            float acc = bs3[0];
            #pragma unroll 4
            for (int kq = 0; kq < 64; kq += 4) {
                float4 h = *(const float4*)&H2[row * 68 + kq];
                float4 w = *(const float4*)&Ws3[kq];
                acc += h.x * w.x + h.y * w.y + h.z * w.z + h.w * w.w;
            }
            int g = base + row;
            if (g < n) out[g] = sigm_(acc);
        }
    }
}

extern "C" void kernel_launch(void* const* d_in, const int* in_sizes, int n_in,
                              void* d_out, int out_size, void* d_ws, size_t ws_size,
                              hipStream_t stream)
{
    (void)in_sizes; (void)n_in; (void)out_size; (void)ws_size;
    constexpr int Nn = 100000, Nt = 30000, Np = 400000, Ne = 1000000;
    constexpr int H = 64, L = 3, T = 4;

    auto fpt = [&](int i){ return (const float*)d_in[i]; };
    auto ipt = [&](int i){ return (const int*)d_in[i]; };

    const float* in_node = fpt(0);
    const float* in_net  = fpt(1);
    const float* in_pin  = fpt(2);
    const float* in_edge = fpt(3);
    const int* psrc = ipt(4);
    const int* pdst = ipt(5);
    const int* esrc = ipt(6);
    const int* edst = ipt(7);

    float* ws = (float*)d_ws;
    size_t o = 0;
    auto alloc = [&](size_t nel){ float* p = ws + o; o += nel; return p; };
    float* node_a = alloc((size_t)Nn * H);
    float* node_b = alloc((size_t)Nn * H);
    float* net_a  = alloc((size_t)Nt * H);
    float* net_b  = alloc((size_t)Nt * H);
    float* agg    = alloc((size_t)Nt * H);
    float* hv     = alloc((size_t)Nt * H);
    float* pinf   = alloc((size_t)Np * 16);
    float* h_cf   = alloc((size_t)Nn * H);
    float* hp     = alloc((size_t)Nn * H);
    float* h_ng   = alloc((size_t)Nn * H);
    float* ew3    = alloc((size_t)3 * Ne);
    float* snorm  = alloc((size_t)Nn);
    float* dnorm  = alloc((size_t)Nt);
    // CSR workspace: near (keyed by edst, Nn rows) and pins (keyed by pdst, Nt rows)
    int* cnt       = (int*)alloc((size_t)Nn);
    int* row_start = (int*)alloc((size_t)Nn + 1);
    int* nxt       = (int*)alloc((size_t)Nn);
    int* eidx      = (int*)alloc((size_t)Ne);
    int* bsum      = (int*)alloc((size_t)512);
    int* pcnt      = (int*)alloc((size_t)Nt);
    int* prow      = (int*)alloc((size_t)Nt + 1);
    int* pnxt      = (int*)alloc((size_t)Nt);
    int* peidx     = (int*)alloc((size_t)Np);
    int* pbsum     = (int*)alloc((size_t)256);

    constexpr int NB  = (Nn + 255) / 256;
    constexpr int NB2 = (Nt + 255) / 256;

    // degree norms for pins
    hipMemsetAsync(snorm, 0, (size_t)Nn * 4, stream);
    hipMemsetAsync(dnorm, 0, (size_t)Nt * 4, stream);
    deg_kernel<<<(Np + 255) / 256, 256, 0, stream>>>(psrc, pdst, (int*)snorm, (int*)dnorm, Np);
    norm_kernel<<<(Nn + 255) / 256, 256, 0, stream>>>((int*)snorm, Nn);
    norm_kernel<<<(Nt + 255) / 256, 256, 0, stream>>>((int*)dnorm, Nt);

    // build dst-CSR for 'near' (edst -> Nn rows)
    hipMemsetAsync(cnt, 0, (size_t)Nn * 4, stream);
    csr_count_kernel<<<(Ne + 255) / 256, 256, 0, stream>>>(edst, cnt, Ne);
    scan_block_sum_kernel<<<NB, 256, 0, stream>>>(cnt, bsum, Nn);
    scan_bsum_kernel<<<1, 64, 0, stream>>>(bsum, NB, row_start + Nn);
    scan_final_kernel<<<NB, 256, 0, stream>>>(cnt, bsum, row_start, nxt, Nn);
    csr_fill_kernel<<<(Ne + 255) / 256, 256, 0, stream>>>(edst, nxt, eidx, Ne);

    // build dst-CSR for 'pins' (pdst -> Nt rows)
    hipMemsetAsync(pcnt, 0, (size_t)Nt * 4, stream);
    csr_count_kernel<<<(Np + 255) / 256, 256, 0, stream>>>(pdst, pcnt, Np);
    scan_block_sum_kernel<<<NB2, 256, 0, stream>>>(pcnt, pbsum, Nt);
    scan_bsum_kernel<<<1, 64, 0, stream>>>(pbsum, NB2, prow + Nt);
    scan_final_kernel<<<NB2, 256, 0, stream>>>(pcnt, pbsum, prow, pnxt, Nt);
    csr_fill_kernel<<<(Np + 255) / 256, 256, 0, stream>>>(pdst, pnxt, peidx, Np);

    // input encoders
    gemm64_kernel<16, 1><<<1024, 256, 0, stream>>>(in_node, fpt(8),  fpt(9),  node_a, Nn);
    gemm64_kernel< 8, 1><<<469, 256, 0, stream>>>(in_net,  fpt(10), fpt(11), net_a,  Nt);
    lin_kernel<8, 16, 1><<<1024, 256, 0, stream>>>(in_pin, fpt(12), fpt(13), pinf, Np);
    edge_ew_kernel<<<2048, 256, 0, stream>>>(in_edge, fpt(14), fpt(15), fpt(16), fpt(17), ew3, Ne);

    float* ncur = node_a; float* nnew = node_b;
    float* tcur = net_a;  float* tnew = net_b;

    for (int i = 0; i < L; i++) {
        // pins GraphConv (node -> net): gather over pdst-CSR, dnorm folded
        pins_gather_kernel<<<(Nt + 3) / 4, 256, 0, stream>>>(ncur, snorm, dnorm, psrc, prow, peidx, agg, Nt);
        mfma_gemm_kernel<1><<<469, 256, 0, stream>>>(agg, fpt(18) + (size_t)i * 4096, fpt(19) + (size_t)i * 64, tnew, Nt);

        // CFConv (net -> node)
        mfma_gemm_kernel<0><<<469, 256, 0, stream>>>(tcur, fpt(20) + (size_t)i * 4096, fpt(21) + (size_t)i * 64, hv, Nt);
        hipMemsetAsync(h_cf, 0, (size_t)Nn * H * 4, stream);
        cf_pin5_kernel<<<1024, 256, 0, stream>>>(pinf, hv, psrc, pdst,
                                                 fpt(22) + (size_t)i * 1024, fpt(23) + (size_t)i * 64,
                                                 fpt(24) + (size_t)i * 4096, fpt(25) + (size_t)i * 64,
                                                 h_cf, Np);

        // SAGE (near): hp = relu(ncur @ pool + b), gather-max over dst-CSR
        mfma_gemm_kernel<2><<<1024, 256, 0, stream>>>(ncur, fpt(28) + (size_t)i * 4096, fpt(29) + (size_t)i * 64, hp, Nn);
        sage_gather_kernel<<<(Nn + 3) / 4, 256, 0, stream>>>(hp, ew3 + (size_t)i * Ne, esrc, row_start, eidx, h_ng, Nn);

        // combine: nnew = lrelu(max(ssp(h_cf@Wc+bc), ncur@Ws + h_ng@Wn + sb))  (single MFMA kernel)
        mfma_combine_kernel<<<1024, 256, 0, stream>>>(h_cf, ncur, h_ng,
                                                      fpt(26) + (size_t)i * 4096, fpt(27) + (size_t)i * 64,
                                                      fpt(30) + (size_t)i * 4096, fpt(31) + (size_t)i * 4096,
                                                      fpt(32) + (size_t)i * 64,
                                                      nnew, Nn);

        float* t;
        t = ncur; ncur = nnew; nnew = t;
        t = tcur; tcur = tnew; tnew = t;
    }

    float* out = (float*)d_out;
    node_head3_kernel<<<640, 256, 0, stream>>>(in_node, ncur, fpt(33), fpt(34), fpt(35), fpt(36), fpt(37), fpt(38), out, Nn);
    net_head3_kernel<<<480, 256, 0, stream>>>(in_net, tcur, fpt(39), fpt(40), fpt(41), fpt(42), fpt(43), fpt(44), out + (size_t)Nn * T, Nt);
}

// Round 11
// 1377.361 us; speedup vs baseline: 10.6942x; 1.0436x over previous
//
#include <hip/hip_runtime.h>
#include <hip/hip_bf16.h>

#define DEV __device__ __forceinline__

DEV float lrelu_(float x){ return x > 0.f ? x : 0.01f * x; }
DEV float ssp_(float x){ return fmaxf(x, 0.f) + __logf(1.f + __expf(-fabsf(x))) - 0.69314718055994530942f; }
DEV float sigm_(float x){ return 1.f / (1.f + __expf(-x)); }

DEV unsigned short f2bf(float x){
    unsigned int u = __float_as_uint(x);
    unsigned int r = (u + 0x7FFFu + ((u >> 16) & 1u)) >> 16;
    return (unsigned short)r;
}
DEV float bf2f(unsigned short s){ return __uint_as_float((unsigned int)s << 16); }
DEV ushort4 pack4(float4 v){
    ushort4 u; u.x = f2bf(v.x); u.y = f2bf(v.y); u.z = f2bf(v.z); u.w = f2bf(v.w); return u;
}

DEV void fma44(float (&acc)[4][4], const float4 (&xa)[4], const float4 (&wa)[4])
{
    #pragma unroll
    for (int kk = 0; kk < 4; kk++) {
        #pragma unroll
        for (int i = 0; i < 4; i++) {
            float x = ((const float*)&xa[i])[kk];
            #pragma unroll
            for (int j = 0; j < 4; j++)
                acc[i][j] += x * ((const float*)&wa[kk])[j];
        }
    }
}

typedef short s8v __attribute__((ext_vector_type(8)));
typedef float f4v __attribute__((ext_vector_type(4)));

// ====== generic tiled GEMM (VALU, small K): Y[N x 64] = act(X @ W[K x 64] + b) ======
// OUTBF: write bf16 (ushort) output
template<int K, int ACT, bool OUTBF>
__global__ __launch_bounds__(256) void gemm64_kernel(const float* __restrict__ X,
                                                     const float* __restrict__ W,
                                                     const float* __restrict__ B,
                                                     void* __restrict__ Yv, int nrows)
{
    constexpr int XS = K + 4;
    constexpr int KQ = K / 4;
    __shared__ float Ws[K * 64];
    __shared__ float bs[64];
    __shared__ float Xs[64 * XS];
    for (int i = threadIdx.x; i < K * 64; i += 256) Ws[i] = W[i];
    if (threadIdx.x < 64) bs[threadIdx.x] = B[threadIdx.x];
    const int tr = threadIdx.x >> 4, tc = threadIdx.x & 15;
    const int r0 = tr * 4, c0 = tc * 4;
    for (int base = blockIdx.x * 64; base < nrows; base += gridDim.x * 64) {
        __syncthreads();
        for (int i = threadIdx.x; i < 64 * KQ; i += 256) {
            int row = i / KQ, kq = (i % KQ) * 4;
            int g = base + row;
            float4 v = make_float4(0.f, 0.f, 0.f, 0.f);
            if (g < nrows) v = *(const float4*)&X[(size_t)g * K + kq];
            *(float4*)&Xs[row * XS + kq] = v;
        }
        __syncthreads();
        float acc[4][4];
        #pragma unroll
        for (int i = 0; i < 4; i++)
            #pragma unroll
            for (int j = 0; j < 4; j++) acc[i][j] = bs[c0 + j];
        #pragma unroll 4
        for (int kq = 0; kq < K; kq += 4) {
            float4 xa[4], wa[4];
            #pragma unroll
            for (int i = 0; i < 4; i++) xa[i] = *(const float4*)&Xs[(r0 + i) * XS + kq];
            #pragma unroll
            for (int j = 0; j < 4; j++) wa[j] = *(const float4*)&Ws[(kq + j) * 64 + c0];
            fma44(acc, xa, wa);
        }
        #pragma unroll
        for (int i = 0; i < 4; i++) {
            int g = base + r0 + i;
            if (g < nrows) {
                float4 o;
                float* op = (float*)&o;
                #pragma unroll
                for (int j = 0; j < 4; j++) {
                    float a = acc[i][j];
                    if (ACT == 1) a = lrelu_(a);
                    else if (ACT == 2) a = fmaxf(a, 0.f);
                    op[j] = a;
                }
                if (OUTBF) *(ushort4*)&((unsigned short*)Yv)[(size_t)g * 64 + c0] = pack4(o);
                else       *(float4*)&((float*)Yv)[(size_t)g * 64 + c0] = o;
            }
        }
    }
}

// ====== MFMA GEMM: Y = act(X @ W64x64 + b); INBF/OUTBF select bf16 storage ======
template<int ACT, bool INBF, bool OUTBF>
__global__ __launch_bounds__(256) void mfma_gemm_kernel(const void* __restrict__ Xv,
                                                        const float* __restrict__ W,
                                                        const float* __restrict__ B,
                                                        void* __restrict__ Yv, int nrows)
{
    __shared__ __align__(16) unsigned short WT[64 * 72];   // [n][k]
    __shared__ __align__(16) unsigned short Axs[64 * 72];  // [row][k]
    __shared__ float bs[64];
    for (int i = threadIdx.x; i < 4096; i += 256) {
        int k = i >> 6, nn = i & 63;
        WT[nn * 72 + k] = f2bf(W[i]);
    }
    if (threadIdx.x < 64) bs[threadIdx.x] = B[threadIdx.x];
    const int lane = threadIdx.x & 63, wv = threadIdx.x >> 6;
    const int l15 = lane & 15, quad = lane >> 4;
    const int arow = 16 * wv + l15;
    const int koff = quad * 8;
    for (int base = blockIdx.x * 64; base < nrows; base += gridDim.x * 64) {
        __syncthreads();
        {
            int row = threadIdx.x >> 2, kq = (threadIdx.x & 3) * 16;
            int g = base + row;
            if (INBF) {
                const unsigned short* Xb = (const unsigned short*)Xv;
                uint4 v0 = make_uint4(0,0,0,0), v1 = v0;
                if (g < nrows) {
                    v0 = *(const uint4*)&Xb[(size_t)g * 64 + kq];
                    v1 = *(const uint4*)&Xb[(size_t)g * 64 + kq + 8];
                }
                *(uint4*)&Axs[row * 72 + kq] = v0;
                *(uint4*)&Axs[row * 72 + kq + 8] = v1;
            } else {
                const float* Xf = (const float*)Xv;
                #pragma unroll
                for (int m = 0; m < 4; m++) {
                    float4 v = make_float4(0,0,0,0);
                    if (g < nrows) v = *(const float4*)&Xf[(size_t)g * 64 + kq + m * 4];
                    *(ushort4*)&Axs[row * 72 + kq + m * 4] = pack4(v);
                }
            }
        }
        __syncthreads();
        f4v acc[4];
        #pragma unroll
        for (int t = 0; t < 4; t++) acc[t] = (f4v){0.f,0.f,0.f,0.f};
        s8v a0 = *(const s8v*)&Axs[arow * 72 + koff];
        s8v a1 = *(const s8v*)&Axs[arow * 72 + 32 + koff];
        #pragma unroll
        for (int t = 0; t < 4; t++) {
            int nn = t * 16 + l15;
            s8v b0 = *(const s8v*)&WT[nn * 72 + koff];
            s8v b1 = *(const s8v*)&WT[nn * 72 + 32 + koff];
            acc[t] = __builtin_amdgcn_mfma_f32_16x16x32_bf16(a0, b0, acc[t], 0, 0, 0);
            acc[t] = __builtin_amdgcn_mfma_f32_16x16x32_bf16(a1, b1, acc[t], 0, 0, 0);
        }
        const int mrow = 16 * wv + quad * 4;
        #pragma unroll
        for (int t = 0; t < 4; t++) {
            int col = t * 16 + l15;
            float b = bs[col];
            #pragma unroll
            for (int r = 0; r < 4; r++) {
                int g = base + mrow + r;
                if (g < nrows) {
                    float a = acc[t][r] + b;
                    if (ACT == 1) a = lrelu_(a);
                    else if (ACT == 2) a = fmaxf(a, 0.f);
                    if (OUTBF) ((unsigned short*)Yv)[(size_t)g * 64 + col] = f2bf(a);
                    else       ((float*)Yv)[(size_t)g * 64 + col] = a;
                }
            }
        }
    }
}

// ====== MFMA triple-GEMM combine:
//   out(bf16) = lrelu(max( ssp(h_cf@Wc + bc),  nf@Ws + h_ng@Wn + sb ))
//   h_cf fp32; nf, h_ng bf16
__global__ __launch_bounds__(256) void mfma_combine_kernel(const float* __restrict__ h_cf,
                                                           const unsigned short* __restrict__ nfb,
                                                           const unsigned short* __restrict__ ngb,
                                                           const float* __restrict__ Wc, const float* __restrict__ cB,
                                                           const float* __restrict__ sW, const float* __restrict__ nW,
                                                           const float* __restrict__ sB,
                                                           unsigned short* __restrict__ outb, int n)
{
    __shared__ __align__(16) unsigned short WcT[64 * 72], WsT[64 * 72], WnT[64 * 72];
    __shared__ __align__(16) unsigned short Ac[32 * 72], As[32 * 72], An[32 * 72];
    __shared__ float bc[64], bsg[64];
    for (int i = threadIdx.x; i < 4096; i += 256) {
        int k = i >> 6, nn = i & 63;
        WcT[nn * 72 + k] = f2bf(Wc[i]);
        WsT[nn * 72 + k] = f2bf(sW[i]);
        WnT[nn * 72 + k] = f2bf(nW[i]);
    }
    if (threadIdx.x < 64) { bc[threadIdx.x] = cB[threadIdx.x]; bsg[threadIdx.x] = sB[threadIdx.x]; }
    const int lane = threadIdx.x & 63, wv = threadIdx.x >> 6;
    const int l15 = lane & 15, quad = lane >> 4;
    const int arow = (wv & 1) * 16 + l15;
    const int ct0 = (wv >> 1) * 2;
    const int koff = quad * 8;
    for (int base = blockIdx.x * 32; base < n; base += gridDim.x * 32) {
        __syncthreads();
        {
            int row = threadIdx.x >> 3, kq = (threadIdx.x & 7) * 8;
            int g = base + row;
            float4 c0v = make_float4(0,0,0,0), c1 = c0v;
            uint4 vf = make_uint4(0,0,0,0), vg = vf;
            if (g < n) {
                const float* pc = &h_cf[(size_t)g * 64 + kq];
                c0v = *(const float4*)pc; c1 = *(const float4*)(pc + 4);
                vf = *(const uint4*)&nfb[(size_t)g * 64 + kq];
                vg = *(const uint4*)&ngb[(size_t)g * 64 + kq];
            }
            *(ushort4*)&Ac[row * 72 + kq] = pack4(c0v);
            *(ushort4*)&Ac[row * 72 + kq + 4] = pack4(c1);
            *(uint4*)&As[row * 72 + kq] = vf;
            *(uint4*)&An[row * 72 + kq] = vg;
        }
        __syncthreads();
        f4v accC[2], accS[2];
        #pragma unroll
        for (int t = 0; t < 2; t++) { accC[t] = (f4v){0.f,0.f,0.f,0.f}; accS[t] = (f4v){0.f,0.f,0.f,0.f}; }
        s8v ac0 = *(const s8v*)&Ac[arow * 72 + koff];
        s8v ac1 = *(const s8v*)&Ac[arow * 72 + 32 + koff];
        s8v as0 = *(const s8v*)&As[arow * 72 + koff];
        s8v as1 = *(const s8v*)&As[arow * 72 + 32 + koff];
        s8v an0 = *(const s8v*)&An[arow * 72 + koff];
        s8v an1 = *(const s8v*)&An[arow * 72 + 32 + koff];
        #pragma unroll
        for (int t = 0; t < 2; t++) {
            int nn = (ct0 + t) * 16 + l15;
            s8v wc0 = *(const s8v*)&WcT[nn * 72 + koff];
            s8v wc1 = *(const s8v*)&WcT[nn * 72 + 32 + koff];
            accC[t] = __builtin_amdgcn_mfma_f32_16x16x32_bf16(ac0, wc0, accC[t], 0, 0, 0);
            accC[t] = __builtin_amdgcn_mfma_f32_16x16x32_bf16(ac1, wc1, accC[t], 0, 0, 0);
            s8v ws0 = *(const s8v*)&WsT[nn * 72 + koff];
            s8v ws1 = *(const s8v*)&WsT[nn * 72 + 32 + koff];
            accS[t] = __builtin_amdgcn_mfma_f32_16x16x32_bf16(as0, ws0, accS[t], 0, 0, 0);
            accS[t] = __builtin_amdgcn_mfma_f32_16x16x32_bf16(as1, ws1, accS[t], 0, 0, 0);
            s8v wn0 = *(const s8v*)&WnT[nn * 72 + koff];
            s8v wn1 = *(const s8v*)&WnT[nn * 72 + 32 + koff];
            accS[t] = __builtin_amdgcn_mfma_f32_16x16x32_bf16(an0, wn0, accS[t], 0, 0, 0);
            accS[t] = __builtin_amdgcn_mfma_f32_16x16x32_bf16(an1, wn1, accS[t], 0, 0, 0);
        }
        const int mrow = (wv & 1) * 16 + quad * 4;
        #pragma unroll
        for (int t = 0; t < 2; t++) {
            int col = (ct0 + t) * 16 + l15;
            float bcv = bc[col], bsv = bsg[col];
            #pragma unroll
            for (int r = 0; r < 4; r++) {
                int g = base + mrow + r;
                if (g < n)
                    outb[(size_t)g * 64 + col] = f2bf(lrelu_(fmaxf(ssp_(accC[t][r] + bcv), accS[t][r] + bsv)));
            }
        }
    }
}

// ---------------- small scalar GEMV (pin encoder, C=16) ----------------
template<int K, int C, int ACT>
__global__ __launch_bounds__(256) void lin_kernel(const float* __restrict__ X,
                                                  const float* __restrict__ W,
                                                  const float* __restrict__ B,
                                                  float* __restrict__ Y, int nrows)
{
    constexpr int ROWS = 256 / C;
    __shared__ float Ws[K * C];
    __shared__ float bs[C];
    __shared__ float Xs[ROWS * K];
    for (int i = threadIdx.x; i < K * C; i += 256) Ws[i] = W[i];
    if (threadIdx.x < C) bs[threadIdx.x] = B[threadIdx.x];
    __syncthreads();
    const int r = threadIdx.x / C, c = threadIdx.x % C;
    for (int base = blockIdx.x * ROWS; base < nrows; base += gridDim.x * ROWS) {
        __syncthreads();
        for (int i = threadIdx.x; i < ROWS * K; i += 256) {
            int rr = base + i / K;
            Xs[i] = (rr < nrows) ? X[(size_t)rr * K + i % K] : 0.f;
        }
        __syncthreads();
        int row = base + r;
        if (row < nrows) {
            float acc = bs[c];
            #pragma unroll
            for (int k = 0; k < K; k++) acc += Xs[r * K + k] * Ws[k * C + c];
            if (ACT == 1) acc = lrelu_(acc);
            else if (ACT == 2) acc = fmaxf(acc, 0.f);
            Y[(size_t)row * C + c] = acc;
        }
    }
}

// ---------------- degrees (for pins norms) ----------------
__global__ __launch_bounds__(256) void deg_kernel(const int* __restrict__ src, const int* __restrict__ dst,
                                                  int* __restrict__ degs, int* __restrict__ degd, int np)
{
    int p = blockIdx.x * 256 + threadIdx.x;
    if (p < np) { atomicAdd(&degs[src[p]], 1); atomicAdd(&degd[dst[p]], 1); }
}

__global__ __launch_bounds__(256) void norm_kernel(int* __restrict__ arr, int n)
{
    int i = blockIdx.x * 256 + threadIdx.x;
    if (i < n) {
        int v = arr[i]; if (v < 1) v = 1;
        arr[i] = __float_as_int(rsqrtf((float)v));
    }
}

// ================= CSR build (generic, keyed by given index array) =================
__global__ __launch_bounds__(256) void csr_count_kernel(const int* __restrict__ key, int* __restrict__ cnt, int ne)
{
    int e = blockIdx.x * 256 + threadIdx.x;
    if (e < ne) atomicAdd(&cnt[key[e]], 1);
}

__global__ __launch_bounds__(256) void scan_block_sum_kernel(const int* __restrict__ cnt, int* __restrict__ bsum, int n)
{
    __shared__ int sh[256];
    int i = blockIdx.x * 256 + threadIdx.x;
    sh[threadIdx.x] = (i < n) ? cnt[i] : 0;
    __syncthreads();
    for (int s = 128; s > 0; s >>= 1) {
        if (threadIdx.x < s) sh[threadIdx.x] += sh[threadIdx.x + s];
        __syncthreads();
    }
    if (threadIdx.x == 0) bsum[blockIdx.x] = sh[0];
}

__global__ void scan_bsum_kernel(int* __restrict__ bsum, int nb, int* __restrict__ total_out)
{
    if (threadIdx.x == 0 && blockIdx.x == 0) {
        int run = 0;
        for (int i = 0; i < nb; i++) { int v = bsum[i]; bsum[i] = run; run += v; }
        *total_out = run;
    }
}

__global__ __launch_bounds__(256) void scan_final_kernel(const int* __restrict__ cnt, const int* __restrict__ bsum,
                                                         int* __restrict__ row_start, int* __restrict__ nxt, int n)
{
    __shared__ int sh[256];
    int i = blockIdx.x * 256 + threadIdx.x;
    int v = (i < n) ? cnt[i] : 0;
    sh[threadIdx.x] = v;
    __syncthreads();
    for (int s = 1; s < 256; s <<= 1) {
        int add = (threadIdx.x >= s) ? sh[threadIdx.x - s] : 0;
        __syncthreads();
        sh[threadIdx.x] += add;
        __syncthreads();
    }
    if (i < n) {
        int excl = sh[threadIdx.x] - v + bsum[blockIdx.x];
        row_start[i] = excl;
        nxt[i] = excl;
    }
}

__global__ __launch_bounds__(256) void csr_fill_kernel(const int* __restrict__ key, int* __restrict__ nxt,
                                                       int* __restrict__ eidx, int ne)
{
    int e = blockIdx.x * 256 + threadIdx.x;
    if (e < ne) {
        int slot = atomicAdd(&nxt[key[e]], 1);
        eidx[slot] = e;
    }
}

// ---------------- edge weights for all 3 layers ----------------
__global__ __launch_bounds__(256) void edge_ew_kernel(const float* __restrict__ in_edge,
                                                      const float* __restrict__ elW, const float* __restrict__ elb,
                                                      const float* __restrict__ gW, const float* __restrict__ gb,
                                                      float* __restrict__ ew3, int ne)
{
    __shared__ float W[32], B[8], G[24], Gb[3];
    if (threadIdx.x < 32) W[threadIdx.x] = elW[threadIdx.x];
    if (threadIdx.x < 8)  B[threadIdx.x] = elb[threadIdx.x];
    if (threadIdx.x < 24) G[threadIdx.x] = gW[threadIdx.x];
    if (threadIdx.x < 3)  Gb[threadIdx.x] = gb[threadIdx.x];
    __syncthreads();
    for (int e = blockIdx.x * 256 + threadIdx.x; e < ne; e += gridDim.x * 256) {
        float4 x = *(const float4*)&in_edge[(size_t)e * 4];
        float ef[8];
        #pragma unroll
        for (int j = 0; j < 8; j++)
            ef[j] = lrelu_(B[j] + x.x * W[j] + x.y * W[8 + j] + x.z * W[16 + j] + x.w * W[24 + j]);
        #pragma unroll
        for (int i = 0; i < 3; i++) {
            float a = Gb[i];
            #pragma unroll
            for (int j = 0; j < 8; j++) a += ef[j] * G[i * 8 + j];
            ew3[(size_t)i * ne + e] = sigm_(a);
        }
    }
}

// ---------------- pins GraphConv gather over pdst-CSR (bf16 nf in, bf16 agg out) ----------------
__global__ __launch_bounds__(256) void pins_gather_kernel(const unsigned short* __restrict__ nfb,
                                                          const float* __restrict__ snorm,
                                                          const float* __restrict__ dnorm,
                                                          const int* __restrict__ psrc,
                                                          const int* __restrict__ prow,
                                                          const int* __restrict__ peidx,
                                                          unsigned short* __restrict__ aggb, int nt)
{
    const int lane = threadIdx.x & 63, wv = threadIdx.x >> 6;
    for (int d = blockIdx.x * 4 + wv; d < nt; d += gridDim.x * 4) {
        int rs = prow[d], re = prow[d + 1];
        float acc = 0.f;
        int k = rs;
        for (; k + 1 < re; k += 2) {
            int p0 = peidx[k], p1 = peidx[k + 1];
            int s0 = psrc[p0], s1 = psrc[p1];
            float n0 = snorm[s0], n1 = snorm[s1];
            float v0 = bf2f(nfb[(size_t)s0 * 64 + lane]) * n0;
            float v1 = bf2f(nfb[(size_t)s1 * 64 + lane]) * n1;
            acc += v0 + v1;
        }
        if (k < re) {
            int p0 = peidx[k];
            int s0 = psrc[p0];
            acc += bf2f(nfb[(size_t)s0 * 64 + lane]) * snorm[s0];
        }
        aggb[(size_t)d * 64 + lane] = f2bf(acc * dnorm[d]);
    }
}

// ---------------- CFConv fused: GEMM1 VALU + GEMM2 bf16-MFMA + dense wave scatter ----------------
// hv is bf16 now.
__global__ __launch_bounds__(256) void cf_pin5_kernel(const float* __restrict__ pinf,
                                                      const unsigned short* __restrict__ hvb,
                                                      const int* __restrict__ psrc, const int* __restrict__ pdst,
                                                      const float* __restrict__ W1, const float* __restrict__ B1,
                                                      const float* __restrict__ W2, const float* __restrict__ B2,
                                                      float* __restrict__ h_cf, int np)
{
    __shared__ float Ws1[16 * 64], bs1[64], bs2[64];
    __shared__ __align__(16) unsigned short W2T[64 * 72];  // B operand: [n][k] bf16
    __shared__ __align__(16) unsigned short T1s[64 * 72];  // A operand rows [p][k] bf16; reused as HE
    __shared__ float PF[64 * 20];
    __shared__ int srcS[64], dstS[64];
    for (int i = threadIdx.x; i < 16 * 64; i += 256) Ws1[i] = W1[i];
    for (int i = threadIdx.x; i < 64 * 64; i += 256) {
        int k = i >> 6, n = i & 63;
        W2T[n * 72 + k] = f2bf(W2[i]);
    }
    if (threadIdx.x < 64) { bs1[threadIdx.x] = B1[threadIdx.x]; bs2[threadIdx.x] = B2[threadIdx.x]; }
    const int tr = threadIdx.x >> 4, tc = threadIdx.x & 15;
    const int r0 = tr * 4, c0 = tc * 4;
    const int lane = threadIdx.x & 63, wv = threadIdx.x >> 6;
    const int l15 = lane & 15, quad = lane >> 4;
    const int arow = 16 * wv + l15;
    const int koff = quad * 8;
    for (int base = blockIdx.x * 64; base < np; base += gridDim.x * 64) {
        __syncthreads();
        {
            int row = threadIdx.x >> 2, kq = (threadIdx.x & 3) * 4;
            int p = base + row;
            float4 v = make_float4(0.f, 0.f, 0.f, 0.f);
            if (p < np) v = *(const float4*)&pinf[(size_t)p * 16 + kq];
            *(float4*)&PF[row * 20 + kq] = v;
            if (threadIdx.x < 64) {
                int pp = base + threadIdx.x;
                srcS[threadIdx.x] = (pp < np) ? psrc[pp] : 0;
                dstS[threadIdx.x] = (pp < np) ? pdst[pp] : 0;
            }
        }
        __syncthreads();
        // GEMM1 (VALU, K=16): T1 = ssp(PF @ W1 + b1) -> bf16 LDS rows
        {
            float acc[4][4];
            #pragma unroll
            for (int i = 0; i < 4; i++)
                #pragma unroll
                for (int j = 0; j < 4; j++) acc[i][j] = bs1[c0 + j];
            #pragma unroll
            for (int kq = 0; kq < 16; kq += 4) {
                float4 xa[4], wa[4];
                #pragma unroll
                for (int i = 0; i < 4; i++) xa[i] = *(const float4*)&PF[(r0 + i) * 20 + kq];
                #pragma unroll
                for (int j = 0; j < 4; j++) wa[j] = *(const float4*)&Ws1[(kq + j) * 64 + c0];
                fma44(acc, xa, wa);
            }
            #pragma unroll
            for (int i = 0; i < 4; i++) {
                ushort4 o;
                o.x = f2bf(ssp_(acc[i][0]));
                o.y = f2bf(ssp_(acc[i][1]));
                o.z = f2bf(ssp_(acc[i][2]));
                o.w = f2bf(ssp_(acc[i][3]));
                *(ushort4*)&T1s[(r0 + i) * 72 + c0] = o;
            }
        }
        __syncthreads();
        // GEMM2 (MFMA bf16): HE = ssp(T1 @ W2 + b2); wave w computes rows 16w..16w+15
        {
            f4v acc4[4];
            #pragma unroll
            for (int t = 0; t < 4; t++) acc4[t] = (f4v){0.f, 0.f, 0.f, 0.f};
            s8v a0 = *(const s8v*)&T1s[arow * 72 + koff];
            s8v a1 = *(const s8v*)&T1s[arow * 72 + 32 + koff];
            #pragma unroll
            for (int t = 0; t < 4; t++) {
                int n = t * 16 + l15;
                s8v b0 = *(const s8v*)&W2T[n * 72 + koff];
                s8v b1 = *(const s8v*)&W2T[n * 72 + 32 + koff];
                acc4[t] = __builtin_amdgcn_mfma_f32_16x16x32_bf16(a0, b0, acc4[t], 0, 0, 0);
                acc4[t] = __builtin_amdgcn_mfma_f32_16x16x32_bf16(a1, b1, acc4[t], 0, 0, 0);
            }
            __syncthreads();   // all A reads done; safe to overwrite T1s with HE
            const int mrow = 16 * wv + quad * 4;
            #pragma unroll
            for (int t = 0; t < 4; t++) {
                int col = t * 16 + l15;
                float b = bs2[col];
                #pragma unroll
                for (int r = 0; r < 4; r++)
                    T1s[(mrow + r) * 72 + col] = f2bf(ssp_(acc4[t][r] + b));
            }
        }
        __syncthreads();
        // scatter: one wave per pin-row; 64 lanes = 64 contiguous channels
        #pragma unroll 4
        for (int i = 0; i < 16; i++) {
            int pl = wv * 16 + i;
            int p = base + pl;
            if (p < np) {
                float m = bf2f(hvb[(size_t)dstS[pl] * 64 + lane]) * bf2f(T1s[pl * 72 + lane]);
                unsafeAtomicAdd(&h_cf[(size_t)srcS[pl] * 64 + lane], m);
            }
        }
    }
}

// ---------------- SAGE gather-max over dst-CSR (bf16 hp in, bf16 h_ng out) ----------------
__global__ __launch_bounds__(256) void sage_gather_kernel(const unsigned short* __restrict__ hpb,
                                                          const float* __restrict__ ew,
                                                          const int* __restrict__ esrc,
                                                          const int* __restrict__ row_start,
                                                          const int* __restrict__ eidx,
                                                          unsigned short* __restrict__ ngb, int nn)
{
    const int lane = threadIdx.x & 63, wv = threadIdx.x >> 6;
    for (int d = blockIdx.x * 4 + wv; d < nn; d += gridDim.x * 4) {
        int rs = row_start[d], re = row_start[d + 1];
        float acc = 0.f;
        int k = rs;
        for (; k + 1 < re; k += 2) {
            int e0 = eidx[k], e1 = eidx[k + 1];
            int s0 = esrc[e0], s1 = esrc[e1];
            float w0 = ew[e0], w1 = ew[e1];
            float v0 = bf2f(hpb[(size_t)s0 * 64 + lane]) * w0;
            float v1 = bf2f(hpb[(size_t)s1 * 64 + lane]) * w1;
            acc = fmaxf(acc, fmaxf(v0, v1));
        }
        if (k < re) {
            int e0 = eidx[k];
            int s0 = esrc[e0];
            acc = fmaxf(acc, bf2f(hpb[(size_t)s0 * 64 + lane]) * ew[e0]);
        }
        ngb[(size_t)d * 64 + lane] = f2bf(acc);
    }
}

// ---------------- node head (32 rows/iter, grid-stride, 3-stage MLP; nf is bf16) ----------------
__global__ __launch_bounds__(256) void node_head3_kernel(const float* __restrict__ in_node,
                                                         const unsigned short* __restrict__ nfb,
                                                         const float* __restrict__ W1, const float* __restrict__ B1,
                                                         const float* __restrict__ W2, const float* __restrict__ B2,
                                                         const float* __restrict__ W3, const float* __restrict__ B3,
                                                         float* __restrict__ out, int n)
{
    __shared__ float Ws1[80 * 64], Ws2[64 * 64], Ws3[64 * 4];
    __shared__ float bs1[64], bs2[64], bs3[4];
    __shared__ float Xs[32 * 84];       // reused as H2 (stride 68)
    __shared__ float H1[32 * 68];
    for (int i = threadIdx.x; i < 80 * 64; i += 256) Ws1[i] = W1[i];
    for (int i = threadIdx.x; i < 64 * 64; i += 256) Ws2[i] = W2[i];
    for (int i = threadIdx.x; i < 64 * 4; i += 256) Ws3[i] = W3[i];
    if (threadIdx.x < 64) { bs1[threadIdx.x] = B1[threadIdx.x]; bs2[threadIdx.x] = B2[threadIdx.x]; }
    if (threadIdx.x < 4) bs3[threadIdx.x] = B3[threadIdx.x];
    const int tr = threadIdx.x >> 4, tc = threadIdx.x & 15;
    const int r0 = tr * 2, c0 = tc * 4;
    for (int base = blockIdx.x * 32; base < n; base += gridDim.x * 32) {
        __syncthreads();
        for (int i = threadIdx.x; i < 32 * 4; i += 256) {
            int row = i >> 2, kq = (i & 3) * 4;
            int g = base + row;
            float4 v = make_float4(0,0,0,0);
            if (g < n) v = *(const float4*)&in_node[(size_t)g * 16 + kq];
            *(float4*)&Xs[row * 84 + kq] = v;
        }
        for (int i = threadIdx.x; i < 32 * 16; i += 256) {
            int row = i >> 4, kq = (i & 15) * 4;
            int g = base + row;
            float4 v = make_float4(0,0,0,0);
            if (g < n) {
                ushort4 u = *(const ushort4*)&nfb[(size_t)g * 64 + kq];
                v.x = bf2f(u.x); v.y = bf2f(u.y); v.z = bf2f(u.z); v.w = bf2f(u.w);
            }
            *(float4*)&Xs[row * 84 + 16 + kq] = v;
        }
        __syncthreads();
        {
            float acc[2][4];
            #pragma unroll
            for (int i = 0; i < 2; i++)
                #pragma unroll
                for (int j = 0; j < 4; j++) acc[i][j] = bs1[c0 + j];
            #pragma unroll 4
            for (int kq = 0; kq < 80; kq += 4) {
                float4 xa[2], wa[4];
                #pragma unroll
                for (int i = 0; i < 2; i++) xa[i] = *(const float4*)&Xs[(r0 + i) * 84 + kq];
                #pragma unroll
                for (int j = 0; j < 4; j++) wa[j] = *(const float4*)&Ws1[(kq + j) * 64 + c0];
                #pragma unroll
                for (int kk = 0; kk < 4; kk++)
                    #pragma unroll
                    for (int i = 0; i < 2; i++) {
                        float x = ((const float*)&xa[i])[kk];
                        #pragma unroll
                        for (int j = 0; j < 4; j++) acc[i][j] += x * ((const float*)&wa[kk])[j];
                    }
            }
            #pragma unroll
            for (int i = 0; i < 2; i++) {
                float4 o; float* op = (float*)&o;
                #pragma unroll
                for (int j = 0; j < 4; j++) op[j] = lrelu_(acc[i][j]);
                *(float4*)&H1[(r0 + i) * 68 + c0] = o;
            }
        }
        __syncthreads();
        float* H2 = Xs;
        {
            float acc[2][4];
            #pragma unroll
            for (int i = 0; i < 2; i++)
                #pragma unroll
                for (int j = 0; j < 4; j++) acc[i][j] = bs2[c0 + j];
            #pragma unroll 4
            for (int kq = 0; kq < 64; kq += 4) {
                float4 xa[2], wa[4];
                #pragma unroll
                for (int i = 0; i < 2; i++) xa[i] = *(const float4*)&H1[(r0 + i) * 68 + kq];
                #pragma unroll
                for (int j = 0; j < 4; j++) wa[j] = *(const float4*)&Ws2[(kq + j) * 64 + c0];
                #pragma unroll
                for (int kk = 0; kk < 4; kk++)
                    #pragma unroll
                    for (int i = 0; i < 2; i++) {
                        float x = ((const float*)&xa[i])[kk];
                        #pragma unroll
                        for (int j = 0; j < 4; j++) acc[i][j] += x * ((const float*)&wa[kk])[j];
                    }
            }
            __syncthreads();
            #pragma unroll
            for (int i = 0; i < 2; i++) {
                float4 o; float* op = (float*)&o;
                #pragma unroll
                for (int j = 0; j < 4; j++) op[j] = lrelu_(acc[i][j]);
                *(float4*)&H2[(r0 + i) * 68 + c0] = o;
            }
        }
        __syncthreads();
        if (threadIdx.x < 128) {
            int row = threadIdx.x >> 2, c = threadIdx.x & 3;
            float acc = bs3[c];
            #pragma unroll 4
            for (int kq = 0; kq < 64; kq += 4) {
                float4 h = *(const float4*)&H2[row * 68 + kq];
                #pragma unroll
                for (int j = 0; j < 4; j++) acc += ((const float*)&h)[j] * Ws3[(kq + j) * 4 + c];
            }
            int g = base + row;
            if (g < n) out[(size_t)g * 4 + c] = sigm_(acc);
        }
    }
}

// ---------------- net head (32 rows/iter, grid-stride, C_out=1; tf fp32) ----------------
__global__ __launch_bounds__(256) void net_head3_kernel(const float* __restrict__ in_net, const float* __restrict__ tf,
                                                        const float* __restrict__ W1, const float* __restrict__ B1,
                                                        const float* __restrict__ W2, const float* __restrict__ B2,
                                                        const float* __restrict__ W3, const float* __restrict__ B3,
                                                        float* __restrict__ out, int n)
{
    __shared__ float Ws1[72 * 64], Ws2[64 * 64], Ws3[64];
    __shared__ float bs1[64], bs2[64], bs3[1];
    __shared__ float Xs[32 * 76];       // reused as H2 (stride 68)
    __shared__ float H1[32 * 68];
    for (int i = threadIdx.x; i < 72 * 64; i += 256) Ws1[i] = W1[i];
    for (int i = threadIdx.x; i < 64 * 64; i += 256) Ws2[i] = W2[i];
    if (threadIdx.x < 64) { Ws3[threadIdx.x] = W3[threadIdx.x]; bs1[threadIdx.x] = B1[threadIdx.x]; bs2[threadIdx.x] = B2[threadIdx.x]; }
    if (threadIdx.x == 0) bs3[0] = B3[0];
    const int tr = threadIdx.x >> 4, tc = threadIdx.x & 15;
    const int r0 = tr * 2, c0 = tc * 4;
    for (int base = blockIdx.x * 32; base < n; base += gridDim.x * 32) {
        __syncthreads();
        for (int i = threadIdx.x; i < 32 * 2; i += 256) {
            int row = i >> 1, kq = (i & 1) * 4;
            int g = base + row;
            float4 v = make_float4(0,0,0,0);
            if (g < n) v = *(const float4*)&in_net[(size_t)g * 8 + kq];
            *(float4*)&Xs[row * 76 + kq] = v;
        }
        for (int i = threadIdx.x; i < 32 * 16; i += 256) {
            int row = i >> 4, kq = (i & 15) * 4;
            int g = base + row;
            float4 v = make_float4(0,0,0,0);
            if (g < n) v = *(const float4*)&tf[(size_t)g * 64 + kq];
            *(float4*)&Xs[row * 76 + 8 + kq] = v;
        }
        __syncthreads();
        {
            float acc[2][4];
            #pragma unroll
            for (int i = 0; i < 2; i++)
                #pragma unroll
                for (int j = 0; j < 4; j++) acc[i][j] = bs1[c0 + j];
            #pragma unroll 4
            for (int kq = 0; kq < 72; kq += 4) {
                float4 xa[2], wa[4];
                #pragma unroll
                for (int i = 0; i < 2; i++) xa[i] = *(const float4*)&Xs[(r0 + i) * 76 + kq];
                #pragma unroll
                for (int j = 0; j < 4; j++) wa[j] = *(const float4*)&Ws1[(kq + j) * 64 + c0];
                #pragma unroll
                for (int kk = 0; kk < 4; kk++)
                    #pragma unroll
                    for (int i = 0; i < 2; i++) {
                        float x = ((const float*)&xa[i])[kk];
                        #pragma unroll
                        for (int j = 0; j < 4; j++) acc[i][j] += x * ((const float*)&wa[kk])[j];
                    }
            }
            #pragma unroll
            for (int i = 0; i < 2; i++) {
                float4 o; float* op = (float*)&o;
                #pragma unroll
                for (int j = 0; j < 4; j++) op[j] = lrelu_(acc[i][j]);
                *(float4*)&H1[(r0 + i) * 68 + c0] = o;
            }
        }
        __syncthreads();
        float* H2 = Xs;
        {
            float acc[2][4];
            #pragma unroll
            for (int i = 0; i < 2; i++)
                #pragma unroll
                for (int j = 0; j < 4; j++) acc[i][j] = bs2[c0 + j];
            #pragma unroll 4
            for (int kq = 0; kq < 64; kq += 4) {
                float4 xa[2], wa[4];
                #pragma unroll
                for (int i = 0; i < 2; i++) xa[i] = *(const float4*)&H1[(r0 + i) * 68 + kq];
                #pragma unroll
                for (int j = 0; j < 4; j++) wa[j] = *(const float4*)&Ws2[(kq + j) * 64 + c0];
                #pragma unroll
                for (int kk = 0; kk < 4; kk++)
                    #pragma unroll
                    for (int i = 0; i < 2; i++) {
                        float x = ((const float*)&xa[i])[kk];
                        #pragma unroll
                        for (int j = 0; j < 4; j++) acc[i][j] += x * ((const float*)&wa[kk])[j];
                    }
            }
            __syncthreads();
            #pragma unroll
            for (int i = 0; i < 2; i++) {
                float4 o; float* op = (float*)&o;
                #pragma unroll
                for (int j = 0; j < 4; j++) op[j] = lrelu_(acc[i][j]);
                *(float4*)&H2[(r0 + i) * 68 + c0] = o;
            }
        }
        __syncthreads();
        if (threadIdx.x < 32) {
            int row = threadIdx.x;
            float acc = bs3[0];
            #pragma unroll 4
            for (int kq = 0; kq < 64; kq += 4) {
                float4 h = *(const float4*)&H2[row * 68 + kq];
                float4 w = *(const float4*)&Ws3[kq];
                acc += h.x * w.x + h.y * w.y + h.z * w.z + h.w * w.w;
            }
            int g = base + row;
            if (g < n) out[g] = sigm_(acc);
        }
    }
}

extern "C" void kernel_launch(void* const* d_in, const int* in_sizes, int n_in,
                              void* d_out, int out_size, void* d_ws, size_t ws_size,
                              hipStream_t stream)
{
    (void)in_sizes; (void)n_in; (void)out_size; (void)ws_size;
    constexpr int Nn = 100000, Nt = 30000, Np = 400000, Ne = 1000000;
    constexpr int H = 64, L = 3, T = 4;

    auto fpt = [&](int i){ return (const float*)d_in[i]; };
    auto ipt = [&](int i){ return (const int*)d_in[i]; };

    const float* in_node = fpt(0);
    const float* in_net  = fpt(1);
    const float* in_pin  = fpt(2);
    const float* in_edge = fpt(3);
    const int* psrc = ipt(4);
    const int* pdst = ipt(5);
    const int* esrc = ipt(6);
    const int* edst = ipt(7);

    float* ws = (float*)d_ws;
    size_t o = 0;
    auto alloc = [&](size_t nel){ float* p = ws + o; o += nel; return p; };
    // bf16 feature buffers (allocated in float units, used as ushort)
    unsigned short* node_a = (unsigned short*)alloc((size_t)Nn * 32);
    unsigned short* node_b = (unsigned short*)alloc((size_t)Nn * 32);
    unsigned short* aggb   = (unsigned short*)alloc((size_t)Nt * 32);
    unsigned short* hvb    = (unsigned short*)alloc((size_t)Nt * 32);
    unsigned short* hpb    = (unsigned short*)alloc((size_t)Nn * 32);
    unsigned short* ngb    = (unsigned short*)alloc((size_t)Nn * 32);
    float* net_a  = alloc((size_t)Nt * H);
    float* net_b  = alloc((size_t)Nt * H);
    float* pinf   = alloc((size_t)Np * 16);
    float* h_cf   = alloc((size_t)Nn * H);
    float* ew3    = alloc((size_t)3 * Ne);
    float* snorm  = alloc((size_t)Nn);
    float* dnorm  = alloc((size_t)Nt);
    // CSR workspace
    int* cnt       = (int*)alloc((size_t)Nn);
    int* row_start = (int*)alloc((size_t)Nn + 1);
    int* nxt       = (int*)alloc((size_t)Nn);
    int* eidx      = (int*)alloc((size_t)Ne);
    int* bsum      = (int*)alloc((size_t)512);
    int* pcnt      = (int*)alloc((size_t)Nt);
    int* prow      = (int*)alloc((size_t)Nt + 1);
    int* pnxt      = (int*)alloc((size_t)Nt);
    int* peidx     = (int*)alloc((size_t)Np);
    int* pbsum     = (int*)alloc((size_t)256);

    constexpr int NB  = (Nn + 255) / 256;
    constexpr int NB2 = (Nt + 255) / 256;

    // degree norms for pins
    hipMemsetAsync(snorm, 0, (size_t)Nn * 4, stream);
    hipMemsetAsync(dnorm, 0, (size_t)Nt * 4, stream);
    deg_kernel<<<(Np + 255) / 256, 256, 0, stream>>>(psrc, pdst, (int*)snorm, (int*)dnorm, Np);
    norm_kernel<<<(Nn + 255) / 256, 256, 0, stream>>>((int*)snorm, Nn);
    norm_kernel<<<(Nt + 255) / 256, 256, 0, stream>>>((int*)dnorm, Nt);

    // build dst-CSR for 'near' (edst -> Nn rows)
    hipMemsetAsync(cnt, 0, (size_t)Nn * 4, stream);
    csr_count_kernel<<<(Ne + 255) / 256, 256, 0, stream>>>(edst, cnt, Ne);
    scan_block_sum_kernel<<<NB, 256, 0, stream>>>(cnt, bsum, Nn);
    scan_bsum_kernel<<<1, 64, 0, stream>>>(bsum, NB, row_start + Nn);
    scan_final_kernel<<<NB, 256, 0, stream>>>(cnt, bsum, row_start, nxt, Nn);
    csr_fill_kernel<<<(Ne + 255) / 256, 256, 0, stream>>>(edst, nxt, eidx, Ne);

    // build dst-CSR for 'pins' (pdst -> Nt rows)
    hipMemsetAsync(pcnt, 0, (size_t)Nt * 4, stream);
    csr_count_kernel<<<(Np + 255) / 256, 256, 0, stream>>>(pdst, pcnt, Np);
    scan_block_sum_kernel<<<NB2, 256, 0, stream>>>(pcnt, pbsum, Nt);
    scan_bsum_kernel<<<1, 64, 0, stream>>>(pbsum, NB2, prow + Nt);
    scan_final_kernel<<<NB2, 256, 0, stream>>>(pcnt, pbsum, prow, pnxt, Nt);
    csr_fill_kernel<<<(Np + 255) / 256, 256, 0, stream>>>(pdst, pnxt, peidx, Np);

    // input encoders
    gemm64_kernel<16, 1, true><<<1024, 256, 0, stream>>>(in_node, fpt(8),  fpt(9),  node_a, Nn);
    gemm64_kernel< 8, 1, false><<<469, 256, 0, stream>>>(in_net,  fpt(10), fpt(11), net_a,  Nt);
    lin_kernel<8, 16, 1><<<1024, 256, 0, stream>>>(in_pin, fpt(12), fpt(13), pinf, Np);
    edge_ew_kernel<<<2048, 256, 0, stream>>>(in_edge, fpt(14), fpt(15), fpt(16), fpt(17), ew3, Ne);

    unsigned short* ncur = node_a; unsigned short* nnew = node_b;
    float* tcur = net_a;  float* tnew = net_b;

    for (int i = 0; i < L; i++) {
        // pins GraphConv (node -> net): gather over pdst-CSR (bf16 in/out), then MFMA linear
        pins_gather_kernel<<<(Nt + 3) / 4, 256, 0, stream>>>(ncur, snorm, dnorm, psrc, prow, peidx, aggb, Nt);
        mfma_gemm_kernel<1, true, false><<<469, 256, 0, stream>>>(aggb, fpt(18) + (size_t)i * 4096, fpt(19) + (size_t)i * 64, tnew, Nt);

        // CFConv (net -> node): hv bf16
        mfma_gemm_kernel<0, false, true><<<469, 256, 0, stream>>>(tcur, fpt(20) + (size_t)i * 4096, fpt(21) + (size_t)i * 64, hvb, Nt);
        hipMemsetAsync(h_cf, 0, (size_t)Nn * H * 4, stream);
        cf_pin5_kernel<<<1024, 256, 0, stream>>>(pinf, hvb, psrc, pdst,
                                                 fpt(22) + (size_t)i * 1024, fpt(23) + (size_t)i * 64,
                                                 fpt(24) + (size_t)i * 4096, fpt(25) + (size_t)i * 64,
                                                 h_cf, Np);

        // SAGE (near): hp bf16 = relu(ncur @ pool + b), gather-max (bf16 in/out)
        mfma_gemm_kernel<2, true, true><<<1024, 256, 0, stream>>>(ncur, fpt(28) + (size_t)i * 4096, fpt(29) + (size_t)i * 64, hpb, Nn);
        sage_gather_kernel<<<(Nn + 3) / 4, 256, 0, stream>>>(hpb, ew3 + (size_t)i * Ne, esrc, row_start, eidx, ngb, Nn);

        // combine: nnew(bf16) = lrelu(max(ssp(h_cf@Wc+bc), ncur@Ws + h_ng@Wn + sb))
        mfma_combine_kernel<<<1024, 256, 0, stream>>>(h_cf, ncur, ngb,
                                                      fpt(26) + (size_t)i * 4096, fpt(27) + (size_t)i * 64,
                                                      fpt(30) + (size_t)i * 4096, fpt(31) + (size_t)i * 4096,
                                                      fpt(32) + (size_t)i * 64,
                                                      nnew, Nn);

        unsigned short* t = ncur; ncur = nnew; nnew = t;
        float* tf = tcur; tcur = tnew; tnew = tf;
    }

    float* out = (float*)d_out;
    node_head3_kernel<<<640, 256, 0, stream>>>(in_node, ncur, fpt(33), fpt(34), fpt(35), fpt(36), fpt(37), fpt(38), out, Nn);
    net_head3_kernel<<<480, 256, 0, stream>>>(in_net, tcur, fpt(39), fpt(40), fpt(41), fpt(42), fpt(43), fpt(44), out + (size_t)Nn * T, Nt);
}

// Round 12
// 1140.426 us; speedup vs baseline: 12.9161x; 1.2078x over previous
//
#include <hip/hip_runtime.h>
#include <hip/hip_bf16.h>

#define DEV __device__ __forceinline__

DEV float lrelu_(float x){ return x > 0.f ? x : 0.01f * x; }
DEV float ssp_(float x){ return fmaxf(x, 0.f) + __logf(1.f + __expf(-fabsf(x))) - 0.69314718055994530942f; }
DEV float sigm_(float x){ return 1.f / (1.f + __expf(-x)); }

DEV unsigned short f2bf(float x){
    unsigned int u = __float_as_uint(x);
    unsigned int r = (u + 0x7FFFu + ((u >> 16) & 1u)) >> 16;
    return (unsigned short)r;
}
DEV float bf2f(unsigned short s){ return __uint_as_float((unsigned int)s << 16); }
DEV ushort4 pack4(float4 v){
    ushort4 u; u.x = f2bf(v.x); u.y = f2bf(v.y); u.z = f2bf(v.z); u.w = f2bf(v.w); return u;
}

DEV void fma44(float (&acc)[4][4], const float4 (&xa)[4], const float4 (&wa)[4])
{
    #pragma unroll
    for (int kk = 0; kk < 4; kk++) {
        #pragma unroll
        for (int i = 0; i < 4; i++) {
            float x = ((const float*)&xa[i])[kk];
            #pragma unroll
            for (int j = 0; j < 4; j++)
                acc[i][j] += x * ((const float*)&wa[kk])[j];
        }
    }
}

typedef short s8v __attribute__((ext_vector_type(8)));
typedef float f4v __attribute__((ext_vector_type(4)));

// ====== generic tiled GEMM (VALU, small K): Y[N x 64] = act(X @ W[K x 64] + b) ======
template<int K, int ACT, bool OUTBF>
__global__ __launch_bounds__(256) void gemm64_kernel(const float* __restrict__ X,
                                                     const float* __restrict__ W,
                                                     const float* __restrict__ B,
                                                     void* __restrict__ Yv, int nrows)
{
    constexpr int XS = K + 4;
    constexpr int KQ = K / 4;
    __shared__ float Ws[K * 64];
    __shared__ float bs[64];
    __shared__ float Xs[64 * XS];
    for (int i = threadIdx.x; i < K * 64; i += 256) Ws[i] = W[i];
    if (threadIdx.x < 64) bs[threadIdx.x] = B[threadIdx.x];
    const int tr = threadIdx.x >> 4, tc = threadIdx.x & 15;
    const int r0 = tr * 4, c0 = tc * 4;
    for (int base = blockIdx.x * 64; base < nrows; base += gridDim.x * 64) {
        __syncthreads();
        for (int i = threadIdx.x; i < 64 * KQ; i += 256) {
            int row = i / KQ, kq = (i % KQ) * 4;
            int g = base + row;
            float4 v = make_float4(0.f, 0.f, 0.f, 0.f);
            if (g < nrows) v = *(const float4*)&X[(size_t)g * K + kq];
            *(float4*)&Xs[row * XS + kq] = v;
        }
        __syncthreads();
        float acc[4][4];
        #pragma unroll
        for (int i = 0; i < 4; i++)
            #pragma unroll
            for (int j = 0; j < 4; j++) acc[i][j] = bs[c0 + j];
        #pragma unroll 4
        for (int kq = 0; kq < K; kq += 4) {
            float4 xa[4], wa[4];
            #pragma unroll
            for (int i = 0; i < 4; i++) xa[i] = *(const float4*)&Xs[(r0 + i) * XS + kq];
            #pragma unroll
            for (int j = 0; j < 4; j++) wa[j] = *(const float4*)&Ws[(kq + j) * 64 + c0];
            fma44(acc, xa, wa);
        }
        #pragma unroll
        for (int i = 0; i < 4; i++) {
            int g = base + r0 + i;
            if (g < nrows) {
                float4 o;
                float* op = (float*)&o;
                #pragma unroll
                for (int j = 0; j < 4; j++) {
                    float a = acc[i][j];
                    if (ACT == 1) a = lrelu_(a);
                    else if (ACT == 2) a = fmaxf(a, 0.f);
                    op[j] = a;
                }
                if (OUTBF) *(ushort4*)&((unsigned short*)Yv)[(size_t)g * 64 + c0] = pack4(o);
                else       *(float4*)&((float*)Yv)[(size_t)g * 64 + c0] = o;
            }
        }
    }
}

// ====== MFMA GEMM: Y = act(X @ W64x64 + b); INBF/OUTBF select bf16 storage ======
template<int ACT, bool INBF, bool OUTBF>
__global__ __launch_bounds__(256) void mfma_gemm_kernel(const void* __restrict__ Xv,
                                                        const float* __restrict__ W,
                                                        const float* __restrict__ B,
                                                        void* __restrict__ Yv, int nrows)
{
    __shared__ __align__(16) unsigned short WT[64 * 72];   // [n][k]
    __shared__ __align__(16) unsigned short Axs[64 * 72];  // [row][k]
    __shared__ float bs[64];
    for (int i = threadIdx.x; i < 4096; i += 256) {
        int k = i >> 6, nn = i & 63;
        WT[nn * 72 + k] = f2bf(W[i]);
    }
    if (threadIdx.x < 64) bs[threadIdx.x] = B[threadIdx.x];
    const int lane = threadIdx.x & 63, wv = threadIdx.x >> 6;
    const int l15 = lane & 15, quad = lane >> 4;
    const int arow = 16 * wv + l15;
    const int koff = quad * 8;
    for (int base = blockIdx.x * 64; base < nrows; base += gridDim.x * 64) {
        __syncthreads();
        {
            int row = threadIdx.x >> 2, kq = (threadIdx.x & 3) * 16;
            int g = base + row;
            if (INBF) {
                const unsigned short* Xb = (const unsigned short*)Xv;
                uint4 v0 = make_uint4(0,0,0,0), v1 = v0;
                if (g < nrows) {
                    v0 = *(const uint4*)&Xb[(size_t)g * 64 + kq];
                    v1 = *(const uint4*)&Xb[(size_t)g * 64 + kq + 8];
                }
                *(uint4*)&Axs[row * 72 + kq] = v0;
                *(uint4*)&Axs[row * 72 + kq + 8] = v1;
            } else {
                const float* Xf = (const float*)Xv;
                #pragma unroll
                for (int m = 0; m < 4; m++) {
                    float4 v = make_float4(0,0,0,0);
                    if (g < nrows) v = *(const float4*)&Xf[(size_t)g * 64 + kq + m * 4];
                    *(ushort4*)&Axs[row * 72 + kq + m * 4] = pack4(v);
                }
            }
        }
        __syncthreads();
        f4v acc[4];
        #pragma unroll
        for (int t = 0; t < 4; t++) acc[t] = (f4v){0.f,0.f,0.f,0.f};
        s8v a0 = *(const s8v*)&Axs[arow * 72 + koff];
        s8v a1 = *(const s8v*)&Axs[arow * 72 + 32 + koff];
        #pragma unroll
        for (int t = 0; t < 4; t++) {
            int nn = t * 16 + l15;
            s8v b0 = *(const s8v*)&WT[nn * 72 + koff];
            s8v b1 = *(const s8v*)&WT[nn * 72 + 32 + koff];
            acc[t] = __builtin_amdgcn_mfma_f32_16x16x32_bf16(a0, b0, acc[t], 0, 0, 0);
            acc[t] = __builtin_amdgcn_mfma_f32_16x16x32_bf16(a1, b1, acc[t], 0, 0, 0);
        }
        const int mrow = 16 * wv + quad * 4;
        #pragma unroll
        for (int t = 0; t < 4; t++) {
            int col = t * 16 + l15;
            float b = bs[col];
            #pragma unroll
            for (int r = 0; r < 4; r++) {
                int g = base + mrow + r;
                if (g < nrows) {
                    float a = acc[t][r] + b;
                    if (ACT == 1) a = lrelu_(a);
                    else if (ACT == 2) a = fmaxf(a, 0.f);
                    if (OUTBF) ((unsigned short*)Yv)[(size_t)g * 64 + col] = f2bf(a);
                    else       ((float*)Yv)[(size_t)g * 64 + col] = a;
                }
            }
        }
    }
}

// ====== MFMA triple-GEMM combine ======
__global__ __launch_bounds__(256) void mfma_combine_kernel(const float* __restrict__ h_cf,
                                                           const unsigned short* __restrict__ nfb,
                                                           const unsigned short* __restrict__ ngb,
                                                           const float* __restrict__ Wc, const float* __restrict__ cB,
                                                           const float* __restrict__ sW, const float* __restrict__ nW,
                                                           const float* __restrict__ sB,
                                                           unsigned short* __restrict__ outb, int n)
{
    __shared__ __align__(16) unsigned short WcT[64 * 72], WsT[64 * 72], WnT[64 * 72];
    __shared__ __align__(16) unsigned short Ac[32 * 72], As[32 * 72], An[32 * 72];
    __shared__ float bc[64], bsg[64];
    for (int i = threadIdx.x; i < 4096; i += 256) {
        int k = i >> 6, nn = i & 63;
        WcT[nn * 72 + k] = f2bf(Wc[i]);
        WsT[nn * 72 + k] = f2bf(sW[i]);
        WnT[nn * 72 + k] = f2bf(nW[i]);
    }
    if (threadIdx.x < 64) { bc[threadIdx.x] = cB[threadIdx.x]; bsg[threadIdx.x] = sB[threadIdx.x]; }
    const int lane = threadIdx.x & 63, wv = threadIdx.x >> 6;
    const int l15 = lane & 15, quad = lane >> 4;
    const int arow = (wv & 1) * 16 + l15;
    const int ct0 = (wv >> 1) * 2;
    const int koff = quad * 8;
    for (int base = blockIdx.x * 32; base < n; base += gridDim.x * 32) {
        __syncthreads();
        {
            int row = threadIdx.x >> 3, kq = (threadIdx.x & 7) * 8;
            int g = base + row;
            float4 c0v = make_float4(0,0,0,0), c1 = c0v;
            uint4 vf = make_uint4(0,0,0,0), vg = vf;
            if (g < n) {
                const float* pc = &h_cf[(size_t)g * 64 + kq];
                c0v = *(const float4*)pc; c1 = *(const float4*)(pc + 4);
                vf = *(const uint4*)&nfb[(size_t)g * 64 + kq];
                vg = *(const uint4*)&ngb[(size_t)g * 64 + kq];
            }
            *(ushort4*)&Ac[row * 72 + kq] = pack4(c0v);
            *(ushort4*)&Ac[row * 72 + kq + 4] = pack4(c1);
            *(uint4*)&As[row * 72 + kq] = vf;
            *(uint4*)&An[row * 72 + kq] = vg;
        }
        __syncthreads();
        f4v accC[2], accS[2];
        #pragma unroll
        for (int t = 0; t < 2; t++) { accC[t] = (f4v){0.f,0.f,0.f,0.f}; accS[t] = (f4v){0.f,0.f,0.f,0.f}; }
        s8v ac0 = *(const s8v*)&Ac[arow * 72 + koff];
        s8v ac1 = *(const s8v*)&Ac[arow * 72 + 32 + koff];
        s8v as0 = *(const s8v*)&As[arow * 72 + koff];
        s8v as1 = *(const s8v*)&As[arow * 72 + 32 + koff];
        s8v an0 = *(const s8v*)&An[arow * 72 + koff];
        s8v an1 = *(const s8v*)&An[arow * 72 + 32 + koff];
        #pragma unroll
        for (int t = 0; t < 2; t++) {
            int nn = (ct0 + t) * 16 + l15;
            s8v wc0 = *(const s8v*)&WcT[nn * 72 + koff];
            s8v wc1 = *(const s8v*)&WcT[nn * 72 + 32 + koff];
            accC[t] = __builtin_amdgcn_mfma_f32_16x16x32_bf16(ac0, wc0, accC[t], 0, 0, 0);
            accC[t] = __builtin_amdgcn_mfma_f32_16x16x32_bf16(ac1, wc1, accC[t], 0, 0, 0);
            s8v ws0 = *(const s8v*)&WsT[nn * 72 + koff];
            s8v ws1 = *(const s8v*)&WsT[nn * 72 + 32 + koff];
            accS[t] = __builtin_amdgcn_mfma_f32_16x16x32_bf16(as0, ws0, accS[t], 0, 0, 0);
            accS[t] = __builtin_amdgcn_mfma_f32_16x16x32_bf16(as1, ws1, accS[t], 0, 0, 0);
            s8v wn0 = *(const s8v*)&WnT[nn * 72 + koff];
            s8v wn1 = *(const s8v*)&WnT[nn * 72 + 32 + koff];
            accS[t] = __builtin_amdgcn_mfma_f32_16x16x32_bf16(an0, wn0, accS[t], 0, 0, 0);
            accS[t] = __builtin_amdgcn_mfma_f32_16x16x32_bf16(an1, wn1, accS[t], 0, 0, 0);
        }
        const int mrow = (wv & 1) * 16 + quad * 4;
        #pragma unroll
        for (int t = 0; t < 2; t++) {
            int col = (ct0 + t) * 16 + l15;
            float bcv = bc[col], bsv = bsg[col];
            #pragma unroll
            for (int r = 0; r < 4; r++) {
                int g = base + mrow + r;
                if (g < n)
                    outb[(size_t)g * 64 + col] = f2bf(lrelu_(fmaxf(ssp_(accC[t][r] + bcv), accS[t][r] + bsv)));
            }
        }
    }
}

// ---------------- small scalar GEMV (pin encoder, C=16) ----------------
template<int K, int C, int ACT>
__global__ __launch_bounds__(256) void lin_kernel(const float* __restrict__ X,
                                                  const float* __restrict__ W,
                                                  const float* __restrict__ B,
                                                  float* __restrict__ Y, int nrows)
{
    constexpr int ROWS = 256 / C;
    __shared__ float Ws[K * C];
    __shared__ float bs[C];
    __shared__ float Xs[ROWS * K];
    for (int i = threadIdx.x; i < K * C; i += 256) Ws[i] = W[i];
    if (threadIdx.x < C) bs[threadIdx.x] = B[threadIdx.x];
    __syncthreads();
    const int r = threadIdx.x / C, c = threadIdx.x % C;
    for (int base = blockIdx.x * ROWS; base < nrows; base += gridDim.x * ROWS) {
        __syncthreads();
        for (int i = threadIdx.x; i < ROWS * K; i += 256) {
            int rr = base + i / K;
            Xs[i] = (rr < nrows) ? X[(size_t)rr * K + i % K] : 0.f;
        }
        __syncthreads();
        int row = base + r;
        if (row < nrows) {
            float acc = bs[c];
            #pragma unroll
            for (int k = 0; k < K; k++) acc += Xs[r * K + k] * Ws[k * C + c];
            if (ACT == 1) acc = lrelu_(acc);
            else if (ACT == 2) acc = fmaxf(acc, 0.f);
            Y[(size_t)row * C + c] = acc;
        }
    }
}

// ---------------- degrees (for pins norms) ----------------
__global__ __launch_bounds__(256) void deg_kernel(const int* __restrict__ src, const int* __restrict__ dst,
                                                  int* __restrict__ degs, int* __restrict__ degd, int np)
{
    int p = blockIdx.x * 256 + threadIdx.x;
    if (p < np) { atomicAdd(&degs[src[p]], 1); atomicAdd(&degd[dst[p]], 1); }
}

__global__ __launch_bounds__(256) void norm_kernel(int* __restrict__ arr, int n)
{
    int i = blockIdx.x * 256 + threadIdx.x;
    if (i < n) {
        int v = arr[i]; if (v < 1) v = 1;
        arr[i] = __float_as_int(rsqrtf((float)v));
    }
}

// ================= CSR build (generic, keyed by given index array) =================
__global__ __launch_bounds__(256) void csr_count_kernel(const int* __restrict__ key, int* __restrict__ cnt, int ne)
{
    int e = blockIdx.x * 256 + threadIdx.x;
    if (e < ne) atomicAdd(&cnt[key[e]], 1);
}

__global__ __launch_bounds__(256) void scan_block_sum_kernel(const int* __restrict__ cnt, int* __restrict__ bsum, int n)
{
    __shared__ int sh[256];
    int i = blockIdx.x * 256 + threadIdx.x;
    sh[threadIdx.x] = (i < n) ? cnt[i] : 0;
    __syncthreads();
    for (int s = 128; s > 0; s >>= 1) {
        if (threadIdx.x < s) sh[threadIdx.x] += sh[threadIdx.x + s];
        __syncthreads();
    }
    if (threadIdx.x == 0) bsum[blockIdx.x] = sh[0];
}

// parallel single-block exclusive scan of up to 512 block sums
__global__ __launch_bounds__(512) void scan_bsum_kernel(int* __restrict__ bsum, int nb, int* __restrict__ total_out)
{
    __shared__ int sh[512];
    int i = threadIdx.x;
    int v = (i < nb) ? bsum[i] : 0;
    sh[i] = v;
    __syncthreads();
    for (int s = 1; s < 512; s <<= 1) {
        int add = (i >= s) ? sh[i - s] : 0;
        __syncthreads();
        sh[i] += add;
        __syncthreads();
    }
    if (i < nb) bsum[i] = sh[i] - v;     // exclusive
    if (i == nb - 1) *total_out = sh[i];
}

__global__ __launch_bounds__(256) void scan_final_kernel(const int* __restrict__ cnt, const int* __restrict__ bsum,
                                                         int* __restrict__ row_start, int* __restrict__ nxt, int n)
{
    __shared__ int sh[256];
    int i = blockIdx.x * 256 + threadIdx.x;
    int v = (i < n) ? cnt[i] : 0;
    sh[threadIdx.x] = v;
    __syncthreads();
    for (int s = 1; s < 256; s <<= 1) {
        int add = (threadIdx.x >= s) ? sh[threadIdx.x - s] : 0;
        __syncthreads();
        sh[threadIdx.x] += add;
        __syncthreads();
    }
    if (i < n) {
        int excl = sh[threadIdx.x] - v + bsum[blockIdx.x];
        row_start[i] = excl;
        nxt[i] = excl;
    }
}

__global__ __launch_bounds__(256) void csr_fill_kernel(const int* __restrict__ key, int* __restrict__ nxt,
                                                       int* __restrict__ eidx, int ne)
{
    int e = blockIdx.x * 256 + threadIdx.x;
    if (e < ne) {
        int slot = atomicAdd(&nxt[key[e]], 1);
        eidx[slot] = e;
    }
}

// ---------------- edge weights for all 3 layers ----------------
__global__ __launch_bounds__(256) void edge_ew_kernel(const float* __restrict__ in_edge,
                                                      const float* __restrict__ elW, const float* __restrict__ elb,
                                                      const float* __restrict__ gW, const float* __restrict__ gb,
                                                      float* __restrict__ ew3, int ne)
{
    __shared__ float W[32], B[8], G[24], Gb[3];
    if (threadIdx.x < 32) W[threadIdx.x] = elW[threadIdx.x];
    if (threadIdx.x < 8)  B[threadIdx.x] = elb[threadIdx.x];
    if (threadIdx.x < 24) G[threadIdx.x] = gW[threadIdx.x];
    if (threadIdx.x < 3)  Gb[threadIdx.x] = gb[threadIdx.x];
    __syncthreads();
    for (int e = blockIdx.x * 256 + threadIdx.x; e < ne; e += gridDim.x * 256) {
        float4 x = *(const float4*)&in_edge[(size_t)e * 4];
        float ef[8];
        #pragma unroll
        for (int j = 0; j < 8; j++)
            ef[j] = lrelu_(B[j] + x.x * W[j] + x.y * W[8 + j] + x.z * W[16 + j] + x.w * W[24 + j]);
        #pragma unroll
        for (int i = 0; i < 3; i++) {
            float a = Gb[i];
            #pragma unroll
            for (int j = 0; j < 8; j++) a += ef[j] * G[i * 8 + j];
            ew3[(size_t)i * ne + e] = sigm_(a);
        }
    }
}

// ---------------- pins GraphConv gather (lane-parallel metadata preload + unroll-4) -------------
__global__ __launch_bounds__(256) void pins_gather_kernel(const unsigned short* __restrict__ nfb,
                                                          const float* __restrict__ snorm,
                                                          const float* __restrict__ dnorm,
                                                          const int* __restrict__ psrc,
                                                          const int* __restrict__ prow,
                                                          const int* __restrict__ peidx,
                                                          unsigned short* __restrict__ aggb, int nt)
{
    __shared__ int sS[4][64];
    __shared__ float sN[4][64];
    const int lane = threadIdx.x & 63, wv = threadIdx.x >> 6;
    for (int d = blockIdx.x * 4 + wv; d < nt; d += gridDim.x * 4) {
        int rs = prow[d], re = prow[d + 1];
        float acc = 0.f;
        for (int cbase = rs; cbase < re; cbase += 64) {
            int cnt = re - cbase; if (cnt > 64) cnt = 64;
            if (lane < cnt) {
                int p = peidx[cbase + lane];
                int s = psrc[p];
                sS[wv][lane] = s;
                sN[wv][lane] = snorm[s];
            }
            int k = 0;
            for (; k + 3 < cnt; k += 4) {
                int s0 = sS[wv][k], s1 = sS[wv][k+1], s2 = sS[wv][k+2], s3 = sS[wv][k+3];
                float n0 = sN[wv][k], n1 = sN[wv][k+1], n2 = sN[wv][k+2], n3 = sN[wv][k+3];
                float v0 = bf2f(nfb[(size_t)s0 * 64 + lane]) * n0;
                float v1 = bf2f(nfb[(size_t)s1 * 64 + lane]) * n1;
                float v2 = bf2f(nfb[(size_t)s2 * 64 + lane]) * n2;
                float v3 = bf2f(nfb[(size_t)s3 * 64 + lane]) * n3;
                acc += (v0 + v1) + (v2 + v3);
            }
            for (; k < cnt; k++)
                acc += bf2f(nfb[(size_t)sS[wv][k] * 64 + lane]) * sN[wv][k];
        }
        aggb[(size_t)d * 64 + lane] = f2bf(acc * dnorm[d]);
    }
}

// ---------------- CFConv fused: GEMM1 VALU + GEMM2 bf16-MFMA + dense wave scatter ----------------
__global__ __launch_bounds__(256) void cf_pin5_kernel(const float* __restrict__ pinf,
                                                      const unsigned short* __restrict__ hvb,
                                                      const int* __restrict__ psrc, const int* __restrict__ pdst,
                                                      const float* __restrict__ W1, const float* __restrict__ B1,
                                                      const float* __restrict__ W2, const float* __restrict__ B2,
                                                      float* __restrict__ h_cf, int np)
{
    __shared__ float Ws1[16 * 64], bs1[64], bs2[64];
    __shared__ __align__(16) unsigned short W2T[64 * 72];
    __shared__ __align__(16) unsigned short T1s[64 * 72];
    __shared__ float PF[64 * 20];
    __shared__ int srcS[64], dstS[64];
    for (int i = threadIdx.x; i < 16 * 64; i += 256) Ws1[i] = W1[i];
    for (int i = threadIdx.x; i < 64 * 64; i += 256) {
        int k = i >> 6, n = i & 63;
        W2T[n * 72 + k] = f2bf(W2[i]);
    }
    if (threadIdx.x < 64) { bs1[threadIdx.x] = B1[threadIdx.x]; bs2[threadIdx.x] = B2[threadIdx.x]; }
    const int tr = threadIdx.x >> 4, tc = threadIdx.x & 15;
    const int r0 = tr * 4, c0 = tc * 4;
    const int lane = threadIdx.x & 63, wv = threadIdx.x >> 6;
    const int l15 = lane & 15, quad = lane >> 4;
    const int arow = 16 * wv + l15;
    const int koff = quad * 8;
    for (int base = blockIdx.x * 64; base < np; base += gridDim.x * 64) {
        __syncthreads();
        {
            int row = threadIdx.x >> 2, kq = (threadIdx.x & 3) * 4;
            int p = base + row;
            float4 v = make_float4(0.f, 0.f, 0.f, 0.f);
            if (p < np) v = *(const float4*)&pinf[(size_t)p * 16 + kq];
            *(float4*)&PF[row * 20 + kq] = v;
            if (threadIdx.x < 64) {
                int pp = base + threadIdx.x;
                srcS[threadIdx.x] = (pp < np) ? psrc[pp] : 0;
                dstS[threadIdx.x] = (pp < np) ? pdst[pp] : 0;
            }
        }
        __syncthreads();
        // GEMM1 (VALU, K=16): T1 = ssp(PF @ W1 + b1) -> bf16 LDS rows
        {
            float acc[4][4];
            #pragma unroll
            for (int i = 0; i < 4; i++)
                #pragma unroll
                for (int j = 0; j < 4; j++) acc[i][j] = bs1[c0 + j];
            #pragma unroll
            for (int kq = 0; kq < 16; kq += 4) {
                float4 xa[4], wa[4];
                #pragma unroll
                for (int i = 0; i < 4; i++) xa[i] = *(const float4*)&PF[(r0 + i) * 20 + kq];
                #pragma unroll
                for (int j = 0; j < 4; j++) wa[j] = *(const float4*)&Ws1[(kq + j) * 64 + c0];
                fma44(acc, xa, wa);
            }
            #pragma unroll
            for (int i = 0; i < 4; i++) {
                ushort4 o;
                o.x = f2bf(ssp_(acc[i][0]));
                o.y = f2bf(ssp_(acc[i][1]));
                o.z = f2bf(ssp_(acc[i][2]));
                o.w = f2bf(ssp_(acc[i][3]));
                *(ushort4*)&T1s[(r0 + i) * 72 + c0] = o;
            }
        }
        __syncthreads();
        // GEMM2 (MFMA bf16): HE = ssp(T1 @ W2 + b2)
        {
            f4v acc4[4];
            #pragma unroll
            for (int t = 0; t < 4; t++) acc4[t] = (f4v){0.f, 0.f, 0.f, 0.f};
            s8v a0 = *(const s8v*)&T1s[arow * 72 + koff];
            s8v a1 = *(const s8v*)&T1s[arow * 72 + 32 + koff];
            #pragma unroll
            for (int t = 0; t < 4; t++) {
                int n = t * 16 + l15;
                s8v b0 = *(const s8v*)&W2T[n * 72 + koff];
                s8v b1 = *(const s8v*)&W2T[n * 72 + 32 + koff];
                acc4[t] = __builtin_amdgcn_mfma_f32_16x16x32_bf16(a0, b0, acc4[t], 0, 0, 0);
                acc4[t] = __builtin_amdgcn_mfma_f32_16x16x32_bf16(a1, b1, acc4[t], 0, 0, 0);
            }
            __syncthreads();
            const int mrow = 16 * wv + quad * 4;
            #pragma unroll
            for (int t = 0; t < 4; t++) {
                int col = t * 16 + l15;
                float b = bs2[col];
                #pragma unroll
                for (int r = 0; r < 4; r++)
                    T1s[(mrow + r) * 72 + col] = f2bf(ssp_(acc4[t][r] + b));
            }
        }
        __syncthreads();
        // scatter: one wave per pin-row; 64 lanes = 64 contiguous channels
        #pragma unroll 4
        for (int i = 0; i < 16; i++) {
            int pl = wv * 16 + i;
            int p = base + pl;
            if (p < np) {
                float m = bf2f(hvb[(size_t)dstS[pl] * 64 + lane]) * bf2f(T1s[pl * 72 + lane]);
                unsafeAtomicAdd(&h_cf[(size_t)srcS[pl] * 64 + lane], m);
            }
        }
    }
}

// ---------------- SAGE gather-max (lane-parallel metadata preload + unroll-4) ----------------
__global__ __launch_bounds__(256) void sage_gather_kernel(const unsigned short* __restrict__ hpb,
                                                          const float* __restrict__ ew,
                                                          const int* __restrict__ esrc,
                                                          const int* __restrict__ row_start,
                                                          const int* __restrict__ eidx,
                                                          unsigned short* __restrict__ ngb, int nn)
{
    __shared__ int sS[4][64];
    __shared__ float sWt[4][64];
    const int lane = threadIdx.x & 63, wv = threadIdx.x >> 6;
    for (int d = blockIdx.x * 4 + wv; d < nn; d += gridDim.x * 4) {
        int rs = row_start[d], re = row_start[d + 1];
        float acc = 0.f;
        for (int cbase = rs; cbase < re; cbase += 64) {
            int cnt = re - cbase; if (cnt > 64) cnt = 64;
            if (lane < cnt) {
                int e = eidx[cbase + lane];
                sS[wv][lane] = esrc[e];
                sWt[wv][lane] = ew[e];
            }
            int k = 0;
            for (; k + 3 < cnt; k += 4) {
                int s0 = sS[wv][k], s1 = sS[wv][k+1], s2 = sS[wv][k+2], s3 = sS[wv][k+3];
                float w0 = sWt[wv][k], w1 = sWt[wv][k+1], w2 = sWt[wv][k+2], w3 = sWt[wv][k+3];
                float v0 = bf2f(hpb[(size_t)s0 * 64 + lane]) * w0;
                float v1 = bf2f(hpb[(size_t)s1 * 64 + lane]) * w1;
                float v2 = bf2f(hpb[(size_t)s2 * 64 + lane]) * w2;
                float v3 = bf2f(hpb[(size_t)s3 * 64 + lane]) * w3;
                acc = fmaxf(acc, fmaxf(fmaxf(v0, v1), fmaxf(v2, v3)));
            }
            for (; k < cnt; k++)
                acc = fmaxf(acc, bf2f(hpb[(size_t)sS[wv][k] * 64 + lane]) * sWt[wv][k]);
        }
        ngb[(size_t)d * 64 + lane] = f2bf(acc);
    }
}

// ---------------- node head (32 rows/iter, grid-stride, 3-stage MLP; nf is bf16) ----------------
__global__ __launch_bounds__(256) void node_head3_kernel(const float* __restrict__ in_node,
                                                         const unsigned short* __restrict__ nfb,
                                                         const float* __restrict__ W1, const float* __restrict__ B1,
                                                         const float* __restrict__ W2, const float* __restrict__ B2,
                                                         const float* __restrict__ W3, const float* __restrict__ B3,
                                                         float* __restrict__ out, int n)
{
    __shared__ float Ws1[80 * 64], Ws2[64 * 64], Ws3[64 * 4];
    __shared__ float bs1[64], bs2[64], bs3[4];
    __shared__ float Xs[32 * 84];       // reused as H2 (stride 68)
    __shared__ float H1[32 * 68];
    for (int i = threadIdx.x; i < 80 * 64; i += 256) Ws1[i] = W1[i];
    for (int i = threadIdx.x; i < 64 * 64; i += 256) Ws2[i] = W2[i];
    for (int i = threadIdx.x; i < 64 * 4; i += 256) Ws3[i] = W3[i];
    if (threadIdx.x < 64) { bs1[threadIdx.x] = B1[threadIdx.x]; bs2[threadIdx.x] = B2[threadIdx.x]; }
    if (threadIdx.x < 4) bs3[threadIdx.x] = B3[threadIdx.x];
    const int tr = threadIdx.x >> 4, tc = threadIdx.x & 15;
    const int r0 = tr * 2, c0 = tc * 4;
    for (int base = blockIdx.x * 32; base < n; base += gridDim.x * 32) {
        __syncthreads();
        for (int i = threadIdx.x; i < 32 * 4; i += 256) {
            int row = i >> 2, kq = (i & 3) * 4;
            int g = base + row;
            float4 v = make_float4(0,0,0,0);
            if (g < n) v = *(const float4*)&in_node[(size_t)g * 16 + kq];
            *(float4*)&Xs[row * 84 + kq] = v;
        }
        for (int i = threadIdx.x; i < 32 * 16; i += 256) {
            int row = i >> 4, kq = (i & 15) * 4;
            int g = base + row;
            float4 v = make_float4(0,0,0,0);
            if (g < n) {
                ushort4 u = *(const ushort4*)&nfb[(size_t)g * 64 + kq];
                v.x = bf2f(u.x); v.y = bf2f(u.y); v.z = bf2f(u.z); v.w = bf2f(u.w);
            }
            *(float4*)&Xs[row * 84 + 16 + kq] = v;
        }
        __syncthreads();
        {
            float acc[2][4];
            #pragma unroll
            for (int i = 0; i < 2; i++)
                #pragma unroll
                for (int j = 0; j < 4; j++) acc[i][j] = bs1[c0 + j];
            #pragma unroll 4
            for (int kq = 0; kq < 80; kq += 4) {
                float4 xa[2], wa[4];
                #pragma unroll
                for (int i = 0; i < 2; i++) xa[i] = *(const float4*)&Xs[(r0 + i) * 84 + kq];
                #pragma unroll
                for (int j = 0; j < 4; j++) wa[j] = *(const float4*)&Ws1[(kq + j) * 64 + c0];
                #pragma unroll
                for (int kk = 0; kk < 4; kk++)
                    #pragma unroll
                    for (int i = 0; i < 2; i++) {
                        float x = ((const float*)&xa[i])[kk];
                        #pragma unroll
                        for (int j = 0; j < 4; j++) acc[i][j] += x * ((const float*)&wa[kk])[j];
                    }
            }
            #pragma unroll
            for (int i = 0; i < 2; i++) {
                float4 o; float* op = (float*)&o;
                #pragma unroll
                for (int j = 0; j < 4; j++) op[j] = lrelu_(acc[i][j]);
                *(float4*)&H1[(r0 + i) * 68 + c0] = o;
            }
        }
        __syncthreads();
        float* H2 = Xs;
        {
            float acc[2][4];
            #pragma unroll
            for (int i = 0; i < 2; i++)
                #pragma unroll
                for (int j = 0; j < 4; j++) acc[i][j] = bs2[c0 + j];
            #pragma unroll 4
            for (int kq = 0; kq < 64; kq += 4) {
                float4 xa[2], wa[4];
                #pragma unroll
                for (int i = 0; i < 2; i++) xa[i] = *(const float4*)&H1[(r0 + i) * 68 + kq];
                #pragma unroll
                for (int j = 0; j < 4; j++) wa[j] = *(const float4*)&Ws2[(kq + j) * 64 + c0];
                #pragma unroll
                for (int kk = 0; kk < 4; kk++)
                    #pragma unroll
                    for (int i = 0; i < 2; i++) {
                        float x = ((const float*)&xa[i])[kk];
                        #pragma unroll
                        for (int j = 0; j < 4; j++) acc[i][j] += x * ((const float*)&wa[kk])[j];
                    }
            }
            __syncthreads();
            #pragma unroll
            for (int i = 0; i < 2; i++) {
                float4 o; float* op = (float*)&o;
                #pragma unroll
                for (int j = 0; j < 4; j++) op[j] = lrelu_(acc[i][j]);
                *(float4*)&H2[(r0 + i) * 68 + c0] = o;
            }
        }
        __syncthreads();
        if (threadIdx.x < 128) {
            int row = threadIdx.x >> 2, c = threadIdx.x & 3;
            float acc = bs3[c];
            #pragma unroll 4
            for (int kq = 0; kq < 64; kq += 4) {
                float4 h = *(const float4*)&H2[row * 68 + kq];
                #pragma unroll
                for (int j = 0; j < 4; j++) acc += ((const float*)&h)[j] * Ws3[(kq + j) * 4 + c];
            }
            int g = base + row;
            if (g < n) out[(size_t)g * 4 + c] = sigm_(acc);
        }
    }
}

// ---------------- net head (32 rows/iter, grid-stride, C_out=1; tf fp32) ----------------
__global__ __launch_bounds__(256) void net_head3_kernel(const float* __restrict__ in_net, const float* __restrict__ tf,
                                                        const float* __restrict__ W1, const float* __restrict__ B1,
                                                        const float* __restrict__ W2, const float* __restrict__ B2,
                                                        const float* __restrict__ W3, const float* __restrict__ B3,
                                                        float* __restrict__ out, int n)
{
    __shared__ float Ws1[72 * 64], Ws2[64 * 64], Ws3[64];
    __shared__ float bs1[64], bs2[64], bs3[1];
    __shared__ float Xs[32 * 76];       // reused as H2 (stride 68)
    __shared__ float H1[32 * 68];
    for (int i = threadIdx.x; i < 72 * 64; i += 256) Ws1[i] = W1[i];
    for (int i = threadIdx.x; i < 64 * 64; i += 256) Ws2[i] = W2[i];
    if (threadIdx.x < 64) { Ws3[threadIdx.x] = W3[threadIdx.x]; bs1[threadIdx.x] = B1[threadIdx.x]; bs2[threadIdx.x] = B2[threadIdx.x]; }
    if (threadIdx.x == 0) bs3[0] = B3[0];
    const int tr = threadIdx.x >> 4, tc = threadIdx.x & 15;
    const int r0 = tr * 2, c0 = tc * 4;
    for (int base = blockIdx.x * 32; base < n; base += gridDim.x * 32) {
        __syncthreads();
        for (int i = threadIdx.x; i < 32 * 2; i += 256) {
            int row = i >> 1, kq = (i & 1) * 4;
            int g = base + row;
            float4 v = make_float4(0,0,0,0);
            if (g < n) v = *(const float4*)&in_net[(size_t)g * 8 + kq];
            *(float4*)&Xs[row * 76 + kq] = v;
        }
        for (int i = threadIdx.x; i < 32 * 16; i += 256) {
            int row = i >> 4, kq = (i & 15) * 4;
            int g = base + row;
            float4 v = make_float4(0,0,0,0);
            if (g < n) v = *(const float4*)&tf[(size_t)g * 64 + kq];
            *(float4*)&Xs[row * 76 + 8 + kq] = v;
        }
        __syncthreads();
        {
            float acc[2][4];
            #pragma unroll
            for (int i = 0; i < 2; i++)
                #pragma unroll
                for (int j = 0; j < 4; j++) acc[i][j] = bs1[c0 + j];
            #pragma unroll 4
            for (int kq = 0; kq < 72; kq += 4) {
                float4 xa[2], wa[4];
                #pragma unroll
                for (int i = 0; i < 2; i++) xa[i] = *(const float4*)&Xs[(r0 + i) * 76 + kq];
                #pragma unroll
                for (int j = 0; j < 4; j++) wa[j] = *(const float4*)&Ws1[(kq + j) * 64 + c0];
                #pragma unroll
                for (int kk = 0; kk < 4; kk++)
                    #pragma unroll
                    for (int i = 0; i < 2; i++) {
                        float x = ((const float*)&xa[i])[kk];
                        #pragma unroll
                        for (int j = 0; j < 4; j++) acc[i][j] += x * ((const float*)&wa[kk])[j];
                    }
            }
            #pragma unroll
            for (int i = 0; i < 2; i++) {
                float4 o; float* op = (float*)&o;
                #pragma unroll
                for (int j = 0; j < 4; j++) op[j] = lrelu_(acc[i][j]);
                *(float4*)&H1[(r0 + i) * 68 + c0] = o;
            }
        }
        __syncthreads();
        float* H2 = Xs;
        {
            float acc[2][4];
            #pragma unroll
            for (int i = 0; i < 2; i++)
                #pragma unroll
                for (int j = 0; j < 4; j++) acc[i][j] = bs2[c0 + j];
            #pragma unroll 4
            for (int kq = 0; kq < 64; kq += 4) {
                float4 xa[2], wa[4];
                #pragma unroll
                for (int i = 0; i < 2; i++) xa[i] = *(const float4*)&H1[(r0 + i) * 68 + kq];
                #pragma unroll
                for (int j = 0; j < 4; j++) wa[j] = *(const float4*)&Ws2[(kq + j) * 64 + c0];
                #pragma unroll
                for (int kk = 0; kk < 4; kk++)
                    #pragma unroll
                    for (int i = 0; i < 2; i++) {
                        float x = ((const float*)&xa[i])[kk];
                        #pragma unroll
                        for (int j = 0; j < 4; j++) acc[i][j] += x * ((const float*)&wa[kk])[j];
                    }
            }
            __syncthreads();
            #pragma unroll
            for (int i = 0; i < 2; i++) {
                float4 o; float* op = (float*)&o;
                #pragma unroll
                for (int j = 0; j < 4; j++) op[j] = lrelu_(acc[i][j]);
                *(float4*)&H2[(r0 + i) * 68 + c0] = o;
            }
        }
        __syncthreads();
        if (threadIdx.x < 32) {
            int row = threadIdx.x;
            float acc = bs3[0];
            #pragma unroll 4
            for (int kq = 0; kq < 64; kq += 4) {
                float4 h = *(const float4*)&H2[row * 68 + kq];
                float4 w = *(const float4*)&Ws3[kq];
                acc += h.x * w.x + h.y * w.y + h.z * w.z + h.w * w.w;
            }
            int g = base + row;
            if (g < n) out[g] = sigm_(acc);
        }
    }
}

extern "C" void kernel_launch(void* const* d_in, const int* in_sizes, int n_in,
                              void* d_out, int out_size, void* d_ws, size_t ws_size,
                              hipStream_t stream)
{
    (void)in_sizes; (void)n_in; (void)out_size; (void)ws_size;
    constexpr int Nn = 100000, Nt = 30000, Np = 400000, Ne = 1000000;
    constexpr int H = 64, L = 3, T = 4;

    auto fpt = [&](int i){ return (const float*)d_in[i]; };
    auto ipt = [&](int i){ return (const int*)d_in[i]; };

    const float* in_node = fpt(0);
    const float* in_net  = fpt(1);
    const float* in_pin  = fpt(2);
    const float* in_edge = fpt(3);
    const int* psrc = ipt(4);
    const int* pdst = ipt(5);
    const int* esrc = ipt(6);
    const int* edst = ipt(7);

    float* ws = (float*)d_ws;
    size_t o = 0;
    auto alloc = [&](size_t nel){ float* p = ws + o; o += nel; return p; };
    unsigned short* node_a = (unsigned short*)alloc((size_t)Nn * 32);
    unsigned short* node_b = (unsigned short*)alloc((size_t)Nn * 32);
    unsigned short* aggb   = (unsigned short*)alloc((size_t)Nt * 32);
    unsigned short* hvb    = (unsigned short*)alloc((size_t)Nt * 32);
    unsigned short* hpb    = (unsigned short*)alloc((size_t)Nn * 32);
    unsigned short* ngb    = (unsigned short*)alloc((size_t)Nn * 32);
    float* net_a  = alloc((size_t)Nt * H);
    float* net_b  = alloc((size_t)Nt * H);
    float* pinf   = alloc((size_t)Np * 16);
    float* h_cf   = alloc((size_t)Nn * H);
    float* ew3    = alloc((size_t)3 * Ne);
    float* snorm  = alloc((size_t)Nn);
    float* dnorm  = alloc((size_t)Nt);
    int* cnt       = (int*)alloc((size_t)Nn);
    int* row_start = (int*)alloc((size_t)Nn + 1);
    int* nxt       = (int*)alloc((size_t)Nn);
    int* eidx      = (int*)alloc((size_t)Ne);
    int* bsum      = (int*)alloc((size_t)512);
    int* pcnt      = (int*)alloc((size_t)Nt);
    int* prow      = (int*)alloc((size_t)Nt + 1);
    int* pnxt      = (int*)alloc((size_t)Nt);
    int* peidx     = (int*)alloc((size_t)Np);
    int* pbsum     = (int*)alloc((size_t)256);

    constexpr int NB  = (Nn + 255) / 256;
    constexpr int NB2 = (Nt + 255) / 256;

    // degree norms for pins
    hipMemsetAsync(snorm, 0, (size_t)Nn * 4, stream);
    hipMemsetAsync(dnorm, 0, (size_t)Nt * 4, stream);
    deg_kernel<<<(Np + 255) / 256, 256, 0, stream>>>(psrc, pdst, (int*)snorm, (int*)dnorm, Np);
    norm_kernel<<<(Nn + 255) / 256, 256, 0, stream>>>((int*)snorm, Nn);
    norm_kernel<<<(Nt + 255) / 256, 256, 0, stream>>>((int*)dnorm, Nt);

    // build dst-CSR for 'near' (edst -> Nn rows)
    hipMemsetAsync(cnt, 0, (size_t)Nn * 4, stream);
    csr_count_kernel<<<(Ne + 255) / 256, 256, 0, stream>>>(edst, cnt, Ne);
    scan_block_sum_kernel<<<NB, 256, 0, stream>>>(cnt, bsum, Nn);
    scan_bsum_kernel<<<1, 512, 0, stream>>>(bsum, NB, row_start + Nn);
    scan_final_kernel<<<NB, 256, 0, stream>>>(cnt, bsum, row_start, nxt, Nn);
    csr_fill_kernel<<<(Ne + 255) / 256, 256, 0, stream>>>(edst, nxt, eidx, Ne);

    // build dst-CSR for 'pins' (pdst -> Nt rows)
    hipMemsetAsync(pcnt, 0, (size_t)Nt * 4, stream);
    csr_count_kernel<<<(Np + 255) / 256, 256, 0, stream>>>(pdst, pcnt, Np);
    scan_block_sum_kernel<<<NB2, 256, 0, stream>>>(pcnt, pbsum, Nt);
    scan_bsum_kernel<<<1, 512, 0, stream>>>(pbsum, NB2, prow + Nt);
    scan_final_kernel<<<NB2, 256, 0, stream>>>(pcnt, pbsum, prow, pnxt, Nt);
    csr_fill_kernel<<<(Np + 255) / 256, 256, 0, stream>>>(pdst, pnxt, peidx, Np);

    // input encoders
    gemm64_kernel<16, 1, true><<<1024, 256, 0, stream>>>(in_node, fpt(8),  fpt(9),  node_a, Nn);
    gemm64_kernel< 8, 1, false><<<469, 256, 0, stream>>>(in_net,  fpt(10), fpt(11), net_a,  Nt);
    lin_kernel<8, 16, 1><<<1024, 256, 0, stream>>>(in_pin, fpt(12), fpt(13), pinf, Np);
    edge_ew_kernel<<<2048, 256, 0, stream>>>(in_edge, fpt(14), fpt(15), fpt(16), fpt(17), ew3, Ne);

    unsigned short* ncur = node_a; unsigned short* nnew = node_b;
    float* tcur = net_a;  float* tnew = net_b;

    for (int i = 0; i < L; i++) {
        // pins GraphConv (node -> net)
        pins_gather_kernel<<<(Nt + 3) / 4, 256, 0, stream>>>(ncur, snorm, dnorm, psrc, prow, peidx, aggb, Nt);
        mfma_gemm_kernel<1, true, false><<<469, 256, 0, stream>>>(aggb, fpt(18) + (size_t)i * 4096, fpt(19) + (size_t)i * 64, tnew, Nt);

        // CFConv (net -> node)
        mfma_gemm_kernel<0, false, true><<<469, 256, 0, stream>>>(tcur, fpt(20) + (size_t)i * 4096, fpt(21) + (size_t)i * 64, hvb, Nt);
        hipMemsetAsync(h_cf, 0, (size_t)Nn * H * 4, stream);
        cf_pin5_kernel<<<1024, 256, 0, stream>>>(pinf, hvb, psrc, pdst,
                                                 fpt(22) + (size_t)i * 1024, fpt(23) + (size_t)i * 64,
                                                 fpt(24) + (size_t)i * 4096, fpt(25) + (size_t)i * 64,
                                                 h_cf, Np);

        // SAGE (near)
        mfma_gemm_kernel<2, true, true><<<1024, 256, 0, stream>>>(ncur, fpt(28) + (size_t)i * 4096, fpt(29) + (size_t)i * 64, hpb, Nn);
        sage_gather_kernel<<<(Nn + 3) / 4, 256, 0, stream>>>(hpb, ew3 + (size_t)i * Ne, esrc, row_start, eidx, ngb, Nn);

        // combine
        mfma_combine_kernel<<<1024, 256, 0, stream>>>(h_cf, ncur, ngb,
                                                      fpt(26) + (size_t)i * 4096, fpt(27) + (size_t)i * 64,
                                                      fpt(30) + (size_t)i * 4096, fpt(31) + (size_t)i * 4096,
                                                      fpt(32) + (size_t)i * 64,
                                                      nnew, Nn);

        unsigned short* t = ncur; ncur = nnew; nnew = t;
        float* tf = tcur; tcur = tnew; tnew = tf;
    }

    float* out = (float*)d_out;
    node_head3_kernel<<<640, 256, 0, stream>>>(in_node, ncur, fpt(33), fpt(34), fpt(35), fpt(36), fpt(37), fpt(38), out, Nn);
    net_head3_kernel<<<480, 256, 0, stream>>>(in_net, tcur, fpt(39), fpt(40), fpt(41), fpt(42), fpt(43), fpt(44), out + (size_t)Nn * T, Nt);
}

// Round 13
// 1097.700 us; speedup vs baseline: 13.4188x; 1.0389x over previous
//
#include <hip/hip_runtime.h>
#include <hip/hip_bf16.h>

#define DEV __device__ __forceinline__

DEV float lrelu_(float x){ return x > 0.f ? x : 0.01f * x; }
DEV float ssp_(float x){ return fmaxf(x, 0.f) + __logf(1.f + __expf(-fabsf(x))) - 0.69314718055994530942f; }
DEV float sigm_(float x){ return 1.f / (1.f + __expf(-x)); }

DEV unsigned short f2bf(float x){
    unsigned int u = __float_as_uint(x);
    unsigned int r = (u + 0x7FFFu + ((u >> 16) & 1u)) >> 16;
    return (unsigned short)r;
}
DEV float bf2f(unsigned short s){ return __uint_as_float((unsigned int)s << 16); }
DEV ushort4 pack4(float4 v){
    ushort4 u; u.x = f2bf(v.x); u.y = f2bf(v.y); u.z = f2bf(v.z); u.w = f2bf(v.w); return u;
}

DEV void fma44(float (&acc)[4][4], const float4 (&xa)[4], const float4 (&wa)[4])
{
    #pragma unroll
    for (int kk = 0; kk < 4; kk++) {
        #pragma unroll
        for (int i = 0; i < 4; i++) {
            float x = ((const float*)&xa[i])[kk];
            #pragma unroll
            for (int j = 0; j < 4; j++)
                acc[i][j] += x * ((const float*)&wa[kk])[j];
        }
    }
}

typedef short s8v __attribute__((ext_vector_type(8)));
typedef float f4v __attribute__((ext_vector_type(4)));

// ====== generic tiled GEMM (VALU, small K): Y[N x 64] = act(X @ W[K x 64] + b) ======
template<int K, int ACT, bool OUTBF>
__global__ __launch_bounds__(256) void gemm64_kernel(const float* __restrict__ X,
                                                     const float* __restrict__ W,
                                                     const float* __restrict__ B,
                                                     void* __restrict__ Yv, int nrows)
{
    constexpr int XS = K + 4;
    constexpr int KQ = K / 4;
    __shared__ float Ws[K * 64];
    __shared__ float bs[64];
    __shared__ float Xs[64 * XS];
    for (int i = threadIdx.x; i < K * 64; i += 256) Ws[i] = W[i];
    if (threadIdx.x < 64) bs[threadIdx.x] = B[threadIdx.x];
    const int tr = threadIdx.x >> 4, tc = threadIdx.x & 15;
    const int r0 = tr * 4, c0 = tc * 4;
    for (int base = blockIdx.x * 64; base < nrows; base += gridDim.x * 64) {
        __syncthreads();
        for (int i = threadIdx.x; i < 64 * KQ; i += 256) {
            int row = i / KQ, kq = (i % KQ) * 4;
            int g = base + row;
            float4 v = make_float4(0.f, 0.f, 0.f, 0.f);
            if (g < nrows) v = *(const float4*)&X[(size_t)g * K + kq];
            *(float4*)&Xs[row * XS + kq] = v;
        }
        __syncthreads();
        float acc[4][4];
        #pragma unroll
        for (int i = 0; i < 4; i++)
            #pragma unroll
            for (int j = 0; j < 4; j++) acc[i][j] = bs[c0 + j];
        #pragma unroll 4
        for (int kq = 0; kq < K; kq += 4) {
            float4 xa[4], wa[4];
            #pragma unroll
            for (int i = 0; i < 4; i++) xa[i] = *(const float4*)&Xs[(r0 + i) * XS + kq];
            #pragma unroll
            for (int j = 0; j < 4; j++) wa[j] = *(const float4*)&Ws[(kq + j) * 64 + c0];
            fma44(acc, xa, wa);
        }
        #pragma unroll
        for (int i = 0; i < 4; i++) {
            int g = base + r0 + i;
            if (g < nrows) {
                float4 o;
                float* op = (float*)&o;
                #pragma unroll
                for (int j = 0; j < 4; j++) {
                    float a = acc[i][j];
                    if (ACT == 1) a = lrelu_(a);
                    else if (ACT == 2) a = fmaxf(a, 0.f);
                    op[j] = a;
                }
                if (OUTBF) *(ushort4*)&((unsigned short*)Yv)[(size_t)g * 64 + c0] = pack4(o);
                else       *(float4*)&((float*)Yv)[(size_t)g * 64 + c0] = o;
            }
        }
    }
}

// ====== MFMA GEMM: Y = act(X @ W64x64 + b); INBF/OUTBF select bf16 storage ======
template<int ACT, bool INBF, bool OUTBF>
__global__ __launch_bounds__(256) void mfma_gemm_kernel(const void* __restrict__ Xv,
                                                        const float* __restrict__ W,
                                                        const float* __restrict__ B,
                                                        void* __restrict__ Yv, int nrows)
{
    __shared__ __align__(16) unsigned short WT[64 * 72];   // [n][k]
    __shared__ __align__(16) unsigned short Axs[64 * 72];  // [row][k]
    __shared__ float bs[64];
    for (int i = threadIdx.x; i < 4096; i += 256) {
        int k = i >> 6, nn = i & 63;
        WT[nn * 72 + k] = f2bf(W[i]);
    }
    if (threadIdx.x < 64) bs[threadIdx.x] = B[threadIdx.x];
    const int lane = threadIdx.x & 63, wv = threadIdx.x >> 6;
    const int l15 = lane & 15, quad = lane >> 4;
    const int arow = 16 * wv + l15;
    const int koff = quad * 8;
    for (int base = blockIdx.x * 64; base < nrows; base += gridDim.x * 64) {
        __syncthreads();
        {
            int row = threadIdx.x >> 2, kq = (threadIdx.x & 3) * 16;
            int g = base + row;
            if (INBF) {
                const unsigned short* Xb = (const unsigned short*)Xv;
                uint4 v0 = make_uint4(0,0,0,0), v1 = v0;
                if (g < nrows) {
                    v0 = *(const uint4*)&Xb[(size_t)g * 64 + kq];
                    v1 = *(const uint4*)&Xb[(size_t)g * 64 + kq + 8];
                }
                *(uint4*)&Axs[row * 72 + kq] = v0;
                *(uint4*)&Axs[row * 72 + kq + 8] = v1;
            } else {
                const float* Xf = (const float*)Xv;
                #pragma unroll
                for (int m = 0; m < 4; m++) {
                    float4 v = make_float4(0,0,0,0);
                    if (g < nrows) v = *(const float4*)&Xf[(size_t)g * 64 + kq + m * 4];
                    *(ushort4*)&Axs[row * 72 + kq + m * 4] = pack4(v);
                }
            }
        }
        __syncthreads();
        f4v acc[4];
        #pragma unroll
        for (int t = 0; t < 4; t++) acc[t] = (f4v){0.f,0.f,0.f,0.f};
        s8v a0 = *(const s8v*)&Axs[arow * 72 + koff];
        s8v a1 = *(const s8v*)&Axs[arow * 72 + 32 + koff];
        #pragma unroll
        for (int t = 0; t < 4; t++) {
            int nn = t * 16 + l15;
            s8v b0 = *(const s8v*)&WT[nn * 72 + koff];
            s8v b1 = *(const s8v*)&WT[nn * 72 + 32 + koff];
            acc[t] = __builtin_amdgcn_mfma_f32_16x16x32_bf16(a0, b0, acc[t], 0, 0, 0);
            acc[t] = __builtin_amdgcn_mfma_f32_16x16x32_bf16(a1, b1, acc[t], 0, 0, 0);
        }
        const int mrow = 16 * wv + quad * 4;
        #pragma unroll
        for (int t = 0; t < 4; t++) {
            int col = t * 16 + l15;
            float b = bs[col];
            #pragma unroll
            for (int r = 0; r < 4; r++) {
                int g = base + mrow + r;
                if (g < nrows) {
                    float a = acc[t][r] + b;
                    if (ACT == 1) a = lrelu_(a);
                    else if (ACT == 2) a = fmaxf(a, 0.f);
                    if (OUTBF) ((unsigned short*)Yv)[(size_t)g * 64 + col] = f2bf(a);
                    else       ((float*)Yv)[(size_t)g * 64 + col] = a;
                }
            }
        }
    }
}

// ====== MFMA triple-GEMM combine (all inputs bf16) ======
__global__ __launch_bounds__(256) void mfma_combine_kernel(const unsigned short* __restrict__ cfb,
                                                           const unsigned short* __restrict__ nfb,
                                                           const unsigned short* __restrict__ ngb,
                                                           const float* __restrict__ Wc, const float* __restrict__ cB,
                                                           const float* __restrict__ sW, const float* __restrict__ nW,
                                                           const float* __restrict__ sB,
                                                           unsigned short* __restrict__ outb, int n)
{
    __shared__ __align__(16) unsigned short WcT[64 * 72], WsT[64 * 72], WnT[64 * 72];
    __shared__ __align__(16) unsigned short Ac[32 * 72], As[32 * 72], An[32 * 72];
    __shared__ float bc[64], bsg[64];
    for (int i = threadIdx.x; i < 4096; i += 256) {
        int k = i >> 6, nn = i & 63;
        WcT[nn * 72 + k] = f2bf(Wc[i]);
        WsT[nn * 72 + k] = f2bf(sW[i]);
        WnT[nn * 72 + k] = f2bf(nW[i]);
    }
    if (threadIdx.x < 64) { bc[threadIdx.x] = cB[threadIdx.x]; bsg[threadIdx.x] = sB[threadIdx.x]; }
    const int lane = threadIdx.x & 63, wv = threadIdx.x >> 6;
    const int l15 = lane & 15, quad = lane >> 4;
    const int arow = (wv & 1) * 16 + l15;
    const int ct0 = (wv >> 1) * 2;
    const int koff = quad * 8;
    for (int base = blockIdx.x * 32; base < n; base += gridDim.x * 32) {
        __syncthreads();
        {
            int row = threadIdx.x >> 3, kq = (threadIdx.x & 7) * 8;
            int g = base + row;
            uint4 vc = make_uint4(0,0,0,0), vf = vc, vg = vc;
            if (g < n) {
                vc = *(const uint4*)&cfb[(size_t)g * 64 + kq];
                vf = *(const uint4*)&nfb[(size_t)g * 64 + kq];
                vg = *(const uint4*)&ngb[(size_t)g * 64 + kq];
            }
            *(uint4*)&Ac[row * 72 + kq] = vc;
            *(uint4*)&As[row * 72 + kq] = vf;
            *(uint4*)&An[row * 72 + kq] = vg;
        }
        __syncthreads();
        f4v accC[2], accS[2];
        #pragma unroll
        for (int t = 0; t < 2; t++) { accC[t] = (f4v){0.f,0.f,0.f,0.f}; accS[t] = (f4v){0.f,0.f,0.f,0.f}; }
        s8v ac0 = *(const s8v*)&Ac[arow * 72 + koff];
        s8v ac1 = *(const s8v*)&Ac[arow * 72 + 32 + koff];
        s8v as0 = *(const s8v*)&As[arow * 72 + koff];
        s8v as1 = *(const s8v*)&As[arow * 72 + 32 + koff];
        s8v an0 = *(const s8v*)&An[arow * 72 + koff];
        s8v an1 = *(const s8v*)&An[arow * 72 + 32 + koff];
        #pragma unroll
        for (int t = 0; t < 2; t++) {
            int nn = (ct0 + t) * 16 + l15;
            s8v wc0 = *(const s8v*)&WcT[nn * 72 + koff];
            s8v wc1 = *(const s8v*)&WcT[nn * 72 + 32 + koff];
            accC[t] = __builtin_amdgcn_mfma_f32_16x16x32_bf16(ac0, wc0, accC[t], 0, 0, 0);
            accC[t] = __builtin_amdgcn_mfma_f32_16x16x32_bf16(ac1, wc1, accC[t], 0, 0, 0);
            s8v ws0 = *(const s8v*)&WsT[nn * 72 + koff];
            s8v ws1 = *(const s8v*)&WsT[nn * 72 + 32 + koff];
            accS[t] = __builtin_amdgcn_mfma_f32_16x16x32_bf16(as0, ws0, accS[t], 0, 0, 0);
            accS[t] = __builtin_amdgcn_mfma_f32_16x16x32_bf16(as1, ws1, accS[t], 0, 0, 0);
            s8v wn0 = *(const s8v*)&WnT[nn * 72 + koff];
            s8v wn1 = *(const s8v*)&WnT[nn * 72 + 32 + koff];
            accS[t] = __builtin_amdgcn_mfma_f32_16x16x32_bf16(an0, wn0, accS[t], 0, 0, 0);
            accS[t] = __builtin_amdgcn_mfma_f32_16x16x32_bf16(an1, wn1, accS[t], 0, 0, 0);
        }
        const int mrow = (wv & 1) * 16 + quad * 4;
        #pragma unroll
        for (int t = 0; t < 2; t++) {
            int col = (ct0 + t) * 16 + l15;
            float bcv = bc[col], bsv = bsg[col];
            #pragma unroll
            for (int r = 0; r < 4; r++) {
                int g = base + mrow + r;
                if (g < n)
                    outb[(size_t)g * 64 + col] = f2bf(lrelu_(fmaxf(ssp_(accC[t][r] + bcv), accS[t][r] + bsv)));
            }
        }
    }
}

// ---------------- small scalar GEMV (pin encoder, C=16) ----------------
template<int K, int C, int ACT>
__global__ __launch_bounds__(256) void lin_kernel(const float* __restrict__ X,
                                                  const float* __restrict__ W,
                                                  const float* __restrict__ B,
                                                  float* __restrict__ Y, int nrows)
{
    constexpr int ROWS = 256 / C;
    __shared__ float Ws[K * C];
    __shared__ float bs[C];
    __shared__ float Xs[ROWS * K];
    for (int i = threadIdx.x; i < K * C; i += 256) Ws[i] = W[i];
    if (threadIdx.x < C) bs[threadIdx.x] = B[threadIdx.x];
    __syncthreads();
    const int r = threadIdx.x / C, c = threadIdx.x % C;
    for (int base = blockIdx.x * ROWS; base < nrows; base += gridDim.x * ROWS) {
        __syncthreads();
        for (int i = threadIdx.x; i < ROWS * K; i += 256) {
            int rr = base + i / K;
            Xs[i] = (rr < nrows) ? X[(size_t)rr * K + i % K] : 0.f;
        }
        __syncthreads();
        int row = base + r;
        if (row < nrows) {
            float acc = bs[c];
            #pragma unroll
            for (int k = 0; k < K; k++) acc += Xs[r * K + k] * Ws[k * C + c];
            if (ACT == 1) acc = lrelu_(acc);
            else if (ACT == 2) acc = fmaxf(acc, 0.f);
            Y[(size_t)row * C + c] = acc;
        }
    }
}

// ---------------- degrees (for pins norms) ----------------
__global__ __launch_bounds__(256) void deg_kernel(const int* __restrict__ src, const int* __restrict__ dst,
                                                  int* __restrict__ degs, int* __restrict__ degd, int np)
{
    int p = blockIdx.x * 256 + threadIdx.x;
    if (p < np) { atomicAdd(&degs[src[p]], 1); atomicAdd(&degd[dst[p]], 1); }
}

__global__ __launch_bounds__(256) void norm_kernel(int* __restrict__ arr, int n)
{
    int i = blockIdx.x * 256 + threadIdx.x;
    if (i < n) {
        int v = arr[i]; if (v < 1) v = 1;
        arr[i] = __float_as_int(rsqrtf((float)v));
    }
}

// ================= CSR build (generic, keyed by given index array) =================
__global__ __launch_bounds__(256) void csr_count_kernel(const int* __restrict__ key, int* __restrict__ cnt, int ne)
{
    int e = blockIdx.x * 256 + threadIdx.x;
    if (e < ne) atomicAdd(&cnt[key[e]], 1);
}

__global__ __launch_bounds__(256) void scan_block_sum_kernel(const int* __restrict__ cnt, int* __restrict__ bsum, int n)
{
    __shared__ int sh[256];
    int i = blockIdx.x * 256 + threadIdx.x;
    sh[threadIdx.x] = (i < n) ? cnt[i] : 0;
    __syncthreads();
    for (int s = 128; s > 0; s >>= 1) {
        if (threadIdx.x < s) sh[threadIdx.x] += sh[threadIdx.x + s];
        __syncthreads();
    }
    if (threadIdx.x == 0) bsum[blockIdx.x] = sh[0];
}

__global__ __launch_bounds__(512) void scan_bsum_kernel(int* __restrict__ bsum, int nb, int* __restrict__ total_out)
{
    __shared__ int sh[512];
    int i = threadIdx.x;
    int v = (i < nb) ? bsum[i] : 0;
    sh[i] = v;
    __syncthreads();
    for (int s = 1; s < 512; s <<= 1) {
        int add = (i >= s) ? sh[i - s] : 0;
        __syncthreads();
        sh[i] += add;
        __syncthreads();
    }
    if (i < nb) bsum[i] = sh[i] - v;     // exclusive
    if (i == nb - 1) *total_out = sh[i];
}

__global__ __launch_bounds__(256) void scan_final_kernel(const int* __restrict__ cnt, const int* __restrict__ bsum,
                                                         int* __restrict__ row_start, int* __restrict__ nxt, int n)
{
    __shared__ int sh[256];
    int i = blockIdx.x * 256 + threadIdx.x;
    int v = (i < n) ? cnt[i] : 0;
    sh[threadIdx.x] = v;
    __syncthreads();
    for (int s = 1; s < 256; s <<= 1) {
        int add = (threadIdx.x >= s) ? sh[threadIdx.x - s] : 0;
        __syncthreads();
        sh[threadIdx.x] += add;
        __syncthreads();
    }
    if (i < n) {
        int excl = sh[threadIdx.x] - v + bsum[blockIdx.x];
        row_start[i] = excl;
        nxt[i] = excl;
    }
}

__global__ __launch_bounds__(256) void csr_fill_kernel(const int* __restrict__ key, int* __restrict__ nxt,
                                                       int* __restrict__ eidx, int ne)
{
    int e = blockIdx.x * 256 + threadIdx.x;
    if (e < ne) {
        int slot = atomicAdd(&nxt[key[e]], 1);
        eidx[slot] = e;
    }
}

// ---------------- edge weights for all 3 layers ----------------
__global__ __launch_bounds__(256) void edge_ew_kernel(const float* __restrict__ in_edge,
                                                      const float* __restrict__ elW, const float* __restrict__ elb,
                                                      const float* __restrict__ gW, const float* __restrict__ gb,
                                                      float* __restrict__ ew3, int ne)
{
    __shared__ float W[32], B[8], G[24], Gb[3];
    if (threadIdx.x < 32) W[threadIdx.x] = elW[threadIdx.x];
    if (threadIdx.x < 8)  B[threadIdx.x] = elb[threadIdx.x];
    if (threadIdx.x < 24) G[threadIdx.x] = gW[threadIdx.x];
    if (threadIdx.x < 3)  Gb[threadIdx.x] = gb[threadIdx.x];
    __syncthreads();
    for (int e = blockIdx.x * 256 + threadIdx.x; e < ne; e += gridDim.x * 256) {
        float4 x = *(const float4*)&in_edge[(size_t)e * 4];
        float ef[8];
        #pragma unroll
        for (int j = 0; j < 8; j++)
            ef[j] = lrelu_(B[j] + x.x * W[j] + x.y * W[8 + j] + x.z * W[16 + j] + x.w * W[24 + j]);
        #pragma unroll
        for (int i = 0; i < 3; i++) {
            float a = Gb[i];
            #pragma unroll
            for (int j = 0; j < 8; j++) a += ef[j] * G[i * 8 + j];
            ew3[(size_t)i * ne + e] = sigm_(a);
        }
    }
}

// ---------------- pins GraphConv gather (lane-parallel metadata preload + unroll-4) -------------
__global__ __launch_bounds__(256) void pins_gather_kernel(const unsigned short* __restrict__ nfb,
                                                          const float* __restrict__ snorm,
                                                          const float* __restrict__ dnorm,
                                                          const int* __restrict__ psrc,
                                                          const int* __restrict__ prow,
                                                          const int* __restrict__ peidx,
                                                          unsigned short* __restrict__ aggb, int nt)
{
    __shared__ int sS[4][64];
    __shared__ float sN[4][64];
    const int lane = threadIdx.x & 63, wv = threadIdx.x >> 6;
    for (int d = blockIdx.x * 4 + wv; d < nt; d += gridDim.x * 4) {
        int rs = prow[d], re = prow[d + 1];
        float acc = 0.f;
        for (int cbase = rs; cbase < re; cbase += 64) {
            int cnt = re - cbase; if (cnt > 64) cnt = 64;
            if (lane < cnt) {
                int p = peidx[cbase + lane];
                int s = psrc[p];
                sS[wv][lane] = s;
                sN[wv][lane] = snorm[s];
            }
            int k = 0;
            for (; k + 3 < cnt; k += 4) {
                int s0 = sS[wv][k], s1 = sS[wv][k+1], s2 = sS[wv][k+2], s3 = sS[wv][k+3];
                float n0 = sN[wv][k], n1 = sN[wv][k+1], n2 = sN[wv][k+2], n3 = sN[wv][k+3];
                float v0 = bf2f(nfb[(size_t)s0 * 64 + lane]) * n0;
                float v1 = bf2f(nfb[(size_t)s1 * 64 + lane]) * n1;
                float v2 = bf2f(nfb[(size_t)s2 * 64 + lane]) * n2;
                float v3 = bf2f(nfb[(size_t)s3 * 64 + lane]) * n3;
                acc += (v0 + v1) + (v2 + v3);
            }
            for (; k < cnt; k++)
                acc += bf2f(nfb[(size_t)sS[wv][k] * 64 + lane]) * sN[wv][k];
        }
        aggb[(size_t)d * 64 + lane] = f2bf(acc * dnorm[d]);
    }
}

// ---------------- CFConv per-pin: GEMM1 MFMA(K padded to 32) + GEMM2 MFMA, dense HE write -------
__global__ __launch_bounds__(256) void cf_pin6_kernel(const float* __restrict__ pinf,
                                                      const float* __restrict__ W1, const float* __restrict__ B1,
                                                      const float* __restrict__ W2, const float* __restrict__ B2,
                                                      unsigned short* __restrict__ HEb, int np)
{
    __shared__ __align__(16) unsigned short W1T[64 * 40];  // B operand [n][k], k 0..31 (16..31 zero)
    __shared__ __align__(16) unsigned short W2T[64 * 72];
    __shared__ __align__(16) unsigned short PFb[64 * 40];  // A rows [p][k 0..31], padded zeros
    __shared__ __align__(16) unsigned short T1s[64 * 72];  // T1 then HE
    __shared__ float bs1[64], bs2[64];
    for (int i = threadIdx.x; i < 64 * 32; i += 256) {
        int n = i & 63, k = i >> 6;
        W1T[n * 40 + k] = (k < 16) ? f2bf(W1[k * 64 + n]) : (unsigned short)0;
    }
    for (int i = threadIdx.x; i < 4096; i += 256) {
        int k = i >> 6, n = i & 63;
        W2T[n * 72 + k] = f2bf(W2[i]);
    }
    if (threadIdx.x < 64) { bs1[threadIdx.x] = B1[threadIdx.x]; bs2[threadIdx.x] = B2[threadIdx.x]; }
    const int lane = threadIdx.x & 63, wv = threadIdx.x >> 6;
    const int l15 = lane & 15, quad = lane >> 4;
    const int arow = 16 * wv + l15;
    const int koff = quad * 8;
    const int mrow = 16 * wv + quad * 4;
    for (int base = blockIdx.x * 64; base < np; base += gridDim.x * 64) {
        __syncthreads();
        {
            int row = threadIdx.x >> 2, kq = (threadIdx.x & 3) * 4;
            int p = base + row;
            float4 v = make_float4(0.f, 0.f, 0.f, 0.f);
            if (p < np) v = *(const float4*)&pinf[(size_t)p * 16 + kq];
            *(ushort4*)&PFb[row * 40 + kq] = pack4(v);
            if ((threadIdx.x & 3) < 2)
                *(uint4*)&PFb[row * 40 + 16 + (threadIdx.x & 3) * 8] = make_uint4(0,0,0,0);
        }
        __syncthreads();
        // GEMM1 (MFMA, K=32 zero-padded): T1 = ssp(PF @ W1 + b1)
        {
            f4v acc1[4];
            #pragma unroll
            for (int t = 0; t < 4; t++) acc1[t] = (f4v){0.f,0.f,0.f,0.f};
            s8v a = *(const s8v*)&PFb[arow * 40 + koff];
            #pragma unroll
            for (int t = 0; t < 4; t++) {
                int n = t * 16 + l15;
                s8v b = *(const s8v*)&W1T[n * 40 + koff];
                acc1[t] = __builtin_amdgcn_mfma_f32_16x16x32_bf16(a, b, acc1[t], 0, 0, 0);
            }
            #pragma unroll
            for (int t = 0; t < 4; t++) {
                int col = t * 16 + l15;
                float b = bs1[col];
                #pragma unroll
                for (int r = 0; r < 4; r++)
                    T1s[(mrow + r) * 72 + col] = f2bf(ssp_(acc1[t][r] + b));
            }
        }
        __syncthreads();
        // GEMM2 (MFMA): HE = ssp(T1 @ W2 + b2); overwrites T1s (guarded)
        {
            f4v acc4[4];
            #pragma unroll
            for (int t = 0; t < 4; t++) acc4[t] = (f4v){0.f, 0.f, 0.f, 0.f};
            s8v a0 = *(const s8v*)&T1s[arow * 72 + koff];
            s8v a1 = *(const s8v*)&T1s[arow * 72 + 32 + koff];
            #pragma unroll
            for (int t = 0; t < 4; t++) {
                int n = t * 16 + l15;
                s8v b0 = *(const s8v*)&W2T[n * 72 + koff];
                s8v b1 = *(const s8v*)&W2T[n * 72 + 32 + koff];
                acc4[t] = __builtin_amdgcn_mfma_f32_16x16x32_bf16(a0, b0, acc4[t], 0, 0, 0);
                acc4[t] = __builtin_amdgcn_mfma_f32_16x16x32_bf16(a1, b1, acc4[t], 0, 0, 0);
            }
            __syncthreads();
            #pragma unroll
            for (int t = 0; t < 4; t++) {
                int col = t * 16 + l15;
                float b = bs2[col];
                #pragma unroll
                for (int r = 0; r < 4; r++)
                    T1s[(mrow + r) * 72 + col] = f2bf(ssp_(acc4[t][r] + b));
            }
        }
        __syncthreads();
        // dense coalesced HE write
        {
            int row = threadIdx.x >> 2, kq = (threadIdx.x & 3) * 16;
            int p = base + row;
            if (p < np) {
                *(uint4*)&HEb[(size_t)p * 64 + kq]     = *(const uint4*)&T1s[row * 72 + kq];
                *(uint4*)&HEb[(size_t)p * 64 + kq + 8] = *(const uint4*)&T1s[row * 72 + kq + 8];
            }
        }
    }
}

// ---------------- CF gather over psrc-CSR: h_cf[n] = sum hv[pdst[p]] * HE[p]  (no atomics) ------
__global__ __launch_bounds__(256) void cf_gather_kernel(const unsigned short* __restrict__ HEb,
                                                        const unsigned short* __restrict__ hvb,
                                                        const int* __restrict__ pdst,
                                                        const int* __restrict__ srow,
                                                        const int* __restrict__ seidx,
                                                        unsigned short* __restrict__ cfb, int nn)
{
    __shared__ int sP[4][64], sD[4][64];
    const int lane = threadIdx.x & 63, wv = threadIdx.x >> 6;
    for (int d = blockIdx.x * 4 + wv; d < nn; d += gridDim.x * 4) {
        int rs = srow[d], re = srow[d + 1];
        float acc = 0.f;
        for (int cbase = rs; cbase < re; cbase += 64) {
            int cnt = re - cbase; if (cnt > 64) cnt = 64;
            if (lane < cnt) {
                int p = seidx[cbase + lane];
                sP[wv][lane] = p;
                sD[wv][lane] = pdst[p];
            }
            int k = 0;
            for (; k + 1 < cnt; k += 2) {
                int p0 = sP[wv][k], p1 = sP[wv][k+1];
                int d0 = sD[wv][k], d1 = sD[wv][k+1];
                float he0 = bf2f(HEb[(size_t)p0 * 64 + lane]);
                float hv0 = bf2f(hvb[(size_t)d0 * 64 + lane]);
                float he1 = bf2f(HEb[(size_t)p1 * 64 + lane]);
                float hv1 = bf2f(hvb[(size_t)d1 * 64 + lane]);
                acc += he0 * hv0 + he1 * hv1;
            }
            if (k < cnt) {
                int p0 = sP[wv][k], d0 = sD[wv][k];
                acc += bf2f(HEb[(size_t)p0 * 64 + lane]) * bf2f(hvb[(size_t)d0 * 64 + lane]);
            }
        }
        cfb[(size_t)d * 64 + lane] = f2bf(acc);
    }
}

// ---------------- SAGE gather-max (lane-parallel metadata preload + unroll-4) ----------------
__global__ __launch_bounds__(256) void sage_gather_kernel(const unsigned short* __restrict__ hpb,
                                                          const float* __restrict__ ew,
                                                          const int* __restrict__ esrc,
                                                          const int* __restrict__ row_start,
                                                          const int* __restrict__ eidx,
                                                          unsigned short* __restrict__ ngb, int nn)
{
    __shared__ int sS[4][64];
    __shared__ float sWt[4][64];
    const int lane = threadIdx.x & 63, wv = threadIdx.x >> 6;
    for (int d = blockIdx.x * 4 + wv; d < nn; d += gridDim.x * 4) {
        int rs = row_start[d], re = row_start[d + 1];
        float acc = 0.f;
        for (int cbase = rs; cbase < re; cbase += 64) {
            int cnt = re - cbase; if (cnt > 64) cnt = 64;
            if (lane < cnt) {
                int e = eidx[cbase + lane];
                sS[wv][lane] = esrc[e];
                sWt[wv][lane] = ew[e];
            }
            int k = 0;
            for (; k + 3 < cnt; k += 4) {
                int s0 = sS[wv][k], s1 = sS[wv][k+1], s2 = sS[wv][k+2], s3 = sS[wv][k+3];
                float w0 = sWt[wv][k], w1 = sWt[wv][k+1], w2 = sWt[wv][k+2], w3 = sWt[wv][k+3];
                float v0 = bf2f(hpb[(size_t)s0 * 64 + lane]) * w0;
                float v1 = bf2f(hpb[(size_t)s1 * 64 + lane]) * w1;
                float v2 = bf2f(hpb[(size_t)s2 * 64 + lane]) * w2;
                float v3 = bf2f(hpb[(size_t)s3 * 64 + lane]) * w3;
                acc = fmaxf(acc, fmaxf(fmaxf(v0, v1), fmaxf(v2, v3)));
            }
            for (; k < cnt; k++)
                acc = fmaxf(acc, bf2f(hpb[(size_t)sS[wv][k] * 64 + lane]) * sWt[wv][k]);
        }
        ngb[(size_t)d * 64 + lane] = f2bf(acc);
    }
}

// ---------------- node head (32 rows/iter, grid-stride, 3-stage MLP; nf is bf16) ----------------
__global__ __launch_bounds__(256) void node_head3_kernel(const float* __restrict__ in_node,
                                                         const unsigned short* __restrict__ nfb,
                                                         const float* __restrict__ W1, const float* __restrict__ B1,
                                                         const float* __restrict__ W2, const float* __restrict__ B2,
                                                         const float* __restrict__ W3, const float* __restrict__ B3,
                                                         float* __restrict__ out, int n)
{
    __shared__ float Ws1[80 * 64], Ws2[64 * 64], Ws3[64 * 4];
    __shared__ float bs1[64], bs2[64], bs3[4];
    __shared__ float Xs[32 * 84];       // reused as H2 (stride 68)
    __shared__ float H1[32 * 68];
    for (int i = threadIdx.x; i < 80 * 64; i += 256) Ws1[i] = W1[i];
    for (int i = threadIdx.x; i < 64 * 64; i += 256) Ws2[i] = W2[i];
    for (int i = threadIdx.x; i < 64 * 4; i += 256) Ws3[i] = W3[i];
    if (threadIdx.x < 64) { bs1[threadIdx.x] = B1[threadIdx.x]; bs2[threadIdx.x] = B2[threadIdx.x]; }
    if (threadIdx.x < 4) bs3[threadIdx.x] = B3[threadIdx.x];
    const int tr = threadIdx.x >> 4, tc = threadIdx.x & 15;
    const int r0 = tr * 2, c0 = tc * 4;
    for (int base = blockIdx.x * 32; base < n; base += gridDim.x * 32) {
        __syncthreads();
        for (int i = threadIdx.x; i < 32 * 4; i += 256) {
            int row = i >> 2, kq = (i & 3) * 4;
            int g = base + row;
            float4 v = make_float4(0,0,0,0);
            if (g < n) v = *(const float4*)&in_node[(size_t)g * 16 + kq];
            *(float4*)&Xs[row * 84 + kq] = v;
        }
        for (int i = threadIdx.x; i < 32 * 16; i += 256) {
            int row = i >> 4, kq = (i & 15) * 4;
            int g = base + row;
            float4 v = make_float4(0,0,0,0);
            if (g < n) {
                ushort4 u = *(const ushort4*)&nfb[(size_t)g * 64 + kq];
                v.x = bf2f(u.x); v.y = bf2f(u.y); v.z = bf2f(u.z); v.w = bf2f(u.w);
            }
            *(float4*)&Xs[row * 84 + 16 + kq] = v;
        }
        __syncthreads();
        {
            float acc[2][4];
            #pragma unroll
            for (int i = 0; i < 2; i++)
                #pragma unroll
                for (int j = 0; j < 4; j++) acc[i][j] = bs1[c0 + j];
            #pragma unroll 4
            for (int kq = 0; kq < 80; kq += 4) {
                float4 xa[2], wa[4];
                #pragma unroll
                for (int i = 0; i < 2; i++) xa[i] = *(const float4*)&Xs[(r0 + i) * 84 + kq];
                #pragma unroll
                for (int j = 0; j < 4; j++) wa[j] = *(const float4*)&Ws1[(kq + j) * 64 + c0];
                #pragma unroll
                for (int kk = 0; kk < 4; kk++)
                    #pragma unroll
                    for (int i = 0; i < 2; i++) {
                        float x = ((const float*)&xa[i])[kk];
                        #pragma unroll
                        for (int j = 0; j < 4; j++) acc[i][j] += x * ((const float*)&wa[kk])[j];
                    }
            }
            #pragma unroll
            for (int i = 0; i < 2; i++) {
                float4 o; float* op = (float*)&o;
                #pragma unroll
                for (int j = 0; j < 4; j++) op[j] = lrelu_(acc[i][j]);
                *(float4*)&H1[(r0 + i) * 68 + c0] = o;
            }
        }
        __syncthreads();
        float* H2 = Xs;
        {
            float acc[2][4];
            #pragma unroll
            for (int i = 0; i < 2; i++)
                #pragma unroll
                for (int j = 0; j < 4; j++) acc[i][j] = bs2[c0 + j];
            #pragma unroll 4
            for (int kq = 0; kq < 64; kq += 4) {
                float4 xa[2], wa[4];
                #pragma unroll
                for (int i = 0; i < 2; i++) xa[i] = *(const float4*)&H1[(r0 + i) * 68 + kq];
                #pragma unroll
                for (int j = 0; j < 4; j++) wa[j] = *(const float4*)&Ws2[(kq + j) * 64 + c0];
                #pragma unroll
                for (int kk = 0; kk < 4; kk++)
                    #pragma unroll
                    for (int i = 0; i < 2; i++) {
                        float x = ((const float*)&xa[i])[kk];
                        #pragma unroll
                        for (int j = 0; j < 4; j++) acc[i][j] += x * ((const float*)&wa[kk])[j];
                    }
            }
            __syncthreads();
            #pragma unroll
            for (int i = 0; i < 2; i++) {
                float4 o; float* op = (float*)&o;
                #pragma unroll
                for (int j = 0; j < 4; j++) op[j] = lrelu_(acc[i][j]);
                *(float4*)&H2[(r0 + i) * 68 + c0] = o;
            }
        }
        __syncthreads();
        if (threadIdx.x < 128) {
            int row = threadIdx.x >> 2, c = threadIdx.x & 3;
            float acc = bs3[c];
            #pragma unroll 4
            for (int kq = 0; kq < 64; kq += 4) {
                float4 h = *(const float4*)&H2[row * 68 + kq];
                #pragma unroll
                for (int j = 0; j < 4; j++) acc += ((const float*)&h)[j] * Ws3[(kq + j) * 4 + c];
            }
            int g = base + row;
            if (g < n) out[(size_t)g * 4 + c] = sigm_(acc);
        }
    }
}

// ---------------- net head (32 rows/iter, grid-stride, C_out=1; tf fp32) ----------------
__global__ __launch_bounds__(256) void net_head3_kernel(const float* __restrict__ in_net, const float* __restrict__ tf,
                                                        const float* __restrict__ W1, const float* __restrict__ B1,
                                                        const float* __restrict__ W2, const float* __restrict__ B2,
                                                        const float* __restrict__ W3, const float* __restrict__ B3,
                                                        float* __restrict__ out, int n)
{
    __shared__ float Ws1[72 * 64], Ws2[64 * 64], Ws3[64];
    __shared__ float bs1[64], bs2[64], bs3[1];
    __shared__ float Xs[32 * 76];       // reused as H2 (stride 68)
    __shared__ float H1[32 * 68];
    for (int i = threadIdx.x; i < 72 * 64; i += 256) Ws1[i] = W1[i];
    for (int i = threadIdx.x; i < 64 * 64; i += 256) Ws2[i] = W2[i];
    if (threadIdx.x < 64) { Ws3[threadIdx.x] = W3[threadIdx.x]; bs1[threadIdx.x] = B1[threadIdx.x]; bs2[threadIdx.x] = B2[threadIdx.x]; }
    if (threadIdx.x == 0) bs3[0] = B3[0];
    const int tr = threadIdx.x >> 4, tc = threadIdx.x & 15;
    const int r0 = tr * 2, c0 = tc * 4;
    for (int base = blockIdx.x * 32; base < n; base += gridDim.x * 32) {
        __syncthreads();
        for (int i = threadIdx.x; i < 32 * 2; i += 256) {
            int row = i >> 1, kq = (i & 1) * 4;
            int g = base + row;
            float4 v = make_float4(0,0,0,0);
            if (g < n) v = *(const float4*)&in_net[(size_t)g * 8 + kq];
            *(float4*)&Xs[row * 76 + kq] = v;
        }
        for (int i = threadIdx.x; i < 32 * 16; i += 256) {
            int row = i >> 4, kq = (i & 15) * 4;
            int g = base + row;
            float4 v = make_float4(0,0,0,0);
            if (g < n) v = *(const float4*)&tf[(size_t)g * 64 + kq];
            *(float4*)&Xs[row * 76 + 8 + kq] = v;
        }
        __syncthreads();
        {
            float acc[2][4];
            #pragma unroll
            for (int i = 0; i < 2; i++)
                #pragma unroll
                for (int j = 0; j < 4; j++) acc[i][j] = bs1[c0 + j];
            #pragma unroll 4
            for (int kq = 0; kq < 72; kq += 4) {
                float4 xa[2], wa[4];
                #pragma unroll
                for (int i = 0; i < 2; i++) xa[i] = *(const float4*)&Xs[(r0 + i) * 76 + kq];
                #pragma unroll
                for (int j = 0; j < 4; j++) wa[j] = *(const float4*)&Ws1[(kq + j) * 64 + c0];
                #pragma unroll
                for (int kk = 0; kk < 4; kk++)
                    #pragma unroll
                    for (int i = 0; i < 2; i++) {
                        float x = ((const float*)&xa[i])[kk];
                        #pragma unroll
                        for (int j = 0; j < 4; j++) acc[i][j] += x * ((const float*)&wa[kk])[j];
                    }
            }
            #pragma unroll
            for (int i = 0; i < 2; i++) {
                float4 o; float* op = (float*)&o;
                #pragma unroll
                for (int j = 0; j < 4; j++) op[j] = lrelu_(acc[i][j]);
                *(float4*)&H1[(r0 + i) * 68 + c0] = o;
            }
        }
        __syncthreads();
        float* H2 = Xs;
        {
            float acc[2][4];
            #pragma unroll
            for (int i = 0; i < 2; i++)
                #pragma unroll
                for (int j = 0; j < 4; j++) acc[i][j] = bs2[c0 + j];
            #pragma unroll 4
            for (int kq = 0; kq < 64; kq += 4) {
                float4 xa[2], wa[4];
                #pragma unroll
                for (int i = 0; i < 2; i++) xa[i] = *(const float4*)&H1[(r0 + i) * 68 + kq];
                #pragma unroll
                for (int j = 0; j < 4; j++) wa[j] = *(const float4*)&Ws2[(kq + j) * 64 + c0];
                #pragma unroll
                for (int kk = 0; kk < 4; kk++)
                    #pragma unroll
                    for (int i = 0; i < 2; i++) {
                        float x = ((const float*)&xa[i])[kk];
                        #pragma unroll
                        for (int j = 0; j < 4; j++) acc[i][j] += x * ((const float*)&wa[kk])[j];
                    }
            }
            __syncthreads();
            #pragma unroll
            for (int i = 0; i < 2; i++) {
                float4 o; float* op = (float*)&o;
                #pragma unroll
                for (int j = 0; j < 4; j++) op[j] = lrelu_(acc[i][j]);
                *(float4*)&H2[(r0 + i) * 68 + c0] = o;
            }
        }
        __syncthreads();
        if (threadIdx.x < 32) {
            int row = threadIdx.x;
            float acc = bs3[0];
            #pragma unroll 4
            for (int kq = 0; kq < 64; kq += 4) {
                float4 h = *(const float4*)&H2[row * 68 + kq];
                float4 w = *(const float4*)&Ws3[kq];
                acc += h.x * w.x + h.y * w.y + h.z * w.z + h.w * w.w;
            }
            int g = base + row;
            if (g < n) out[g] = sigm_(acc);
        }
    }
}

extern "C" void kernel_launch(void* const* d_in, const int* in_sizes, int n_in,
                              void* d_out, int out_size, void* d_ws, size_t ws_size,
                              hipStream_t stream)
{
    (void)in_sizes; (void)n_in; (void)out_size; (void)ws_size;
    constexpr int Nn = 100000, Nt = 30000, Np = 400000, Ne = 1000000;
    constexpr int H = 64, L = 3, T = 4;

    auto fpt = [&](int i){ return (const float*)d_in[i]; };
    auto ipt = [&](int i){ return (const int*)d_in[i]; };

    const float* in_node = fpt(0);
    const float* in_net  = fpt(1);
    const float* in_pin  = fpt(2);
    const float* in_edge = fpt(3);
    const int* psrc = ipt(4);
    const int* pdst = ipt(5);
    const int* esrc = ipt(6);
    const int* edst = ipt(7);

    float* ws = (float*)d_ws;
    size_t o = 0;
    auto alloc = [&](size_t nel){ float* p = ws + o; o += nel; return p; };
    unsigned short* node_a = (unsigned short*)alloc((size_t)Nn * 32);
    unsigned short* node_b = (unsigned short*)alloc((size_t)Nn * 32);
    unsigned short* aggb   = (unsigned short*)alloc((size_t)Nt * 32);
    unsigned short* hvb    = (unsigned short*)alloc((size_t)Nt * 32);
    unsigned short* hpb    = (unsigned short*)alloc((size_t)Nn * 32);
    unsigned short* ngb    = (unsigned short*)alloc((size_t)Nn * 32);
    unsigned short* HEb    = (unsigned short*)alloc((size_t)Np * 32);
    unsigned short* cfb    = (unsigned short*)alloc((size_t)Nn * 32);
    float* net_a  = alloc((size_t)Nt * H);
    float* net_b  = alloc((size_t)Nt * H);
    float* pinf   = alloc((size_t)Np * 16);
    float* ew3    = alloc((size_t)3 * Ne);
    float* snorm  = alloc((size_t)Nn);
    float* dnorm  = alloc((size_t)Nt);
    int* cnt       = (int*)alloc((size_t)Nn);
    int* row_start = (int*)alloc((size_t)Nn + 1);
    int* nxt       = (int*)alloc((size_t)Nn);
    int* eidx      = (int*)alloc((size_t)Ne);
    int* bsum      = (int*)alloc((size_t)512);
    int* pcnt      = (int*)alloc((size_t)Nt);
    int* prow      = (int*)alloc((size_t)Nt + 1);
    int* pnxt      = (int*)alloc((size_t)Nt);
    int* peidx     = (int*)alloc((size_t)Np);
    int* pbsum     = (int*)alloc((size_t)256);
    int* srow      = (int*)alloc((size_t)Nn + 1);
    int* seidx     = (int*)alloc((size_t)Np);

    constexpr int NB  = (Nn + 255) / 256;
    constexpr int NB2 = (Nt + 255) / 256;

    // degree norms for pins
    hipMemsetAsync(snorm, 0, (size_t)Nn * 4, stream);
    hipMemsetAsync(dnorm, 0, (size_t)Nt * 4, stream);
    deg_kernel<<<(Np + 255) / 256, 256, 0, stream>>>(psrc, pdst, (int*)snorm, (int*)dnorm, Np);
    norm_kernel<<<(Nn + 255) / 256, 256, 0, stream>>>((int*)snorm, Nn);
    norm_kernel<<<(Nt + 255) / 256, 256, 0, stream>>>((int*)dnorm, Nt);

    // CSR #1: near keyed by edst (Nn rows)
    hipMemsetAsync(cnt, 0, (size_t)Nn * 4, stream);
    csr_count_kernel<<<(Ne + 255) / 256, 256, 0, stream>>>(edst, cnt, Ne);
    scan_block_sum_kernel<<<NB, 256, 0, stream>>>(cnt, bsum, Nn);
    scan_bsum_kernel<<<1, 512, 0, stream>>>(bsum, NB, row_start + Nn);
    scan_final_kernel<<<NB, 256, 0, stream>>>(cnt, bsum, row_start, nxt, Nn);
    csr_fill_kernel<<<(Ne + 255) / 256, 256, 0, stream>>>(edst, nxt, eidx, Ne);

    // CSR #2: pins keyed by pdst (Nt rows)
    hipMemsetAsync(pcnt, 0, (size_t)Nt * 4, stream);
    csr_count_kernel<<<(Np + 255) / 256, 256, 0, stream>>>(pdst, pcnt, Np);
    scan_block_sum_kernel<<<NB2, 256, 0, stream>>>(pcnt, pbsum, Nt);
    scan_bsum_kernel<<<1, 512, 0, stream>>>(pbsum, NB2, prow + Nt);
    scan_final_kernel<<<NB2, 256, 0, stream>>>(pcnt, pbsum, prow, pnxt, Nt);
    csr_fill_kernel<<<(Np + 255) / 256, 256, 0, stream>>>(pdst, pnxt, peidx, Np);

    // CSR #3: pins keyed by psrc (Nn rows) — reuses cnt/bsum/nxt scratch
    hipMemsetAsync(cnt, 0, (size_t)Nn * 4, stream);
    csr_count_kernel<<<(Np + 255) / 256, 256, 0, stream>>>(psrc, cnt, Np);
    scan_block_sum_kernel<<<NB, 256, 0, stream>>>(cnt, bsum, Nn);
    scan_bsum_kernel<<<1, 512, 0, stream>>>(bsum, NB, srow + Nn);
    scan_final_kernel<<<NB, 256, 0, stream>>>(cnt, bsum, srow, nxt, Nn);
    csr_fill_kernel<<<(Np + 255) / 256, 256, 0, stream>>>(psrc, nxt, seidx, Np);

    // input encoders
    gemm64_kernel<16, 1, true><<<1024, 256, 0, stream>>>(in_node, fpt(8),  fpt(9),  node_a, Nn);
    gemm64_kernel< 8, 1, false><<<469, 256, 0, stream>>>(in_net,  fpt(10), fpt(11), net_a,  Nt);
    lin_kernel<8, 16, 1><<<1024, 256, 0, stream>>>(in_pin, fpt(12), fpt(13), pinf, Np);
    edge_ew_kernel<<<2048, 256, 0, stream>>>(in_edge, fpt(14), fpt(15), fpt(16), fpt(17), ew3, Ne);

    unsigned short* ncur = node_a; unsigned short* nnew = node_b;
    float* tcur = net_a;  float* tnew = net_b;

    for (int i = 0; i < L; i++) {
        // pins GraphConv (node -> net)
        pins_gather_kernel<<<(Nt + 3) / 4, 256, 0, stream>>>(ncur, snorm, dnorm, psrc, prow, peidx, aggb, Nt);
        mfma_gemm_kernel<1, true, false><<<469, 256, 0, stream>>>(aggb, fpt(18) + (size_t)i * 4096, fpt(19) + (size_t)i * 64, tnew, Nt);

        // CFConv (net -> node): hv bf16, per-pin HE (dense), then psrc-CSR gather
        mfma_gemm_kernel<0, false, true><<<469, 256, 0, stream>>>(tcur, fpt(20) + (size_t)i * 4096, fpt(21) + (size_t)i * 64, hvb, Nt);
        cf_pin6_kernel<<<1024, 256, 0, stream>>>(pinf,
                                                 fpt(22) + (size_t)i * 1024, fpt(23) + (size_t)i * 64,
                                                 fpt(24) + (size_t)i * 4096, fpt(25) + (size_t)i * 64,
                                                 HEb, Np);
        cf_gather_kernel<<<(Nn + 3) / 4, 256, 0, stream>>>(HEb, hvb, pdst, srow, seidx, cfb, Nn);

        // SAGE (near)
        mfma_gemm_kernel<2, true, true><<<1024, 256, 0, stream>>>(ncur, fpt(28) + (size_t)i * 4096, fpt(29) + (size_t)i * 64, hpb, Nn);
        sage_gather_kernel<<<(Nn + 3) / 4, 256, 0, stream>>>(hpb, ew3 + (size_t)i * Ne, esrc, row_start, eidx, ngb, Nn);

        // combine
        mfma_combine_kernel<<<1024, 256, 0, stream>>>(cfb, ncur, ngb,
                                                      fpt(26) + (size_t)i * 4096, fpt(27) + (size_t)i * 64,
                                                      fpt(30) + (size_t)i * 4096, fpt(31) + (size_t)i * 4096,
                                                      fpt(32) + (size_t)i * 64,
                                                      nnew, Nn);

        unsigned short* t = ncur; ncur = nnew; nnew = t;
        float* tf = tcur; tcur = tnew; tnew = tf;
    }

    float* out = (float*)d_out;
    node_head3_kernel<<<640, 256, 0, stream>>>(in_node, ncur, fpt(33), fpt(34), fpt(35), fpt(36), fpt(37), fpt(38), out, Nn);
    net_head3_kernel<<<480, 256, 0, stream>>>(in_net, tcur, fpt(39), fpt(40), fpt(41), fpt(42), fpt(43), fpt(44), out + (size_t)Nn * T, Nt);
}